// Round 1
// baseline (12258.147 us; speedup 1.0000x reference)
//
#include <hip/hip_runtime.h>

// ---------------- problem constants ----------------
#define NB 64
#define NT 256
#define BT 16384          // NB*NT
#define NG 66
#define START_ 64
#define STOP_ 65
#define INV_TEMP 0.08838834764831845f  // 1/sqrt(128)

// ---------------- workspace layout (float offsets) ----------------
// ce_pad [64][258][128]      @ 0          (2,113,536)   dead after conv
// q      [BT][512]           @ 2,113,536  (8,388,608)   dead after scores
// kv     [BT][512]           @ 10,502,144 (8,388,608)   dead after x-GEMM
// preF   [BT][1024]          @ 0          (16,777,216)  aliases ce_pad+q+kv-head (all dead)
// scores [64][256][256]      @ 18,890,752 (4,194,304)
// x      [BT][512]           @ 23,085,056 (8,388,608)
// y      [BT][512]           @ 31,473,664 (8,388,608)
// preB   [BT][1024]          @ 39,862,272 (16,777,216)
// emit   [BT][66]            @ 56,639,488 (1,081,344)
// w2     [384][384]          @ 57,720,832 (147,456)
// hbuf   [2][2][64][256]     @ 57,868,288 (65,536)
// bar    int                 @ 57,933,824
#define OFF_CEPAD 0L
#define OFF_Q     2113536L
#define OFF_KV    10502144L
#define OFF_PREF  0L
#define OFF_SC    18890752L
#define OFF_X     23085056L
#define OFF_Y     31473664L
#define OFF_PREB  39862272L
#define OFF_EMIT  56639488L
#define OFF_W2    57720832L
#define OFF_HBUF  57868288L
#define OFF_BAR   57933824L

// ---------------- embedding / gather ----------------
__global__ __launch_bounds__(128) void embed_k(
    const int* __restrict__ word, const int* __restrict__ intents,
    const int* __restrict__ chars, const int* __restrict__ lexi,
    const float* __restrict__ word_emb, const float* __restrict__ lexi_emb,
    const float* __restrict__ intent_emb, const float* __restrict__ char_emb,
    float* __restrict__ kv, float* __restrict__ q, float* __restrict__ ce_pad)
{
    int bt = blockIdx.x;
    int b = bt >> 8, t = bt & 255;
    int tid = threadIdx.x;
    const float4* wrow = (const float4*)(word_emb + (long)word[bt] * 256);
    const float4* lrow = (const float4*)(lexi_emb + (long)lexi[bt] * 128);
    const float4* irow = (const float4*)(intent_emb + (long)intents[b] * 128);
    const float4* crow = (const float4*)(char_emb + (long)chars[bt] * 128);
    float4* kvrow = (float4*)(kv + (long)bt * 512);
    float4* qrow  = (float4*)(q  + (long)bt * 512);
    float4* cerow = (float4*)(ce_pad + ((long)b * 258 + t + 1) * 128);
    if (tid < 64)       kvrow[tid] = wrow[tid];
    else if (tid < 96)  kvrow[tid] = lrow[tid - 64];
    else { float4 v = irow[tid - 96]; kvrow[tid] = v; qrow[tid] = v; }
    if (tid < 32) cerow[tid] = crow[tid];
    if (t == 0) {
        float4 z = make_float4(0.f, 0.f, 0.f, 0.f);
        if (tid < 32)      ((float4*)(ce_pad + (long)b * 258 * 128))[tid] = z;
        else if (tid < 64) ((float4*)(ce_pad + ((long)b * 258 + 257) * 128))[tid - 32] = z;
    }
}

// repack conv_w (O,C,K) -> w2[o][k*128+c]; zero loss slot & barrier
__global__ __launch_bounds__(256) void prep_k(const float* __restrict__ conv_w,
                                              float* __restrict__ w2,
                                              float* __restrict__ out0, int* __restrict__ bar)
{
    int idx = blockIdx.x * 256 + threadIdx.x;
    if (idx == 0) { out0[0] = 0.f; bar[0] = 0; }
    if (idx < 384 * 384) {
        int o = idx / 384, r = idx % 384;
        int k = r >> 7, c = r & 127;
        w2[o * 384 + r] = conv_w[o * 384 + c * 3 + k];
    }
}

// ---------------- generic fp32 GEMM: C = alpha*A@op(B) + bias0 + bias1 ----------------
// tile 128x128, K-step 16, 256 threads, 8x8 micro-tile (split 4+4 at stride 64)
#define GT 128
#define GK 16
__global__ __launch_bounds__(256) void gemm_k(
    const float* __restrict__ A, int lda, long sA, int amode,
    const float* __restrict__ Bm, int ldb, long sB, int transB,
    float* __restrict__ C, int ldc, long sC,
    int N, int K,
    const float* __restrict__ bias0, const float* __restrict__ bias1, float alpha)
{
    A  += (long)blockIdx.z * sA;
    Bm += (long)blockIdx.z * sB;
    C  += (long)blockIdx.z * sC;
    const int m0 = blockIdx.x * GT, n0 = blockIdx.y * GT;
    __shared__ float As[GK][GT + 4];
    __shared__ float Bs[GK][GT + 4];
    const int tid = threadIdx.x;
    const int tm = (tid & 15) * 4;
    const int tn = (tid >> 4) * 4;
    float acc[8][8];
#pragma unroll
    for (int i = 0; i < 8; i++)
#pragma unroll
        for (int j = 0; j < 8; j++) acc[i][j] = 0.f;
    const int lr = tid >> 2;
    const int lk = (tid & 3) * 4;

    for (int k0 = 0; k0 < K; k0 += GK) {
#pragma unroll
        for (int p = 0; p < 2; p++) {
            int m = m0 + p * 64 + lr;
            long rowoff = (amode == 0) ? ((long)m * lda)
                                       : ((long)m * 128 + (long)(m >> 8) * 256);
            float4 v = *(const float4*)(A + rowoff + k0 + lk);
            As[lk + 0][p * 64 + lr] = v.x;
            As[lk + 1][p * 64 + lr] = v.y;
            As[lk + 2][p * 64 + lr] = v.z;
            As[lk + 3][p * 64 + lr] = v.w;
        }
        if (transB) {
#pragma unroll
            for (int p = 0; p < 2; p++) {
                int n = n0 + p * 64 + lr;
                float4 v = make_float4(0.f, 0.f, 0.f, 0.f);
                if (n < N) v = *(const float4*)(Bm + (long)n * ldb + k0 + lk);
                Bs[lk + 0][p * 64 + lr] = v.x;
                Bs[lk + 1][p * 64 + lr] = v.y;
                Bs[lk + 2][p * 64 + lr] = v.z;
                Bs[lk + 3][p * 64 + lr] = v.w;
            }
        } else {
            int kk = tid >> 4;
            int nn = (tid & 15) * 8;
            float4 v0 = *(const float4*)(Bm + (long)(k0 + kk) * ldb + n0 + nn);
            float4 v1 = *(const float4*)(Bm + (long)(k0 + kk) * ldb + n0 + nn + 4);
            *(float4*)&Bs[kk][nn] = v0;
            *(float4*)&Bs[kk][nn + 4] = v1;
        }
        __syncthreads();
#pragma unroll
        for (int kk = 0; kk < GK; kk++) {
            float4 a0 = *(const float4*)&As[kk][tm];
            float4 a1 = *(const float4*)&As[kk][tm + 64];
            float4 b0 = *(const float4*)&Bs[kk][tn];
            float4 b1 = *(const float4*)&Bs[kk][tn + 64];
            float av[8] = {a0.x, a0.y, a0.z, a0.w, a1.x, a1.y, a1.z, a1.w};
            float bv[8] = {b0.x, b0.y, b0.z, b0.w, b1.x, b1.y, b1.z, b1.w};
#pragma unroll
            for (int i = 0; i < 8; i++)
#pragma unroll
                for (int j = 0; j < 8; j++)
                    acc[i][j] = fmaf(av[i], bv[j], acc[i][j]);
        }
        __syncthreads();
    }
#pragma unroll
    for (int i = 0; i < 8; i++) {
        int m = m0 + ((i < 4) ? (tm + i) : (tm + 64 + i - 4));
#pragma unroll
        for (int j = 0; j < 8; j++) {
            int n = n0 + ((j < 4) ? (tn + j) : (tn + 64 + j - 4));
            if (n < N) {
                float v = alpha * acc[i][j];
                if (bias0) v += bias0[n];
                if (bias1) v += bias1[n];
                C[(long)m * ldc + n] = v;
            }
        }
    }
}

// ---------------- row softmax over 256 cols ----------------
__global__ __launch_bounds__(256) void softmax_k(float* __restrict__ scores)
{
    int row = blockIdx.x * 4 + (threadIdx.x >> 6);
    int lane = threadIdx.x & 63;
    float4* p = (float4*)(scores + (long)row * 256);
    float4 v = p[lane];
    float m = fmaxf(fmaxf(v.x, v.y), fmaxf(v.z, v.w));
#pragma unroll
    for (int off = 32; off; off >>= 1) m = fmaxf(m, __shfl_xor(m, off));
    v.x = __expf(v.x - m); v.y = __expf(v.y - m);
    v.z = __expf(v.z - m); v.w = __expf(v.w - m);
    float s = v.x + v.y + v.z + v.w;
#pragma unroll
    for (int off = 32; off; off >>= 1) s += __shfl_xor(s, off);
    float inv = 1.f / s;
    v.x *= inv; v.y *= inv; v.z *= inv; v.w *= inv;
    p[lane] = v;
}

// ---------------- BiLSTM recurrence (persistent, manual grid barrier) ----------------
// grid = 256 blocks: dir(2) x hchunk(32, 8 h-dims each) x bchunk(4, 16 batch each)
// w_hh slice (4 gates x 8 j x 256) resident in LDS; c-state in registers.
__global__ __launch_bounds__(256) void lstm_k(
    const float* __restrict__ preF, const float* __restrict__ preB,
    const float* __restrict__ whh,      // layer base: [2][1024][256]
    float* __restrict__ hbuf,           // [2 parity][2 dir][64][256]
    float* __restrict__ out,            // [BT][512], cols dir*256+j
    int* __restrict__ bar, int syncbase)
{
    const int bid = blockIdx.x;
    const int dir = bid >> 7;
    const int hc  = (bid >> 2) & 31;
    const int bc  = bid & 3;
    const int j0 = hc * 8, b0 = bc * 16;
    const int tid = threadIdx.x;
    __shared__ float wl[4][8][260];
    __shared__ float hl[16][260];
    __shared__ float red[4][4][8][16];   // [ks][g][jj][bb]
    const float* pre = dir ? preB : preF;
    const float* w = whh + (long)dir * 1024 * 256;
    // load weight slice: rows {g*256 + j0+jj}
    {
        int row = tid >> 3;            // 0..31
        int g = row >> 3, jj = row & 7;
        int c0 = (tid & 7) * 32;
        const float* src = w + (long)(g * 256 + j0 + jj) * 256 + c0;
#pragma unroll
        for (int i = 0; i < 8; i++)
            *(float4*)&wl[g][jj][c0 + i * 4] = *(const float4*)(src + i * 4);
    }
    // zero parity-0 h
    if (hc == 0) {
        float4 z = make_float4(0.f, 0.f, 0.f, 0.f);
        float* dst = hbuf + ((long)dir * 64 + b0) * 256;
        for (int i = tid; i < 1024; i += 256) ((float4*)dst)[i] = z;
    }
    const int jjA = tid & 7, bgA = (tid >> 3) & 7, ksA = tid >> 6;
    const int jjB = tid & 7, bbB = tid >> 3;  // valid for tid<128
    float creg = 0.f;
    int syncno = syncbase;

#define GRID_BAR() do { \
    __syncthreads(); \
    if (tid == 0) { \
        __hip_atomic_fetch_add(bar, 1, __ATOMIC_RELEASE, __HIP_MEMORY_SCOPE_AGENT); \
        ++syncno; \
        while (__hip_atomic_load(bar, __ATOMIC_ACQUIRE, __HIP_MEMORY_SCOPE_AGENT) < syncno * 256) { \
            __builtin_amdgcn_s_sleep(2); \
        } \
    } \
    __syncthreads(); \
} while (0)

    GRID_BAR();

    for (int t = 0; t < 256; t++) {
        const int par = t & 1;
        // stage h_prev for our 16 batches
        {
            int bl = tid >> 4, k0 = (tid & 15) * 16;
            const float* src = hbuf + (((long)par * 2 + dir) * 64 + b0 + bl) * 256 + k0;
#pragma unroll
            for (int i = 0; i < 4; i++)
                *(float4*)&hl[bl][k0 + i * 4] = *(const float4*)(src + i * 4);
        }
        __syncthreads();
        // phase A: partial dot products
        {
            float acc[4][2];
#pragma unroll
            for (int g = 0; g < 4; g++) { acc[g][0] = 0.f; acc[g][1] = 0.f; }
            const int kbase = ksA * 64;
#pragma unroll 4
            for (int k = 0; k < 64; k += 4) {
                float4 h0 = *(const float4*)&hl[bgA * 2 + 0][kbase + k];
                float4 h1 = *(const float4*)&hl[bgA * 2 + 1][kbase + k];
#pragma unroll
                for (int g = 0; g < 4; g++) {
                    float4 wv = *(const float4*)&wl[g][jjA][kbase + k];
                    acc[g][0] = fmaf(wv.x, h0.x, fmaf(wv.y, h0.y, fmaf(wv.z, h0.z, fmaf(wv.w, h0.w, acc[g][0]))));
                    acc[g][1] = fmaf(wv.x, h1.x, fmaf(wv.y, h1.y, fmaf(wv.z, h1.z, fmaf(wv.w, h1.w, acc[g][1]))));
                }
            }
#pragma unroll
            for (int g = 0; g < 4; g++) {
                red[ksA][g][jjA][bgA * 2 + 0] = acc[g][0];
                red[ksA][g][jjA][bgA * 2 + 1] = acc[g][1];
            }
        }
        __syncthreads();
        // phase B: reduce, gates, state update
        if (tid < 128) {
            const int tpre = dir ? (255 - t) : t;
            const float* prow = pre + ((long)(b0 + bbB) * 256 + tpre) * 1024 + j0 + jjB;
            float gate[4];
#pragma unroll
            for (int g = 0; g < 4; g++)
                gate[g] = red[0][g][jjB][bbB] + red[1][g][jjB][bbB]
                        + red[2][g][jjB][bbB] + red[3][g][jjB][bbB] + prow[g * 256];
            float ig = 1.f / (1.f + __expf(-gate[0]));
            float fg = 1.f / (1.f + __expf(-gate[1]));
            float gg = tanhf(gate[2]);
            float og = 1.f / (1.f + __expf(-gate[3]));
            creg = fg * creg + ig * gg;
            float h = og * tanhf(creg);
            hbuf[(((long)(1 - par) * 2 + dir) * 64 + b0 + bbB) * 256 + j0 + jjB] = h;
            out[((long)(b0 + bbB) * 256 + tpre) * 512 + dir * 256 + j0 + jjB] = h;
        }
        GRID_BAR();
    }
#undef GRID_BAR
}

// ---------------- CRF NLL + Viterbi ----------------
// blocks 0..63: NLL for batch b ; blocks 64..127: Viterbi for batch b
__global__ __launch_bounds__(128) void crf_k(
    const float* __restrict__ emit, const float* __restrict__ trans,
    const int* __restrict__ labels, float* __restrict__ outv)
{
    const int b = blockIdx.x & 63;
    const bool vit = blockIdx.x >= 64;
    const int tid = threadIdx.x;
    __shared__ float Tl[NG * NG];
    __shared__ float bufA[NG], bufB[NG];
    __shared__ unsigned char bp[256][NG];
    __shared__ float redv[128];
    for (int i = tid; i < NG * NG; i += 128) Tl[i] = trans[i];
    __syncthreads();
    const float* eb = emit + (long)b * 256 * NG;

    if (!vit) {
        if (tid < NG) bufA[tid] = Tl[START_ * NG + tid] + eb[tid];
        __syncthreads();
        for (int t = 1; t < 256; t++) {
            float* prev = (t & 1) ? bufA : bufB;
            float* cur  = (t & 1) ? bufB : bufA;
            if (tid < NG) {
                float m = -1e30f;
                for (int i = 0; i < NG; i++) m = fmaxf(m, prev[i] + Tl[i * NG + tid]);
                float s = 0.f;
                for (int i = 0; i < NG; i++) s += __expf(prev[i] + Tl[i * NG + tid] - m);
                cur[tid] = m + __logf(s) + eb[t * NG + tid];
            }
            __syncthreads();
        }
        // gold (parallel partial sums)
        const int* lab = labels + b * 256;
        float g = 0.f;
        for (int t = tid; t < 256; t += 128) g += eb[t * NG + lab[t]];
        for (int t = tid; t < 255; t += 128) g += Tl[lab[t] * NG + lab[t + 1]];
        redv[tid] = g;
        __syncthreads();
        if (tid == 0) {
            float* fin = bufB;  // t=255 wrote bufB
            float m = -1e30f;
            for (int j = 0; j < NG; j++) m = fmaxf(m, fin[j] + Tl[j * NG + STOP_]);
            float s = 0.f;
            for (int j = 0; j < NG; j++) s += __expf(fin[j] + Tl[j * NG + STOP_] - m);
            float logZ = m + __logf(s);
            float gold = Tl[START_ * NG + lab[0]] + Tl[lab[255] * NG + STOP_];
            for (int i = 0; i < 128; i++) gold += redv[i];
            atomicAdd(outv, logZ - gold);
        }
    } else {
        if (tid < NG) bufA[tid] = Tl[START_ * NG + tid] + eb[tid];
        __syncthreads();
        for (int t = 1; t < 256; t++) {
            float* prev = (t & 1) ? bufA : bufB;
            float* cur  = (t & 1) ? bufB : bufA;
            if (tid < NG) {
                float m = -1e30f; int arg = 0;
                for (int i = 0; i < NG; i++) {
                    float v = prev[i] + Tl[i * NG + tid];
                    if (v > m) { m = v; arg = i; }   // strict > keeps FIRST argmax
                }
                bp[t][tid] = (unsigned char)arg;
                cur[tid] = m + eb[t * NG + tid];
            }
            __syncthreads();
        }
        if (tid == 0) {
            float* fin = bufB;
            float m = -1e30f; int tag = 0;
            for (int j = 0; j < NG; j++) {
                float v = fin[j] + Tl[j * NG + STOP_];
                if (v > m) { m = v; tag = j; }
            }
            float* od = outv + 1 + (long)b * 256;
            od[255] = (float)tag;
            for (int t = 255; t >= 1; t--) { tag = bp[t][tag]; od[t - 1] = (float)tag; }
        }
    }
}

// ---------------- host ----------------
extern "C" void kernel_launch(void* const* d_in, const int* in_sizes, int n_in,
                              void* d_out, int out_size, void* d_ws, size_t ws_size,
                              hipStream_t stream)
{
    const int*   batch_word    = (const int*)d_in[0];
    const int*   batch_intents = (const int*)d_in[1];
    const int*   batch_char    = (const int*)d_in[3];
    const int*   batch_lexi    = (const int*)d_in[6];
    const int*   batch_label   = (const int*)d_in[7];
    const float* char_emb      = (const float*)d_in[8];
    const float* word_emb      = (const float*)d_in[9];
    const float* lexi_emb      = (const float*)d_in[10];
    const float* intent_emb    = (const float*)d_in[11];
    const float* conv_w        = (const float*)d_in[12];
    const float* conv_b        = (const float*)d_in[13];
    const float* w_ih          = (const float*)d_in[14];
    const float* w_hh          = (const float*)d_in[15];
    const float* b_ih          = (const float*)d_in[16];
    const float* b_hh          = (const float*)d_in[17];
    const float* proj_w        = (const float*)d_in[18];
    const float* proj_b        = (const float*)d_in[19];
    const float* trans         = (const float*)d_in[20];
    float* out = (float*)d_out;
    float* ws  = (float*)d_ws;

    float* ce_pad = ws + OFF_CEPAD;
    float* q      = ws + OFF_Q;
    float* kv     = ws + OFF_KV;
    float* preF   = ws + OFF_PREF;
    float* scores = ws + OFF_SC;
    float* x      = ws + OFF_X;
    float* y      = ws + OFF_Y;
    float* preB   = ws + OFF_PREB;
    float* emit   = ws + OFF_EMIT;
    float* w2     = ws + OFF_W2;
    float* hbuf   = ws + OFF_HBUF;
    int*   bar    = (int*)(ws + OFF_BAR);

    embed_k<<<BT, 128, 0, stream>>>(batch_word, batch_intents, batch_char, batch_lexi,
                                    word_emb, lexi_emb, intent_emb, char_emb, kv, q, ce_pad);
    prep_k<<<(384 * 384 + 255) / 256, 256, 0, stream>>>(conv_w, w2, out, bar);

    // char CNN as GEMM (A gathered from ce_pad), C into q cols 0..383
    gemm_k<<<dim3(128, 3, 1), 256, 0, stream>>>(ce_pad, 0, 0L, 1,
                                                w2, 384, 0L, 1,
                                                q, 512, 0L, 384, 384,
                                                conv_b, nullptr, 1.f);
    // attention scores = q @ kv^T / TEMP  (batched)
    gemm_k<<<dim3(2, 2, NB), 256, 0, stream>>>(q, 512, 131072L, 0,
                                               kv, 512, 131072L, 1,
                                               scores, 256, 65536L, 256, 512,
                                               nullptr, nullptr, INV_TEMP);
    softmax_k<<<4096, 256, 0, stream>>>(scores);
    // x = softmax(scores) @ kv
    gemm_k<<<dim3(2, 4, NB), 256, 0, stream>>>(scores, 256, 65536L, 0,
                                               kv, 512, 131072L, 0,
                                               x, 512, 131072L, 512, 256,
                                               nullptr, nullptr, 1.f);

    for (int l = 0; l < 2; l++) {
        const float* xin = l ? y : x;
        float* xout = l ? x : y;
        for (int d = 0; d < 2; d++) {
            gemm_k<<<dim3(128, 8, 1), 256, 0, stream>>>(
                xin, 512, 0L, 0,
                w_ih + (long)(l * 2 + d) * 1024 * 512, 512, 0L, 1,
                d ? preB : preF, 1024, 0L, 1024, 512,
                b_ih + (l * 2 + d) * 1024, b_hh + (l * 2 + d) * 1024, 1.f);
        }
        lstm_k<<<256, 256, 0, stream>>>(preF, preB,
                                        w_hh + (long)l * 2 * 1024 * 256,
                                        hbuf, xout, bar, l * 257);
    }

    // emissions
    gemm_k<<<dim3(128, 1, 1), 256, 0, stream>>>(x, 512, 0L, 0,
                                                proj_w, 512, 0L, 1,
                                                emit, NG, 0L, NG, 512,
                                                proj_b, nullptr, 1.f);
    // CRF NLL (blocks 0..63) + Viterbi (blocks 64..127)
    crf_k<<<128, 128, 0, stream>>>(emit, trans, batch_label, out);
}

// Round 2
// 9003.029 us; speedup vs baseline: 1.3616x; 1.3616x over previous
//
#include <hip/hip_runtime.h>

// ---------------- problem constants ----------------
#define NB 64
#define NT 256
#define BT 16384          // NB*NT
#define NG 66
#define START_ 64
#define STOP_ 65
#define INV_TEMP 0.08838834764831845f  // 1/sqrt(128)

// ---------------- workspace layout (float offsets) ----------------
// ce_pad [64][258][128]      @ 0          (2,113,536)   dead after conv
// q      [BT][512]           @ 2,113,536  (8,388,608)   dead after scores
// kv     [BT][512]           @ 10,502,144 (8,388,608)   dead after x-GEMM
// preF   [BT][1024]          @ 0          (16,777,216)  aliases ce_pad+q+kv-head (all dead)
// scores [64][256][256]      @ 18,890,752 (4,194,304)
// x      [BT][512]           @ 23,085,056 (8,388,608)
// y      [BT][512]           @ 31,473,664 (8,388,608)
// preB   [BT][1024]          @ 39,862,272 (16,777,216)
// emit   [BT][66]            @ 56,639,488 (1,081,344)   ALIASES wt (wt dead before proj)
// wt     [2][2][256][1024]   @ 56,639,488 (1,048,576)   transposed w_hh, dead after lstm
// w2     [384][384]          @ 57,720,832 (147,456)
#define OFF_CEPAD 0L
#define OFF_Q     2113536L
#define OFF_KV    10502144L
#define OFF_PREF  0L
#define OFF_SC    18890752L
#define OFF_X     23085056L
#define OFF_Y     31473664L
#define OFF_PREB  39862272L
#define OFF_EMIT  56639488L
#define OFF_WT    56639488L
#define OFF_W2    57720832L

// ---------------- embedding / gather ----------------
__global__ __launch_bounds__(128) void embed_k(
    const int* __restrict__ word, const int* __restrict__ intents,
    const int* __restrict__ chars, const int* __restrict__ lexi,
    const float* __restrict__ word_emb, const float* __restrict__ lexi_emb,
    const float* __restrict__ intent_emb, const float* __restrict__ char_emb,
    float* __restrict__ kv, float* __restrict__ q, float* __restrict__ ce_pad)
{
    int bt = blockIdx.x;
    int b = bt >> 8, t = bt & 255;
    int tid = threadIdx.x;
    const float4* wrow = (const float4*)(word_emb + (long)word[bt] * 256);
    const float4* lrow = (const float4*)(lexi_emb + (long)lexi[bt] * 128);
    const float4* irow = (const float4*)(intent_emb + (long)intents[b] * 128);
    const float4* crow = (const float4*)(char_emb + (long)chars[bt] * 128);
    float4* kvrow = (float4*)(kv + (long)bt * 512);
    float4* qrow  = (float4*)(q  + (long)bt * 512);
    float4* cerow = (float4*)(ce_pad + ((long)b * 258 + t + 1) * 128);
    if (tid < 64)       kvrow[tid] = wrow[tid];
    else if (tid < 96)  kvrow[tid] = lrow[tid - 64];
    else { float4 v = irow[tid - 96]; kvrow[tid] = v; qrow[tid] = v; }
    if (tid < 32) cerow[tid] = crow[tid];
    if (t == 0) {
        float4 z = make_float4(0.f, 0.f, 0.f, 0.f);
        if (tid < 32)      ((float4*)(ce_pad + (long)b * 258 * 128))[tid] = z;
        else if (tid < 64) ((float4*)(ce_pad + ((long)b * 258 + 257) * 128))[tid - 32] = z;
    }
}

// repack conv_w (O,C,K) -> w2[o][k*128+c]; zero loss slot
__global__ __launch_bounds__(256) void prep_k(const float* __restrict__ conv_w,
                                              float* __restrict__ w2,
                                              float* __restrict__ out0)
{
    int idx = blockIdx.x * 256 + threadIdx.x;
    if (idx == 0) out0[0] = 0.f;
    if (idx < 384 * 384) {
        int o = idx / 384, r = idx % 384;
        int k = r >> 7, c = r & 127;
        w2[o * 384 + r] = conv_w[o * 384 + c * 3 + k];
    }
}

// transpose w_hh [4][1024 row][256 k] -> wt [4][256 k][1024 row] via LDS tiles
__global__ __launch_bounds__(256) void wt_k(const float* __restrict__ whh,
                                            float* __restrict__ wt)
{
    // grid = 4 ld * 16 rowtiles * 4 ktiles = 256 blocks
    int bid = blockIdx.x;
    int ld = bid >> 6;
    int rt = (bid >> 2) & 15;
    int kt = bid & 3;
    const float* src = whh + ((long)ld * 1024 + rt * 64) * 256 + kt * 64;
    float* dst = wt + (long)ld * 262144 + (long)kt * 64 * 1024 + rt * 64;
    __shared__ float tile[64][65];
    int c = threadIdx.x & 63, r0 = threadIdx.x >> 6;  // r0 in 0..3
#pragma unroll
    for (int i = 0; i < 16; i++)
        tile[r0 + i * 4][c] = src[(long)(r0 + i * 4) * 256 + c];
    __syncthreads();
#pragma unroll
    for (int i = 0; i < 16; i++)
        dst[(long)(r0 + i * 4) * 1024 + c] = tile[c][r0 + i * 4];
}

// ---------------- generic fp32 GEMM: C = alpha*A@op(B) + bias0 + bias1 ----------------
// tile 128x128, K-step 16, 256 threads, 8x8 micro-tile (split 4+4 at stride 64)
#define GT 128
#define GK 16
__global__ __launch_bounds__(256) void gemm_k(
    const float* __restrict__ A, int lda, long sA, int amode,
    const float* __restrict__ Bm, int ldb, long sB, int transB,
    float* __restrict__ C, int ldc, long sC,
    int N, int K,
    const float* __restrict__ bias0, const float* __restrict__ bias1, float alpha)
{
    A  += (long)blockIdx.z * sA;
    Bm += (long)blockIdx.z * sB;
    C  += (long)blockIdx.z * sC;
    const int m0 = blockIdx.x * GT, n0 = blockIdx.y * GT;
    __shared__ float As[GK][GT + 4];
    __shared__ float Bs[GK][GT + 4];
    const int tid = threadIdx.x;
    const int tm = (tid & 15) * 4;
    const int tn = (tid >> 4) * 4;
    float acc[8][8];
#pragma unroll
    for (int i = 0; i < 8; i++)
#pragma unroll
        for (int j = 0; j < 8; j++) acc[i][j] = 0.f;
    const int lr = tid >> 2;
    const int lk = (tid & 3) * 4;

    for (int k0 = 0; k0 < K; k0 += GK) {
#pragma unroll
        for (int p = 0; p < 2; p++) {
            int m = m0 + p * 64 + lr;
            long rowoff = (amode == 0) ? ((long)m * lda)
                                       : ((long)m * 128 + (long)(m >> 8) * 256);
            float4 v = *(const float4*)(A + rowoff + k0 + lk);
            As[lk + 0][p * 64 + lr] = v.x;
            As[lk + 1][p * 64 + lr] = v.y;
            As[lk + 2][p * 64 + lr] = v.z;
            As[lk + 3][p * 64 + lr] = v.w;
        }
        if (transB) {
#pragma unroll
            for (int p = 0; p < 2; p++) {
                int n = n0 + p * 64 + lr;
                float4 v = make_float4(0.f, 0.f, 0.f, 0.f);
                if (n < N) v = *(const float4*)(Bm + (long)n * ldb + k0 + lk);
                Bs[lk + 0][p * 64 + lr] = v.x;
                Bs[lk + 1][p * 64 + lr] = v.y;
                Bs[lk + 2][p * 64 + lr] = v.z;
                Bs[lk + 3][p * 64 + lr] = v.w;
            }
        } else {
            int kk = tid >> 4;
            int nn = (tid & 15) * 8;
            float4 v0 = *(const float4*)(Bm + (long)(k0 + kk) * ldb + n0 + nn);
            float4 v1 = *(const float4*)(Bm + (long)(k0 + kk) * ldb + n0 + nn + 4);
            *(float4*)&Bs[kk][nn] = v0;
            *(float4*)&Bs[kk][nn + 4] = v1;
        }
        __syncthreads();
#pragma unroll
        for (int kk = 0; kk < GK; kk++) {
            float4 a0 = *(const float4*)&As[kk][tm];
            float4 a1 = *(const float4*)&As[kk][tm + 64];
            float4 b0 = *(const float4*)&Bs[kk][tn];
            float4 b1 = *(const float4*)&Bs[kk][tn + 64];
            float av[8] = {a0.x, a0.y, a0.z, a0.w, a1.x, a1.y, a1.z, a1.w};
            float bv[8] = {b0.x, b0.y, b0.z, b0.w, b1.x, b1.y, b1.z, b1.w};
#pragma unroll
            for (int i = 0; i < 8; i++)
#pragma unroll
                for (int j = 0; j < 8; j++)
                    acc[i][j] = fmaf(av[i], bv[j], acc[i][j]);
        }
        __syncthreads();
    }
#pragma unroll
    for (int i = 0; i < 8; i++) {
        int m = m0 + ((i < 4) ? (tm + i) : (tm + 64 + i - 4));
#pragma unroll
        for (int j = 0; j < 8; j++) {
            int n = n0 + ((j < 4) ? (tn + j) : (tn + 64 + j - 4));
            if (n < N) {
                float v = alpha * acc[i][j];
                if (bias0) v += bias0[n];
                if (bias1) v += bias1[n];
                C[(long)m * ldc + n] = v;
            }
        }
    }
}

// ---------------- row softmax over 256 cols ----------------
__global__ __launch_bounds__(256) void softmax_k(float* __restrict__ scores)
{
    int row = blockIdx.x * 4 + (threadIdx.x >> 6);
    int lane = threadIdx.x & 63;
    float4* p = (float4*)(scores + (long)row * 256);
    float4 v = p[lane];
    float m = fmaxf(fmaxf(v.x, v.y), fmaxf(v.z, v.w));
#pragma unroll
    for (int off = 32; off; off >>= 1) m = fmaxf(m, __shfl_xor(m, off));
    v.x = __expf(v.x - m); v.y = __expf(v.y - m);
    v.z = __expf(v.z - m); v.w = __expf(v.w - m);
    float s = v.x + v.y + v.z + v.w;
#pragma unroll
    for (int off = 32; off; off >>= 1) s += __shfl_xor(s, off);
    float inv = 1.f / s;
    v.x *= inv; v.y *= inv; v.z *= inv; v.w *= inv;
    p[lane] = v;
}

// ---------------- BiLSTM recurrence: batch-parallel, NO grid sync ----------------
// 64 blocks = 2 dirs x 32 batch-pairs; 256 threads; h & gates in LDS; c in regs.
// Weights streamed from L2 each step in transposed layout wt[dir][k][1024 rows]:
// at fixed k, lane loads float4 = 4 consecutive gate-rows (fully coalesced, 1KB/wave),
// h[k] is an all-lanes-same-address LDS broadcast (free).
__global__ __launch_bounds__(256) void lstm_k(
    const float* __restrict__ preF, const float* __restrict__ preB,
    const float* __restrict__ wt,   // layer base: [2 dir][256 k][1024 row]
    float* __restrict__ out)        // [BT][512], cols dir*256+j
{
    const int dir = blockIdx.x & 1;
    const int b0  = (blockIdx.x >> 1) * 2;
    const int tid = threadIdx.x;
    const int r0  = tid * 4;            // 4 consecutive gate-rows per thread
    __shared__ float hl[2][256];
    __shared__ float gl[2][1024];
    const float* pre = dir ? preB : preF;
    const float* W = wt + (long)dir * 262144;
    float c0 = 0.f, c1 = 0.f;
    hl[0][tid] = 0.f; hl[1][tid] = 0.f;
    __syncthreads();

    for (int t = 0; t < 256; t++) {
        const int tpre = dir ? (255 - t) : t;
        // ---- gates phase: acc[row][batch] = pre + Whh @ h ----
        float4 p0 = *(const float4*)(pre + ((long)b0 * 256 + tpre) * 1024 + r0);
        float4 p1 = *(const float4*)(pre + ((long)(b0 + 1) * 256 + tpre) * 1024 + r0);
        float acc[4][2] = {{p0.x, p1.x}, {p0.y, p1.y}, {p0.z, p1.z}, {p0.w, p1.w}};
        if (t > 0) {
#define FMA4(WV, HB0, HB1)                                                       \
    acc[0][0] = fmaf(WV.x, HB0, acc[0][0]); acc[0][1] = fmaf(WV.x, HB1, acc[0][1]); \
    acc[1][0] = fmaf(WV.y, HB0, acc[1][0]); acc[1][1] = fmaf(WV.y, HB1, acc[1][1]); \
    acc[2][0] = fmaf(WV.z, HB0, acc[2][0]); acc[2][1] = fmaf(WV.z, HB1, acc[2][1]); \
    acc[3][0] = fmaf(WV.w, HB0, acc[3][0]); acc[3][1] = fmaf(WV.w, HB1, acc[3][1]);
#pragma unroll 4
            for (int k = 0; k < 256; k += 4) {
                float4 h0 = *(const float4*)&hl[0][k];
                float4 h1 = *(const float4*)&hl[1][k];
                const float* wp = W + (long)k * 1024 + r0;
                float4 w0 = *(const float4*)(wp);
                float4 w1 = *(const float4*)(wp + 1024);
                float4 w2v = *(const float4*)(wp + 2048);
                float4 w3v = *(const float4*)(wp + 3072);
                FMA4(w0, h0.x, h1.x);
                FMA4(w1, h0.y, h1.y);
                FMA4(w2v, h0.z, h1.z);
                FMA4(w3v, h0.w, h1.w);
            }
#undef FMA4
        }
        *(float4*)&gl[0][r0] = make_float4(acc[0][0], acc[1][0], acc[2][0], acc[3][0]);
        *(float4*)&gl[1][r0] = make_float4(acc[0][1], acc[1][1], acc[2][1], acc[3][1]);
        __syncthreads();
        // ---- update phase: thread tid owns h-dim j=tid for both batches ----
        {
            const int j = tid;
            float i0 = gl[0][j], f0 = gl[0][256 + j], g0 = gl[0][512 + j], o0 = gl[0][768 + j];
            float i1 = gl[1][j], f1 = gl[1][256 + j], g1 = gl[1][512 + j], o1 = gl[1][768 + j];
            float si0 = 1.f / (1.f + __expf(-i0)), sf0 = 1.f / (1.f + __expf(-f0));
            float so0 = 1.f / (1.f + __expf(-o0));
            float si1 = 1.f / (1.f + __expf(-i1)), sf1 = 1.f / (1.f + __expf(-f1));
            float so1 = 1.f / (1.f + __expf(-o1));
            c0 = sf0 * c0 + si0 * tanhf(g0);
            c1 = sf1 * c1 + si1 * tanhf(g1);
            float h0v = so0 * tanhf(c0);
            float h1v = so1 * tanhf(c1);
            hl[0][j] = h0v;
            hl[1][j] = h1v;
            out[((long)b0 * 256 + tpre) * 512 + dir * 256 + j] = h0v;
            out[((long)(b0 + 1) * 256 + tpre) * 512 + dir * 256 + j] = h1v;
        }
        __syncthreads();
    }
}

// ---------------- CRF NLL + Viterbi ----------------
// blocks 0..63: NLL for batch b ; blocks 64..127: Viterbi for batch b
__global__ __launch_bounds__(128) void crf_k(
    const float* __restrict__ emit, const float* __restrict__ trans,
    const int* __restrict__ labels, float* __restrict__ outv)
{
    const int b = blockIdx.x & 63;
    const bool vit = blockIdx.x >= 64;
    const int tid = threadIdx.x;
    __shared__ float Tl[NG * NG];
    __shared__ float bufA[NG], bufB[NG];
    __shared__ unsigned char bp[256][NG];
    __shared__ float redv[128];
    for (int i = tid; i < NG * NG; i += 128) Tl[i] = trans[i];
    __syncthreads();
    const float* eb = emit + (long)b * 256 * NG;

    if (!vit) {
        if (tid < NG) bufA[tid] = Tl[START_ * NG + tid] + eb[tid];
        __syncthreads();
        for (int t = 1; t < 256; t++) {
            float* prev = (t & 1) ? bufA : bufB;
            float* cur  = (t & 1) ? bufB : bufA;
            if (tid < NG) {
                float m = -1e30f;
                for (int i = 0; i < NG; i++) m = fmaxf(m, prev[i] + Tl[i * NG + tid]);
                float s = 0.f;
                for (int i = 0; i < NG; i++) s += __expf(prev[i] + Tl[i * NG + tid] - m);
                cur[tid] = m + __logf(s) + eb[t * NG + tid];
            }
            __syncthreads();
        }
        const int* lab = labels + b * 256;
        float g = 0.f;
        for (int t = tid; t < 256; t += 128) g += eb[t * NG + lab[t]];
        for (int t = tid; t < 255; t += 128) g += Tl[lab[t] * NG + lab[t + 1]];
        redv[tid] = g;
        __syncthreads();
        if (tid == 0) {
            float* fin = bufB;
            float m = -1e30f;
            for (int j = 0; j < NG; j++) m = fmaxf(m, fin[j] + Tl[j * NG + STOP_]);
            float s = 0.f;
            for (int j = 0; j < NG; j++) s += __expf(fin[j] + Tl[j * NG + STOP_] - m);
            float logZ = m + __logf(s);
            float gold = Tl[START_ * NG + lab[0]] + Tl[lab[255] * NG + STOP_];
            for (int i = 0; i < 128; i++) gold += redv[i];
            atomicAdd(outv, logZ - gold);
        }
    } else {
        if (tid < NG) bufA[tid] = Tl[START_ * NG + tid] + eb[tid];
        __syncthreads();
        for (int t = 1; t < 256; t++) {
            float* prev = (t & 1) ? bufA : bufB;
            float* cur  = (t & 1) ? bufB : bufA;
            if (tid < NG) {
                float m = -1e30f; int arg = 0;
                for (int i = 0; i < NG; i++) {
                    float v = prev[i] + Tl[i * NG + tid];
                    if (v > m) { m = v; arg = i; }   // strict > keeps FIRST argmax
                }
                bp[t][tid] = (unsigned char)arg;
                cur[tid] = m + eb[t * NG + tid];
            }
            __syncthreads();
        }
        if (tid == 0) {
            float* fin = bufB;
            float m = -1e30f; int tag = 0;
            for (int j = 0; j < NG; j++) {
                float v = fin[j] + Tl[j * NG + STOP_];
                if (v > m) { m = v; tag = j; }
            }
            float* od = outv + 1 + (long)b * 256;
            od[255] = (float)tag;
            for (int t = 255; t >= 1; t--) { tag = bp[t][tag]; od[t - 1] = (float)tag; }
        }
    }
}

// ---------------- host ----------------
extern "C" void kernel_launch(void* const* d_in, const int* in_sizes, int n_in,
                              void* d_out, int out_size, void* d_ws, size_t ws_size,
                              hipStream_t stream)
{
    const int*   batch_word    = (const int*)d_in[0];
    const int*   batch_intents = (const int*)d_in[1];
    const int*   batch_char    = (const int*)d_in[3];
    const int*   batch_lexi    = (const int*)d_in[6];
    const int*   batch_label   = (const int*)d_in[7];
    const float* char_emb      = (const float*)d_in[8];
    const float* word_emb      = (const float*)d_in[9];
    const float* lexi_emb      = (const float*)d_in[10];
    const float* intent_emb    = (const float*)d_in[11];
    const float* conv_w        = (const float*)d_in[12];
    const float* conv_b        = (const float*)d_in[13];
    const float* w_ih          = (const float*)d_in[14];
    const float* w_hh          = (const float*)d_in[15];
    const float* b_ih          = (const float*)d_in[16];
    const float* b_hh          = (const float*)d_in[17];
    const float* proj_w        = (const float*)d_in[18];
    const float* proj_b        = (const float*)d_in[19];
    const float* trans         = (const float*)d_in[20];
    float* out = (float*)d_out;
    float* ws  = (float*)d_ws;

    float* ce_pad = ws + OFF_CEPAD;
    float* q      = ws + OFF_Q;
    float* kv     = ws + OFF_KV;
    float* preF   = ws + OFF_PREF;
    float* scores = ws + OFF_SC;
    float* x      = ws + OFF_X;
    float* y      = ws + OFF_Y;
    float* preB   = ws + OFF_PREB;
    float* emit   = ws + OFF_EMIT;
    float* wt     = ws + OFF_WT;
    float* w2     = ws + OFF_W2;

    embed_k<<<BT, 128, 0, stream>>>(batch_word, batch_intents, batch_char, batch_lexi,
                                    word_emb, lexi_emb, intent_emb, char_emb, kv, q, ce_pad);
    prep_k<<<(384 * 384 + 255) / 256, 256, 0, stream>>>(conv_w, w2, out);
    wt_k<<<256, 256, 0, stream>>>(w_hh, wt);

    // char CNN as GEMM (A gathered from ce_pad), C into q cols 0..383
    gemm_k<<<dim3(128, 3, 1), 256, 0, stream>>>(ce_pad, 0, 0L, 1,
                                                w2, 384, 0L, 1,
                                                q, 512, 0L, 384, 384,
                                                conv_b, nullptr, 1.f);
    // attention scores = q @ kv^T / TEMP  (batched)
    gemm_k<<<dim3(2, 2, NB), 256, 0, stream>>>(q, 512, 131072L, 0,
                                               kv, 512, 131072L, 1,
                                               scores, 256, 65536L, 256, 512,
                                               nullptr, nullptr, INV_TEMP);
    softmax_k<<<4096, 256, 0, stream>>>(scores);
    // x = softmax(scores) @ kv
    gemm_k<<<dim3(2, 4, NB), 256, 0, stream>>>(scores, 256, 65536L, 0,
                                               kv, 512, 131072L, 0,
                                               x, 512, 131072L, 512, 256,
                                               nullptr, nullptr, 1.f);

    for (int l = 0; l < 2; l++) {
        const float* xin = l ? y : x;
        float* xout = l ? x : y;
        for (int d = 0; d < 2; d++) {
            gemm_k<<<dim3(128, 8, 1), 256, 0, stream>>>(
                xin, 512, 0L, 0,
                w_ih + (long)(l * 2 + d) * 1024 * 512, 512, 0L, 1,
                d ? preB : preF, 1024, 0L, 1024, 512,
                b_ih + (l * 2 + d) * 1024, b_hh + (l * 2 + d) * 1024, 1.f);
        }
        lstm_k<<<64, 256, 0, stream>>>(preF, preB, wt + (long)l * 2 * 262144, xout);
    }

    // emissions (overwrites wt region — wt is dead after last lstm)
    gemm_k<<<dim3(128, 1, 1), 256, 0, stream>>>(x, 512, 0L, 0,
                                                proj_w, 512, 0L, 1,
                                                emit, NG, 0L, NG, 512,
                                                proj_b, nullptr, 1.f);
    // CRF NLL (blocks 0..63) + Viterbi (blocks 64..127)
    crf_k<<<128, 128, 0, stream>>>(emit, trans, batch_label, out);
}

// Round 3
// 6790.453 us; speedup vs baseline: 1.8052x; 1.3258x over previous
//
#include <hip/hip_runtime.h>

// ---------------- problem constants ----------------
#define NB 64
#define NT 256
#define BT 16384          // NB*NT
#define NG 66
#define START_ 64
#define STOP_ 65
#define INV_TEMP 0.08838834764831845f  // 1/sqrt(128)

typedef _Float16 half2_t __attribute__((ext_vector_type(2)));
union H2U { unsigned u; half2_t h; };

// ---------------- workspace layout (float offsets) ----------------
// ce_pad [64][258][128]      @ 0          (2,113,536)   dead after conv
// q      [BT][512]           @ 2,113,536  (8,388,608)   dead after scores
// kv     [BT][512]           @ 10,502,144 (8,388,608)   dead after x-GEMM
// preF   [BT][1024]          @ 0          (16,777,216)  aliases ce_pad+q+kv-head (all dead)
// scores [64][256][256]      @ 18,890,752 (4,194,304)
// x      [BT][512]           @ 23,085,056 (8,388,608)
// y      [BT][512]           @ 31,473,664 (8,388,608)
// preB   [BT][1024]          @ 39,862,272 (16,777,216)
// emit   [BT][66]            @ 56,639,488 (1,081,344)   ALIASES wt (wt dead before proj)
// wt fp16 [4 ld][128 kp][1024] @ 56,639,488 (524,288 f) transposed+packed w_hh
// w2     [384][384]          @ 57,720,832 (147,456)
#define OFF_CEPAD 0L
#define OFF_Q     2113536L
#define OFF_KV    10502144L
#define OFF_PREF  0L
#define OFF_SC    18890752L
#define OFF_X     23085056L
#define OFF_Y     31473664L
#define OFF_PREB  39862272L
#define OFF_EMIT  56639488L
#define OFF_WT    56639488L
#define OFF_W2    57720832L

// ---------------- embedding / gather ----------------
__global__ __launch_bounds__(128) void embed_k(
    const int* __restrict__ word, const int* __restrict__ intents,
    const int* __restrict__ chars, const int* __restrict__ lexi,
    const float* __restrict__ word_emb, const float* __restrict__ lexi_emb,
    const float* __restrict__ intent_emb, const float* __restrict__ char_emb,
    float* __restrict__ kv, float* __restrict__ q, float* __restrict__ ce_pad)
{
    int bt = blockIdx.x;
    int b = bt >> 8, t = bt & 255;
    int tid = threadIdx.x;
    const float4* wrow = (const float4*)(word_emb + (long)word[bt] * 256);
    const float4* lrow = (const float4*)(lexi_emb + (long)lexi[bt] * 128);
    const float4* irow = (const float4*)(intent_emb + (long)intents[b] * 128);
    const float4* crow = (const float4*)(char_emb + (long)chars[bt] * 128);
    float4* kvrow = (float4*)(kv + (long)bt * 512);
    float4* qrow  = (float4*)(q  + (long)bt * 512);
    float4* cerow = (float4*)(ce_pad + ((long)b * 258 + t + 1) * 128);
    if (tid < 64)       kvrow[tid] = wrow[tid];
    else if (tid < 96)  kvrow[tid] = lrow[tid - 64];
    else { float4 v = irow[tid - 96]; kvrow[tid] = v; qrow[tid] = v; }
    if (tid < 32) cerow[tid] = crow[tid];
    if (t == 0) {
        float4 z = make_float4(0.f, 0.f, 0.f, 0.f);
        if (tid < 32)      ((float4*)(ce_pad + (long)b * 258 * 128))[tid] = z;
        else if (tid < 64) ((float4*)(ce_pad + ((long)b * 258 + 257) * 128))[tid - 32] = z;
    }
}

// repack conv_w (O,C,K) -> w2[o][k*128+c]; zero loss slot
__global__ __launch_bounds__(256) void prep_k(const float* __restrict__ conv_w,
                                              float* __restrict__ w2,
                                              float* __restrict__ out0)
{
    int idx = blockIdx.x * 256 + threadIdx.x;
    if (idx == 0) out0[0] = 0.f;
    if (idx < 384 * 384) {
        int o = idx / 384, r = idx % 384;
        int k = r >> 7, c = r & 127;
        w2[o * 384 + r] = conv_w[o * 384 + c * 3 + k];
    }
}

// transpose+pack w_hh fp32 [4 ld][1024 row][256 k] -> wt fp16 half2 [4 ld][128 kp][1024 row]
__global__ __launch_bounds__(256) void wt_k(const float* __restrict__ whh,
                                            unsigned* __restrict__ wt)
{
    // grid = 4 ld * 16 rowtiles * 4 ktiles = 256 blocks; tile 64 rows x 64 k
    int bid = blockIdx.x;
    int ld = bid >> 6;
    int rt = (bid >> 2) & 15;
    int kt = bid & 3;
    const float* src = whh + ((long)ld * 1024 + rt * 64) * 256 + kt * 64;
    __shared__ float tile[64][65];
    int c = threadIdx.x & 63, r0 = threadIdx.x >> 6;  // r0 in 0..3
#pragma unroll
    for (int i = 0; i < 16; i++)
        tile[r0 + i * 4][c] = src[(long)(r0 + i * 4) * 256 + c];
    __syncthreads();
    // write: row-local = c (coalesced), kpair-local = r0 + i*4 (32 kpairs)
    unsigned* dst = wt + (long)ld * 131072 + (long)(kt * 32) * 1024 + rt * 64;
#pragma unroll
    for (int i = 0; i < 8; i++) {
        int kl = r0 + i * 4;
        H2U u;
        u.h[0] = (_Float16)tile[c][2 * kl];
        u.h[1] = (_Float16)tile[c][2 * kl + 1];
        dst[(long)kl * 1024 + c] = u.u;
    }
}

// ---------------- generic fp32 GEMM: C = alpha*A@op(B) + bias0 + bias1 ----------------
#define GT 128
#define GK 16
__global__ __launch_bounds__(256) void gemm_k(
    const float* __restrict__ A, int lda, long sA, int amode,
    const float* __restrict__ Bm, int ldb, long sB, int transB,
    float* __restrict__ C, int ldc, long sC,
    int N, int K,
    const float* __restrict__ bias0, const float* __restrict__ bias1, float alpha)
{
    A  += (long)blockIdx.z * sA;
    Bm += (long)blockIdx.z * sB;
    C  += (long)blockIdx.z * sC;
    const int m0 = blockIdx.x * GT, n0 = blockIdx.y * GT;
    __shared__ float As[GK][GT + 4];
    __shared__ float Bs[GK][GT + 4];
    const int tid = threadIdx.x;
    const int tm = (tid & 15) * 4;
    const int tn = (tid >> 4) * 4;
    float acc[8][8];
#pragma unroll
    for (int i = 0; i < 8; i++)
#pragma unroll
        for (int j = 0; j < 8; j++) acc[i][j] = 0.f;
    const int lr = tid >> 2;
    const int lk = (tid & 3) * 4;

    for (int k0 = 0; k0 < K; k0 += GK) {
#pragma unroll
        for (int p = 0; p < 2; p++) {
            int m = m0 + p * 64 + lr;
            long rowoff = (amode == 0) ? ((long)m * lda)
                                       : ((long)m * 128 + (long)(m >> 8) * 256);
            float4 v = *(const float4*)(A + rowoff + k0 + lk);
            As[lk + 0][p * 64 + lr] = v.x;
            As[lk + 1][p * 64 + lr] = v.y;
            As[lk + 2][p * 64 + lr] = v.z;
            As[lk + 3][p * 64 + lr] = v.w;
        }
        if (transB) {
#pragma unroll
            for (int p = 0; p < 2; p++) {
                int n = n0 + p * 64 + lr;
                float4 v = make_float4(0.f, 0.f, 0.f, 0.f);
                if (n < N) v = *(const float4*)(Bm + (long)n * ldb + k0 + lk);
                Bs[lk + 0][p * 64 + lr] = v.x;
                Bs[lk + 1][p * 64 + lr] = v.y;
                Bs[lk + 2][p * 64 + lr] = v.z;
                Bs[lk + 3][p * 64 + lr] = v.w;
            }
        } else {
            int kk = tid >> 4;
            int nn = (tid & 15) * 8;
            float4 v0 = *(const float4*)(Bm + (long)(k0 + kk) * ldb + n0 + nn);
            float4 v1 = *(const float4*)(Bm + (long)(k0 + kk) * ldb + n0 + nn + 4);
            *(float4*)&Bs[kk][nn] = v0;
            *(float4*)&Bs[kk][nn + 4] = v1;
        }
        __syncthreads();
#pragma unroll
        for (int kk = 0; kk < GK; kk++) {
            float4 a0 = *(const float4*)&As[kk][tm];
            float4 a1 = *(const float4*)&As[kk][tm + 64];
            float4 b0 = *(const float4*)&Bs[kk][tn];
            float4 b1 = *(const float4*)&Bs[kk][tn + 64];
            float av[8] = {a0.x, a0.y, a0.z, a0.w, a1.x, a1.y, a1.z, a1.w};
            float bv[8] = {b0.x, b0.y, b0.z, b0.w, b1.x, b1.y, b1.z, b1.w};
#pragma unroll
            for (int i = 0; i < 8; i++)
#pragma unroll
                for (int j = 0; j < 8; j++)
                    acc[i][j] = fmaf(av[i], bv[j], acc[i][j]);
        }
        __syncthreads();
    }
#pragma unroll
    for (int i = 0; i < 8; i++) {
        int m = m0 + ((i < 4) ? (tm + i) : (tm + 64 + i - 4));
#pragma unroll
        for (int j = 0; j < 8; j++) {
            int n = n0 + ((j < 4) ? (tn + j) : (tn + 64 + j - 4));
            if (n < N) {
                float v = alpha * acc[i][j];
                if (bias0) v += bias0[n];
                if (bias1) v += bias1[n];
                C[(long)m * ldc + n] = v;
            }
        }
    }
}

// ---------------- row softmax over 256 cols ----------------
__global__ __launch_bounds__(256) void softmax_k(float* __restrict__ scores)
{
    int row = blockIdx.x * 4 + (threadIdx.x >> 6);
    int lane = threadIdx.x & 63;
    float4* p = (float4*)(scores + (long)row * 256);
    float4 v = p[lane];
    float m = fmaxf(fmaxf(v.x, v.y), fmaxf(v.z, v.w));
#pragma unroll
    for (int off = 32; off; off >>= 1) m = fmaxf(m, __shfl_xor(m, off));
    v.x = __expf(v.x - m); v.y = __expf(v.y - m);
    v.z = __expf(v.z - m); v.w = __expf(v.w - m);
    float s = v.x + v.y + v.z + v.w;
#pragma unroll
    for (int off = 32; off; off >>= 1) s += __shfl_xor(s, off);
    float inv = 1.f / s;
    v.x *= inv; v.y *= inv; v.z *= inv; v.w *= inv;
    p[lane] = v;
}

// ---------------- BiLSTM recurrence: fp16 weights + v_dot2_f32_f16 ----------------
// 64 blocks = 2 dirs x 32 batch-pairs; 512 threads (8 waves/CU).
// Thread owns 2 gate-rows x 2 batches. W streamed from L2 as half2[kpair][1024 rows]
// (0.5 MB/step/CU). h kept as packed half2 pairs in LDS (b64 broadcast per kpair).
// fp32 accumulate via v_dot2_f32_f16.
__global__ __launch_bounds__(512) void lstm_k(
    const float* __restrict__ preF, const float* __restrict__ preB,
    const unsigned* __restrict__ wtL,  // layer base: [2 dir][128 kp][1024 row] half2
    float* __restrict__ out)           // [BT][512], cols dir*256+j
{
    const int dir = blockIdx.x & 1;
    const int b0  = (blockIdx.x >> 1) * 2;
    const int tid = threadIdx.x;
    const int r0  = tid * 2;            // 2 consecutive gate-rows per thread
    __shared__ uint2 hlp[128];          // .x = batch0 half2(h[2k],h[2k+1]), .y = batch1
    __shared__ float hraw[2][256];
    __shared__ float gl[2][1024];
    const float* pre = dir ? preB : preF;
    const unsigned* W2 = wtL + (long)dir * 131072;
    float c0 = 0.f, c1 = 0.f;

    for (int t = 0; t < 256; t++) {
        const int tpre = dir ? (255 - t) : t;
        // ---- gates phase (all 512 threads): acc[row][batch] = pre + Whh @ h ----
        float2 p0 = *(const float2*)(pre + ((long)b0 * 256 + tpre) * 1024 + r0);
        float2 p1 = *(const float2*)(pre + ((long)(b0 + 1) * 256 + tpre) * 1024 + r0);
        float a00 = 0.f, a01 = 0.f, a10 = 0.f, a11 = 0.f;
        if (t > 0) {
#pragma unroll 8
            for (int kk = 0; kk < 128; kk++) {
                uint2 wv = *(const uint2*)(W2 + (long)kk * 1024 + r0);
                uint2 hv = hlp[kk];
                H2U w0; w0.u = wv.x;
                H2U w1; w1.u = wv.y;
                H2U h0; h0.u = hv.x;
                H2U h1; h1.u = hv.y;
                a00 = __builtin_amdgcn_fdot2(w0.h, h0.h, a00, false);
                a01 = __builtin_amdgcn_fdot2(w0.h, h1.h, a01, false);
                a10 = __builtin_amdgcn_fdot2(w1.h, h0.h, a10, false);
                a11 = __builtin_amdgcn_fdot2(w1.h, h1.h, a11, false);
            }
        }
        *(float2*)&gl[0][r0] = make_float2(a00 + p0.x, a10 + p0.y);
        *(float2*)&gl[1][r0] = make_float2(a01 + p1.x, a11 + p1.y);
        __syncthreads();
        // ---- update phase: tid<256, thread owns h-dim j for both batches ----
        if (tid < 256) {
            const int j = tid;
            float i0 = gl[0][j], f0 = gl[0][256 + j], g0 = gl[0][512 + j], o0 = gl[0][768 + j];
            float i1 = gl[1][j], f1 = gl[1][256 + j], g1 = gl[1][512 + j], o1 = gl[1][768 + j];
            float si0 = 1.f / (1.f + __expf(-i0)), sf0 = 1.f / (1.f + __expf(-f0));
            float so0 = 1.f / (1.f + __expf(-o0));
            float si1 = 1.f / (1.f + __expf(-i1)), sf1 = 1.f / (1.f + __expf(-f1));
            float so1 = 1.f / (1.f + __expf(-o1));
            c0 = sf0 * c0 + si0 * tanhf(g0);
            c1 = sf1 * c1 + si1 * tanhf(g1);
            float h0v = so0 * tanhf(c0);
            float h1v = so1 * tanhf(c1);
            hraw[0][j] = h0v;
            hraw[1][j] = h1v;
            out[((long)b0 * 256 + tpre) * 512 + dir * 256 + j] = h0v;
            out[((long)(b0 + 1) * 256 + tpre) * 512 + dir * 256 + j] = h1v;
        }
        __syncthreads();
        // ---- pack phase: tid<128 packs h into half2 pairs ----
        if (tid < 128) {
            H2U u0, u1;
            u0.h[0] = (_Float16)hraw[0][2 * tid];
            u0.h[1] = (_Float16)hraw[0][2 * tid + 1];
            u1.h[0] = (_Float16)hraw[1][2 * tid];
            u1.h[1] = (_Float16)hraw[1][2 * tid + 1];
            hlp[tid] = make_uint2(u0.u, u1.u);
        }
        __syncthreads();
    }
}

// ---------------- CRF NLL + Viterbi ----------------
__global__ __launch_bounds__(128) void crf_k(
    const float* __restrict__ emit, const float* __restrict__ trans,
    const int* __restrict__ labels, float* __restrict__ outv)
{
    const int b = blockIdx.x & 63;
    const bool vit = blockIdx.x >= 64;
    const int tid = threadIdx.x;
    __shared__ float Tl[NG * NG];
    __shared__ float bufA[NG], bufB[NG];
    __shared__ unsigned char bp[256][NG];
    __shared__ float redv[128];
    for (int i = tid; i < NG * NG; i += 128) Tl[i] = trans[i];
    __syncthreads();
    const float* eb = emit + (long)b * 256 * NG;

    if (!vit) {
        if (tid < NG) bufA[tid] = Tl[START_ * NG + tid] + eb[tid];
        __syncthreads();
        for (int t = 1; t < 256; t++) {
            float* prev = (t & 1) ? bufA : bufB;
            float* cur  = (t & 1) ? bufB : bufA;
            if (tid < NG) {
                float m = -1e30f;
                for (int i = 0; i < NG; i++) m = fmaxf(m, prev[i] + Tl[i * NG + tid]);
                float s = 0.f;
                for (int i = 0; i < NG; i++) s += __expf(prev[i] + Tl[i * NG + tid] - m);
                cur[tid] = m + __logf(s) + eb[t * NG + tid];
            }
            __syncthreads();
        }
        const int* lab = labels + b * 256;
        float g = 0.f;
        for (int t = tid; t < 256; t += 128) g += eb[t * NG + lab[t]];
        for (int t = tid; t < 255; t += 128) g += Tl[lab[t] * NG + lab[t + 1]];
        redv[tid] = g;
        __syncthreads();
        if (tid == 0) {
            float* fin = bufB;
            float m = -1e30f;
            for (int j = 0; j < NG; j++) m = fmaxf(m, fin[j] + Tl[j * NG + STOP_]);
            float s = 0.f;
            for (int j = 0; j < NG; j++) s += __expf(fin[j] + Tl[j * NG + STOP_] - m);
            float logZ = m + __logf(s);
            float gold = Tl[START_ * NG + lab[0]] + Tl[lab[255] * NG + STOP_];
            for (int i = 0; i < 128; i++) gold += redv[i];
            atomicAdd(outv, logZ - gold);
        }
    } else {
        if (tid < NG) bufA[tid] = Tl[START_ * NG + tid] + eb[tid];
        __syncthreads();
        for (int t = 1; t < 256; t++) {
            float* prev = (t & 1) ? bufA : bufB;
            float* cur  = (t & 1) ? bufB : bufA;
            if (tid < NG) {
                float m = -1e30f; int arg = 0;
                for (int i = 0; i < NG; i++) {
                    float v = prev[i] + Tl[i * NG + tid];
                    if (v > m) { m = v; arg = i; }   // strict > keeps FIRST argmax
                }
                bp[t][tid] = (unsigned char)arg;
                cur[tid] = m + eb[t * NG + tid];
            }
            __syncthreads();
        }
        if (tid == 0) {
            float* fin = bufB;
            float m = -1e30f; int tag = 0;
            for (int j = 0; j < NG; j++) {
                float v = fin[j] + Tl[j * NG + STOP_];
                if (v > m) { m = v; tag = j; }
            }
            float* od = outv + 1 + (long)b * 256;
            od[255] = (float)tag;
            for (int t = 255; t >= 1; t--) { tag = bp[t][tag]; od[t - 1] = (float)tag; }
        }
    }
}

// ---------------- host ----------------
extern "C" void kernel_launch(void* const* d_in, const int* in_sizes, int n_in,
                              void* d_out, int out_size, void* d_ws, size_t ws_size,
                              hipStream_t stream)
{
    const int*   batch_word    = (const int*)d_in[0];
    const int*   batch_intents = (const int*)d_in[1];
    const int*   batch_char    = (const int*)d_in[3];
    const int*   batch_lexi    = (const int*)d_in[6];
    const int*   batch_label   = (const int*)d_in[7];
    const float* char_emb      = (const float*)d_in[8];
    const float* word_emb      = (const float*)d_in[9];
    const float* lexi_emb      = (const float*)d_in[10];
    const float* intent_emb    = (const float*)d_in[11];
    const float* conv_w        = (const float*)d_in[12];
    const float* conv_b        = (const float*)d_in[13];
    const float* w_ih          = (const float*)d_in[14];
    const float* w_hh          = (const float*)d_in[15];
    const float* b_ih          = (const float*)d_in[16];
    const float* b_hh          = (const float*)d_in[17];
    const float* proj_w        = (const float*)d_in[18];
    const float* proj_b        = (const float*)d_in[19];
    const float* trans         = (const float*)d_in[20];
    float* out = (float*)d_out;
    float* ws  = (float*)d_ws;

    float* ce_pad   = ws + OFF_CEPAD;
    float* q        = ws + OFF_Q;
    float* kv       = ws + OFF_KV;
    float* preF     = ws + OFF_PREF;
    float* scores   = ws + OFF_SC;
    float* x        = ws + OFF_X;
    float* y        = ws + OFF_Y;
    float* preB     = ws + OFF_PREB;
    float* emit     = ws + OFF_EMIT;
    unsigned* wt_u  = (unsigned*)(ws + OFF_WT);
    float* w2       = ws + OFF_W2;

    embed_k<<<BT, 128, 0, stream>>>(batch_word, batch_intents, batch_char, batch_lexi,
                                    word_emb, lexi_emb, intent_emb, char_emb, kv, q, ce_pad);
    prep_k<<<(384 * 384 + 255) / 256, 256, 0, stream>>>(conv_w, w2, out);
    wt_k<<<256, 256, 0, stream>>>(w_hh, wt_u);

    // char CNN as GEMM (A gathered from ce_pad), C into q cols 0..383
    gemm_k<<<dim3(128, 3, 1), 256, 0, stream>>>(ce_pad, 0, 0L, 1,
                                                w2, 384, 0L, 1,
                                                q, 512, 0L, 384, 384,
                                                conv_b, nullptr, 1.f);
    // attention scores = q @ kv^T / TEMP  (batched)
    gemm_k<<<dim3(2, 2, NB), 256, 0, stream>>>(q, 512, 131072L, 0,
                                               kv, 512, 131072L, 1,
                                               scores, 256, 65536L, 256, 512,
                                               nullptr, nullptr, INV_TEMP);
    softmax_k<<<4096, 256, 0, stream>>>(scores);
    // x = softmax(scores) @ kv
    gemm_k<<<dim3(2, 4, NB), 256, 0, stream>>>(scores, 256, 65536L, 0,
                                               kv, 512, 131072L, 0,
                                               x, 512, 131072L, 512, 256,
                                               nullptr, nullptr, 1.f);

    for (int l = 0; l < 2; l++) {
        const float* xin = l ? y : x;
        float* xout = l ? x : y;
        for (int d = 0; d < 2; d++) {
            gemm_k<<<dim3(128, 8, 1), 256, 0, stream>>>(
                xin, 512, 0L, 0,
                w_ih + (long)(l * 2 + d) * 1024 * 512, 512, 0L, 1,
                d ? preB : preF, 1024, 0L, 1024, 512,
                b_ih + (l * 2 + d) * 1024, b_hh + (l * 2 + d) * 1024, 1.f);
        }
        lstm_k<<<64, 512, 0, stream>>>(preF, preB, wt_u + (long)l * 2 * 131072, xout);
    }

    // emissions (overwrites wt region — wt is dead after last lstm)
    gemm_k<<<dim3(128, 1, 1), 256, 0, stream>>>(x, 512, 0L, 0,
                                                proj_w, 512, 0L, 1,
                                                emit, NG, 0L, NG, 512,
                                                proj_b, nullptr, 1.f);
    // CRF NLL (blocks 0..63) + Viterbi (blocks 64..127)
    crf_k<<<128, 128, 0, stream>>>(emit, trans, batch_label, out);
}

// Round 4
// 4473.081 us; speedup vs baseline: 2.7404x; 1.5181x over previous
//
#include <hip/hip_runtime.h>

// ---------------- problem constants ----------------
#define NB 64
#define NT 256
#define BT 16384          // NB*NT
#define NG 66
#define START_ 64
#define STOP_ 65
#define INV_TEMP 0.08838834764831845f  // 1/sqrt(128)

typedef _Float16 half2_t __attribute__((ext_vector_type(2)));
union H2U { unsigned u; half2_t h; };

// ---------------- workspace layout (float offsets) ----------------
// ce_pad [64][258][128]      @ 0          (2,113,536)   dead after conv
// q      [BT][512]           @ 2,113,536  (8,388,608)   dead after scores
// kv     [BT][512]           @ 10,502,144 (8,388,608)   dead after x-GEMM
// preF   [BT][1024]          @ 0          (16,777,216)  aliases ce_pad+q+kv-head (all dead)
// scores [64][256][256]      @ 18,890,752 (4,194,304)
// x      [BT][512]           @ 23,085,056 (8,388,608)
// y      [BT][512]           @ 31,473,664 (8,388,608)
// preB   [BT][1024]          @ 39,862,272 (16,777,216)
// emit   [BT][66]            @ 56,639,488 (1,081,344)   ALIASES wt (wt dead before proj)
// wt fp16 [4 ld][64 kq][1024 r] uint2 @ 56,639,488 (524,288 f = 2 MB)
// w2     [384][384]          @ 57,720,832 (147,456)
#define OFF_CEPAD 0L
#define OFF_Q     2113536L
#define OFF_KV    10502144L
#define OFF_PREF  0L
#define OFF_SC    18890752L
#define OFF_X     23085056L
#define OFF_Y     31473664L
#define OFF_PREB  39862272L
#define OFF_EMIT  56639488L
#define OFF_WT    56639488L
#define OFF_W2    57720832L

// ---------------- embedding / gather ----------------
__global__ __launch_bounds__(128) void embed_k(
    const int* __restrict__ word, const int* __restrict__ intents,
    const int* __restrict__ chars, const int* __restrict__ lexi,
    const float* __restrict__ word_emb, const float* __restrict__ lexi_emb,
    const float* __restrict__ intent_emb, const float* __restrict__ char_emb,
    float* __restrict__ kv, float* __restrict__ q, float* __restrict__ ce_pad)
{
    int bt = blockIdx.x;
    int b = bt >> 8, t = bt & 255;
    int tid = threadIdx.x;
    const float4* wrow = (const float4*)(word_emb + (long)word[bt] * 256);
    const float4* lrow = (const float4*)(lexi_emb + (long)lexi[bt] * 128);
    const float4* irow = (const float4*)(intent_emb + (long)intents[b] * 128);
    const float4* crow = (const float4*)(char_emb + (long)chars[bt] * 128);
    float4* kvrow = (float4*)(kv + (long)bt * 512);
    float4* qrow  = (float4*)(q  + (long)bt * 512);
    float4* cerow = (float4*)(ce_pad + ((long)b * 258 + t + 1) * 128);
    if (tid < 64)       kvrow[tid] = wrow[tid];
    else if (tid < 96)  kvrow[tid] = lrow[tid - 64];
    else { float4 v = irow[tid - 96]; kvrow[tid] = v; qrow[tid] = v; }
    if (tid < 32) cerow[tid] = crow[tid];
    if (t == 0) {
        float4 z = make_float4(0.f, 0.f, 0.f, 0.f);
        if (tid < 32)      ((float4*)(ce_pad + (long)b * 258 * 128))[tid] = z;
        else if (tid < 64) ((float4*)(ce_pad + ((long)b * 258 + 257) * 128))[tid - 32] = z;
    }
}

// repack conv_w (O,C,K) -> w2[o][k*128+c]; zero loss slot
__global__ __launch_bounds__(256) void prep_k(const float* __restrict__ conv_w,
                                              float* __restrict__ w2,
                                              float* __restrict__ out0)
{
    int idx = blockIdx.x * 256 + threadIdx.x;
    if (idx == 0) out0[0] = 0.f;
    if (idx < 384 * 384) {
        int o = idx / 384, r = idx % 384;
        int k = r >> 7, c = r & 127;
        w2[o * 384 + r] = conv_w[o * 384 + c * 3 + k];
    }
}

// transpose+pack w_hh fp32 [4 ld][1024 row][256 k]
//   -> wt fp16 uint2 [4 ld][64 kq][1024 row], uint2 = {h2(k4q,k4q+1), h2(k4q+2,k4q+3)}
__global__ __launch_bounds__(256) void wt_k(const float* __restrict__ whh,
                                            uint2* __restrict__ wt)
{
    // grid = 4 ld * 16 rowtiles(64) * 4 ktiles(64k=16kq) = 256 blocks
    int bid = blockIdx.x;
    int ld = bid >> 6;
    int rt = (bid >> 2) & 15;
    int kt = bid & 3;
    const float* src = whh + ((long)ld * 1024 + rt * 64) * 256 + kt * 64;
    __shared__ float tile[64][65];
    int c = threadIdx.x & 63, r0 = threadIdx.x >> 6;  // r0 in 0..3
#pragma unroll
    for (int i = 0; i < 16; i++)
        tile[r0 + i * 4][c] = src[(long)(r0 + i * 4) * 256 + c];
    __syncthreads();
    uint2* dst = wt + (long)ld * 65536;
#pragma unroll
    for (int i = 0; i < 4; i++) {
        int kql = r0 + i * 4;          // 0..15
        H2U ua, ub;
        ua.h[0] = (_Float16)tile[c][4 * kql + 0];
        ua.h[1] = (_Float16)tile[c][4 * kql + 1];
        ub.h[0] = (_Float16)tile[c][4 * kql + 2];
        ub.h[1] = (_Float16)tile[c][4 * kql + 3];
        dst[(long)(kt * 16 + kql) * 1024 + rt * 64 + c] = make_uint2(ua.u, ub.u);
    }
}

// ---------------- generic fp32 GEMM: C = alpha*A@op(B) + bias0 + bias1 ----------------
#define GT 128
#define GK 16
__global__ __launch_bounds__(256) void gemm_k(
    const float* __restrict__ A, int lda, long sA, int amode,
    const float* __restrict__ Bm, int ldb, long sB, int transB,
    float* __restrict__ C, int ldc, long sC,
    int N, int K,
    const float* __restrict__ bias0, const float* __restrict__ bias1, float alpha)
{
    A  += (long)blockIdx.z * sA;
    Bm += (long)blockIdx.z * sB;
    C  += (long)blockIdx.z * sC;
    const int m0 = blockIdx.x * GT, n0 = blockIdx.y * GT;
    __shared__ float As[GK][GT + 4];
    __shared__ float Bs[GK][GT + 4];
    const int tid = threadIdx.x;
    const int tm = (tid & 15) * 4;
    const int tn = (tid >> 4) * 4;
    float acc[8][8];
#pragma unroll
    for (int i = 0; i < 8; i++)
#pragma unroll
        for (int j = 0; j < 8; j++) acc[i][j] = 0.f;
    const int lr = tid >> 2;
    const int lk = (tid & 3) * 4;

    for (int k0 = 0; k0 < K; k0 += GK) {
#pragma unroll
        for (int p = 0; p < 2; p++) {
            int m = m0 + p * 64 + lr;
            long rowoff = (amode == 0) ? ((long)m * lda)
                                       : ((long)m * 128 + (long)(m >> 8) * 256);
            float4 v = *(const float4*)(A + rowoff + k0 + lk);
            As[lk + 0][p * 64 + lr] = v.x;
            As[lk + 1][p * 64 + lr] = v.y;
            As[lk + 2][p * 64 + lr] = v.z;
            As[lk + 3][p * 64 + lr] = v.w;
        }
        if (transB) {
#pragma unroll
            for (int p = 0; p < 2; p++) {
                int n = n0 + p * 64 + lr;
                float4 v = make_float4(0.f, 0.f, 0.f, 0.f);
                if (n < N) v = *(const float4*)(Bm + (long)n * ldb + k0 + lk);
                Bs[lk + 0][p * 64 + lr] = v.x;
                Bs[lk + 1][p * 64 + lr] = v.y;
                Bs[lk + 2][p * 64 + lr] = v.z;
                Bs[lk + 3][p * 64 + lr] = v.w;
            }
        } else {
            int kk = tid >> 4;
            int nn = (tid & 15) * 8;
            float4 v0 = *(const float4*)(Bm + (long)(k0 + kk) * ldb + n0 + nn);
            float4 v1 = *(const float4*)(Bm + (long)(k0 + kk) * ldb + n0 + nn + 4);
            *(float4*)&Bs[kk][nn] = v0;
            *(float4*)&Bs[kk][nn + 4] = v1;
        }
        __syncthreads();
#pragma unroll
        for (int kk = 0; kk < GK; kk++) {
            float4 a0 = *(const float4*)&As[kk][tm];
            float4 a1 = *(const float4*)&As[kk][tm + 64];
            float4 b0 = *(const float4*)&Bs[kk][tn];
            float4 b1 = *(const float4*)&Bs[kk][tn + 64];
            float av[8] = {a0.x, a0.y, a0.z, a0.w, a1.x, a1.y, a1.z, a1.w};
            float bv[8] = {b0.x, b0.y, b0.z, b0.w, b1.x, b1.y, b1.z, b1.w};
#pragma unroll
            for (int i = 0; i < 8; i++)
#pragma unroll
                for (int j = 0; j < 8; j++)
                    acc[i][j] = fmaf(av[i], bv[j], acc[i][j]);
        }
        __syncthreads();
    }
#pragma unroll
    for (int i = 0; i < 8; i++) {
        int m = m0 + ((i < 4) ? (tm + i) : (tm + 64 + i - 4));
#pragma unroll
        for (int j = 0; j < 8; j++) {
            int n = n0 + ((j < 4) ? (tn + j) : (tn + 64 + j - 4));
            if (n < N) {
                float v = alpha * acc[i][j];
                if (bias0) v += bias0[n];
                if (bias1) v += bias1[n];
                C[(long)m * ldc + n] = v;
            }
        }
    }
}

// ---------------- row softmax over 256 cols ----------------
__global__ __launch_bounds__(256) void softmax_k(float* __restrict__ scores)
{
    int row = blockIdx.x * 4 + (threadIdx.x >> 6);
    int lane = threadIdx.x & 63;
    float4* p = (float4*)(scores + (long)row * 256);
    float4 v = p[lane];
    float m = fmaxf(fmaxf(v.x, v.y), fmaxf(v.z, v.w));
#pragma unroll
    for (int off = 32; off; off >>= 1) m = fmaxf(m, __shfl_xor(m, off));
    v.x = __expf(v.x - m); v.y = __expf(v.y - m);
    v.z = __expf(v.z - m); v.w = __expf(v.w - m);
    float s = v.x + v.y + v.z + v.w;
#pragma unroll
    for (int off = 32; off; off >>= 1) s += __shfl_xor(s, off);
    float inv = 1.f / s;
    v.x *= inv; v.y *= inv; v.z *= inv; v.w *= inv;
    p[lane] = v;
}

// ---------------- BiLSTM recurrence v3: cached fp16 weights + fdot2 ----------------
// 64 blocks = 2 dirs x 32 batch-pairs; 512 threads (8 waves); 1 block/CU.
// Thread owns 2 gate-rows x 2 batches. W split per step:
//   kq  0..25 : register-cached (26 uint4 = 104 VGPRs, loop-invariant)
//   kq 26..31 : LDS-cached (48 KB)
//   kq 32..63 : streamed from L2 (256 KB/step) in 4 double-buffered chunks of 8
// h packed once/step into hq[64] (uint4 = 4 k x 2 batches fp16), b128 broadcast reads.
__global__ __launch_bounds__(512) void lstm_k(
    const float* __restrict__ preF, const float* __restrict__ preB,
    const uint4* __restrict__ wtL,  // layer base: [2 dir][64 kq][512 rp] uint4
    float* __restrict__ out)        // [BT][512], cols dir*256+j
{
    const int dir = blockIdx.x & 1;
    const int b0  = (blockIdx.x >> 1) * 2;
    const int tid = threadIdx.x;
    const int r0  = tid * 2;            // 2 consecutive gate-rows per thread
    __shared__ uint4 wlds[6][512];      // kq 26..31 (48 KB)
    __shared__ uint4 hq[64];            // packed h: {b0 kp0, b0 kp1, b1 kp0, b1 kp1}
    __shared__ float gl[2][1024];
    __shared__ float hraw[2][256];
    const float* pre = dir ? preB : preF;
    const uint4* W = wtL + (long)dir * 32768;   // 64 kq * 512 rp

    uint4 wreg[26];
#pragma unroll
    for (int i = 0; i < 26; i++) wreg[i] = W[i * 512 + tid];
#pragma unroll
    for (int i = 0; i < 6; i++) wlds[i][tid] = W[(26 + i) * 512 + tid];
    float c0 = 0.f, c1 = 0.f;
    __syncthreads();

#define DOT(WV, HV) do {                                                         \
    H2U wx, wy, wz, ww, hx, hy, hz, hw;                                          \
    wx.u = (WV).x; wy.u = (WV).y; wz.u = (WV).z; ww.u = (WV).w;                  \
    hx.u = (HV).x; hy.u = (HV).y; hz.u = (HV).z; hw.u = (HV).w;                  \
    a00 = __builtin_amdgcn_fdot2(wx.h, hx.h, a00, false);                        \
    a00 = __builtin_amdgcn_fdot2(wy.h, hy.h, a00, false);                        \
    a01 = __builtin_amdgcn_fdot2(wx.h, hz.h, a01, false);                        \
    a01 = __builtin_amdgcn_fdot2(wy.h, hw.h, a01, false);                        \
    a10 = __builtin_amdgcn_fdot2(wz.h, hx.h, a10, false);                        \
    a10 = __builtin_amdgcn_fdot2(ww.h, hy.h, a10, false);                        \
    a11 = __builtin_amdgcn_fdot2(wz.h, hz.h, a11, false);                        \
    a11 = __builtin_amdgcn_fdot2(ww.h, hw.h, a11, false);                        \
} while (0)

    for (int t = 0; t < 256; t++) {
        const int tpre = dir ? (255 - t) : t;
        float2 p0 = *(const float2*)(pre + ((long)b0 * 256 + tpre) * 1024 + r0);
        float2 p1 = *(const float2*)(pre + ((long)(b0 + 1) * 256 + tpre) * 1024 + r0);
        float a00 = p0.x, a10 = p0.y, a01 = p1.x, a11 = p1.y;
        if (t > 0) {
            uint4 sA[8], sB[8];
            // issue stream chunk A (kq 32..39) before cached compute (covers L2 latency)
#pragma unroll
            for (int i = 0; i < 8; i++) sA[i] = W[(32 + i) * 512 + tid];
            // register-cached part (kq 0..25)
#pragma unroll
            for (int i = 0; i < 26; i++) { uint4 hv = hq[i]; DOT(wreg[i], hv); }
            // issue chunk B (kq 40..47)
#pragma unroll
            for (int i = 0; i < 8; i++) sB[i] = W[(40 + i) * 512 + tid];
            // LDS-cached part (kq 26..31)
#pragma unroll
            for (int i = 0; i < 6; i++) { uint4 wv = wlds[i][tid]; uint4 hv = hq[26 + i]; DOT(wv, hv); }
            // consume A, refill A (kq 48..55)
#pragma unroll
            for (int i = 0; i < 8; i++) { uint4 hv = hq[32 + i]; DOT(sA[i], hv); }
#pragma unroll
            for (int i = 0; i < 8; i++) sA[i] = W[(48 + i) * 512 + tid];
            // consume B, refill B (kq 56..63)
#pragma unroll
            for (int i = 0; i < 8; i++) { uint4 hv = hq[40 + i]; DOT(sB[i], hv); }
#pragma unroll
            for (int i = 0; i < 8; i++) sB[i] = W[(56 + i) * 512 + tid];
#pragma unroll
            for (int i = 0; i < 8; i++) { uint4 hv = hq[48 + i]; DOT(sA[i], hv); }
#pragma unroll
            for (int i = 0; i < 8; i++) { uint4 hv = hq[56 + i]; DOT(sB[i], hv); }
        }
        *(float2*)&gl[0][r0] = make_float2(a00, a10);
        *(float2*)&gl[1][r0] = make_float2(a01, a11);
        __syncthreads();
        // ---- update phase: tid<256, thread owns h-dim j for both batches ----
        if (tid < 256) {
            const int j = tid;
            float i0 = gl[0][j], f0 = gl[0][256 + j], g0 = gl[0][512 + j], o0 = gl[0][768 + j];
            float i1 = gl[1][j], f1 = gl[1][256 + j], g1 = gl[1][512 + j], o1 = gl[1][768 + j];
            float si0 = 1.f / (1.f + __expf(-i0)), sf0 = 1.f / (1.f + __expf(-f0));
            float so0 = 1.f / (1.f + __expf(-o0));
            float si1 = 1.f / (1.f + __expf(-i1)), sf1 = 1.f / (1.f + __expf(-f1));
            float so1 = 1.f / (1.f + __expf(-o1));
            c0 = sf0 * c0 + si0 * tanhf(g0);
            c1 = sf1 * c1 + si1 * tanhf(g1);
            float h0v = so0 * tanhf(c0);
            float h1v = so1 * tanhf(c1);
            hraw[0][j] = h0v;
            hraw[1][j] = h1v;
            out[((long)b0 * 256 + tpre) * 512 + dir * 256 + j] = h0v;
            out[((long)(b0 + 1) * 256 + tpre) * 512 + dir * 256 + j] = h1v;
        }
        __syncthreads();
        // ---- pack phase: tid<64 packs hq[kq] ----
        if (tid < 64) {
            int k4 = tid * 4;
            H2U u0, u1, u2, u3;
            u0.h[0] = (_Float16)hraw[0][k4 + 0]; u0.h[1] = (_Float16)hraw[0][k4 + 1];
            u1.h[0] = (_Float16)hraw[0][k4 + 2]; u1.h[1] = (_Float16)hraw[0][k4 + 3];
            u2.h[0] = (_Float16)hraw[1][k4 + 0]; u2.h[1] = (_Float16)hraw[1][k4 + 1];
            u3.h[0] = (_Float16)hraw[1][k4 + 2]; u3.h[1] = (_Float16)hraw[1][k4 + 3];
            hq[tid] = make_uint4(u0.u, u1.u, u2.u, u3.u);
        }
        __syncthreads();
    }
#undef DOT
}

// ---------------- CRF NLL + Viterbi ----------------
__global__ __launch_bounds__(128) void crf_k(
    const float* __restrict__ emit, const float* __restrict__ trans,
    const int* __restrict__ labels, float* __restrict__ outv)
{
    const int b = blockIdx.x & 63;
    const bool vit = blockIdx.x >= 64;
    const int tid = threadIdx.x;
    __shared__ float Tl[NG * NG];
    __shared__ float bufA[NG], bufB[NG];
    __shared__ unsigned char bp[256][NG];
    __shared__ float redv[128];
    for (int i = tid; i < NG * NG; i += 128) Tl[i] = trans[i];
    __syncthreads();
    const float* eb = emit + (long)b * 256 * NG;

    if (!vit) {
        if (tid < NG) bufA[tid] = Tl[START_ * NG + tid] + eb[tid];
        __syncthreads();
        for (int t = 1; t < 256; t++) {
            float* prev = (t & 1) ? bufA : bufB;
            float* cur  = (t & 1) ? bufB : bufA;
            if (tid < NG) {
                float m = -1e30f;
                for (int i = 0; i < NG; i++) m = fmaxf(m, prev[i] + Tl[i * NG + tid]);
                float s = 0.f;
                for (int i = 0; i < NG; i++) s += __expf(prev[i] + Tl[i * NG + tid] - m);
                cur[tid] = m + __logf(s) + eb[t * NG + tid];
            }
            __syncthreads();
        }
        const int* lab = labels + b * 256;
        float g = 0.f;
        for (int t = tid; t < 256; t += 128) g += eb[t * NG + lab[t]];
        for (int t = tid; t < 255; t += 128) g += Tl[lab[t] * NG + lab[t + 1]];
        redv[tid] = g;
        __syncthreads();
        if (tid == 0) {
            float* fin = bufB;
            float m = -1e30f;
            for (int j = 0; j < NG; j++) m = fmaxf(m, fin[j] + Tl[j * NG + STOP_]);
            float s = 0.f;
            for (int j = 0; j < NG; j++) s += __expf(fin[j] + Tl[j * NG + STOP_] - m);
            float logZ = m + __logf(s);
            float gold = Tl[START_ * NG + lab[0]] + Tl[lab[255] * NG + STOP_];
            for (int i = 0; i < 128; i++) gold += redv[i];
            atomicAdd(outv, logZ - gold);
        }
    } else {
        if (tid < NG) bufA[tid] = Tl[START_ * NG + tid] + eb[tid];
        __syncthreads();
        for (int t = 1; t < 256; t++) {
            float* prev = (t & 1) ? bufA : bufB;
            float* cur  = (t & 1) ? bufB : bufA;
            if (tid < NG) {
                float m = -1e30f; int arg = 0;
                for (int i = 0; i < NG; i++) {
                    float v = prev[i] + Tl[i * NG + tid];
                    if (v > m) { m = v; arg = i; }   // strict > keeps FIRST argmax
                }
                bp[t][tid] = (unsigned char)arg;
                cur[tid] = m + eb[t * NG + tid];
            }
            __syncthreads();
        }
        if (tid == 0) {
            float* fin = bufB;
            float m = -1e30f; int tag = 0;
            for (int j = 0; j < NG; j++) {
                float v = fin[j] + Tl[j * NG + STOP_];
                if (v > m) { m = v; tag = j; }
            }
            float* od = outv + 1 + (long)b * 256;
            od[255] = (float)tag;
            for (int t = 255; t >= 1; t--) { tag = bp[t][tag]; od[t - 1] = (float)tag; }
        }
    }
}

// ---------------- host ----------------
extern "C" void kernel_launch(void* const* d_in, const int* in_sizes, int n_in,
                              void* d_out, int out_size, void* d_ws, size_t ws_size,
                              hipStream_t stream)
{
    const int*   batch_word    = (const int*)d_in[0];
    const int*   batch_intents = (const int*)d_in[1];
    const int*   batch_char    = (const int*)d_in[3];
    const int*   batch_lexi    = (const int*)d_in[6];
    const int*   batch_label   = (const int*)d_in[7];
    const float* char_emb      = (const float*)d_in[8];
    const float* word_emb      = (const float*)d_in[9];
    const float* lexi_emb      = (const float*)d_in[10];
    const float* intent_emb    = (const float*)d_in[11];
    const float* conv_w        = (const float*)d_in[12];
    const float* conv_b        = (const float*)d_in[13];
    const float* w_ih          = (const float*)d_in[14];
    const float* w_hh          = (const float*)d_in[15];
    const float* b_ih          = (const float*)d_in[16];
    const float* b_hh          = (const float*)d_in[17];
    const float* proj_w        = (const float*)d_in[18];
    const float* proj_b        = (const float*)d_in[19];
    const float* trans         = (const float*)d_in[20];
    float* out = (float*)d_out;
    float* ws  = (float*)d_ws;

    float* ce_pad   = ws + OFF_CEPAD;
    float* q        = ws + OFF_Q;
    float* kv       = ws + OFF_KV;
    float* preF     = ws + OFF_PREF;
    float* scores   = ws + OFF_SC;
    float* x        = ws + OFF_X;
    float* y        = ws + OFF_Y;
    float* preB     = ws + OFF_PREB;
    float* emit     = ws + OFF_EMIT;
    uint2* wt_u2    = (uint2*)(ws + OFF_WT);
    float* w2       = ws + OFF_W2;

    embed_k<<<BT, 128, 0, stream>>>(batch_word, batch_intents, batch_char, batch_lexi,
                                    word_emb, lexi_emb, intent_emb, char_emb, kv, q, ce_pad);
    prep_k<<<(384 * 384 + 255) / 256, 256, 0, stream>>>(conv_w, w2, out);
    wt_k<<<256, 256, 0, stream>>>(w_hh, wt_u2);

    // char CNN as GEMM (A gathered from ce_pad), C into q cols 0..383
    gemm_k<<<dim3(128, 3, 1), 256, 0, stream>>>(ce_pad, 0, 0L, 1,
                                                w2, 384, 0L, 1,
                                                q, 512, 0L, 384, 384,
                                                conv_b, nullptr, 1.f);
    // attention scores = q @ kv^T / TEMP  (batched)
    gemm_k<<<dim3(2, 2, NB), 256, 0, stream>>>(q, 512, 131072L, 0,
                                               kv, 512, 131072L, 1,
                                               scores, 256, 65536L, 256, 512,
                                               nullptr, nullptr, INV_TEMP);
    softmax_k<<<4096, 256, 0, stream>>>(scores);
    // x = softmax(scores) @ kv
    gemm_k<<<dim3(2, 4, NB), 256, 0, stream>>>(scores, 256, 65536L, 0,
                                               kv, 512, 131072L, 0,
                                               x, 512, 131072L, 512, 256,
                                               nullptr, nullptr, 1.f);

    for (int l = 0; l < 2; l++) {
        const float* xin = l ? y : x;
        float* xout = l ? x : y;
        for (int d = 0; d < 2; d++) {
            gemm_k<<<dim3(128, 8, 1), 256, 0, stream>>>(
                xin, 512, 0L, 0,
                w_ih + (long)(l * 2 + d) * 1024 * 512, 512, 0L, 1,
                d ? preB : preF, 1024, 0L, 1024, 512,
                b_ih + (l * 2 + d) * 1024, b_hh + (l * 2 + d) * 1024, 1.f);
        }
        lstm_k<<<64, 512, 0, stream>>>(preF, preB,
                                       (const uint4*)(wt_u2 + (long)l * 2 * 65536), xout);
    }

    // emissions (overwrites wt region — wt is dead after last lstm)
    gemm_k<<<dim3(128, 1, 1), 256, 0, stream>>>(x, 512, 0L, 0,
                                                proj_w, 512, 0L, 1,
                                                emit, NG, 0L, NG, 512,
                                                proj_b, nullptr, 1.f);
    // CRF NLL (blocks 0..63) + Viterbi (blocks 64..127)
    crf_k<<<128, 128, 0, stream>>>(emit, trans, batch_label, out);
}

// Round 5
// 3430.141 us; speedup vs baseline: 3.5737x; 1.3041x over previous
//
#include <hip/hip_runtime.h>

// ---------------- problem constants ----------------
#define NB 64
#define NT 256
#define BT 16384          // NB*NT
#define NG 66
#define START_ 64
#define STOP_ 65
#define INV_TEMP 0.08838834764831845f  // 1/sqrt(128)

typedef _Float16 half2_t __attribute__((ext_vector_type(2)));
union H2U { unsigned u; half2_t h; };

// ---------------- workspace layout (float offsets) ----------------
// ce_pad [64][258][128]      @ 0          (2,113,536)   dead after conv
// q      [BT][512]           @ 2,113,536  (8,388,608)   dead after scores
// kv     [BT][512]           @ 10,502,144 (8,388,608)   dead after x-GEMM
// preF   [BT][1024]          @ 0          (16,777,216)  aliases ce_pad+q+kv-head (all dead)
// scores [64][256][256]      @ 18,890,752 (4,194,304)
// x      [BT][512]           @ 23,085,056 (8,388,608)
// y      [BT][512]           @ 31,473,664 (8,388,608)
// preB   [BT][1024]          @ 39,862,272 (16,777,216)
// emit   [BT][66]            @ 56,639,488 (1,081,344)   ALIASES wt (wt dead before proj)
// wt fp16 [4 ld][64 kq][1024 r] uint2 @ 56,639,488 (524,288 f = 2 MB)
// w2     [384][384]          @ 57,720,832 (147,456)
#define OFF_CEPAD 0L
#define OFF_Q     2113536L
#define OFF_KV    10502144L
#define OFF_PREF  0L
#define OFF_SC    18890752L
#define OFF_X     23085056L
#define OFF_Y     31473664L
#define OFF_PREB  39862272L
#define OFF_EMIT  56639488L
#define OFF_WT    56639488L
#define OFF_W2    57720832L

// ---------------- embedding / gather ----------------
__global__ __launch_bounds__(128) void embed_k(
    const int* __restrict__ word, const int* __restrict__ intents,
    const int* __restrict__ chars, const int* __restrict__ lexi,
    const float* __restrict__ word_emb, const float* __restrict__ lexi_emb,
    const float* __restrict__ intent_emb, const float* __restrict__ char_emb,
    float* __restrict__ kv, float* __restrict__ q, float* __restrict__ ce_pad)
{
    int bt = blockIdx.x;
    int b = bt >> 8, t = bt & 255;
    int tid = threadIdx.x;
    const float4* wrow = (const float4*)(word_emb + (long)word[bt] * 256);
    const float4* lrow = (const float4*)(lexi_emb + (long)lexi[bt] * 128);
    const float4* irow = (const float4*)(intent_emb + (long)intents[b] * 128);
    const float4* crow = (const float4*)(char_emb + (long)chars[bt] * 128);
    float4* kvrow = (float4*)(kv + (long)bt * 512);
    float4* qrow  = (float4*)(q  + (long)bt * 512);
    float4* cerow = (float4*)(ce_pad + ((long)b * 258 + t + 1) * 128);
    if (tid < 64)       kvrow[tid] = wrow[tid];
    else if (tid < 96)  kvrow[tid] = lrow[tid - 64];
    else { float4 v = irow[tid - 96]; kvrow[tid] = v; qrow[tid] = v; }
    if (tid < 32) cerow[tid] = crow[tid];
    if (t == 0) {
        float4 z = make_float4(0.f, 0.f, 0.f, 0.f);
        if (tid < 32)      ((float4*)(ce_pad + (long)b * 258 * 128))[tid] = z;
        else if (tid < 64) ((float4*)(ce_pad + ((long)b * 258 + 257) * 128))[tid - 32] = z;
    }
}

// repack conv_w (O,C,K) -> w2[o][k*128+c]; zero loss slot
__global__ __launch_bounds__(256) void prep_k(const float* __restrict__ conv_w,
                                              float* __restrict__ w2,
                                              float* __restrict__ out0)
{
    int idx = blockIdx.x * 256 + threadIdx.x;
    if (idx == 0) out0[0] = 0.f;
    if (idx < 384 * 384) {
        int o = idx / 384, r = idx % 384;
        int k = r >> 7, c = r & 127;
        w2[o * 384 + r] = conv_w[o * 384 + c * 3 + k];
    }
}

// transpose+pack w_hh fp32 [4 ld][1024 row][256 k]
//   -> wt fp16 uint2 [4 ld][64 kq][1024 row], uint2 = {h2(k4q,k4q+1), h2(k4q+2,k4q+3)}
__global__ __launch_bounds__(256) void wt_k(const float* __restrict__ whh,
                                            uint2* __restrict__ wt)
{
    // grid = 4 ld * 16 rowtiles(64) * 4 ktiles(64k=16kq) = 256 blocks
    int bid = blockIdx.x;
    int ld = bid >> 6;
    int rt = (bid >> 2) & 15;
    int kt = bid & 3;
    const float* src = whh + ((long)ld * 1024 + rt * 64) * 256 + kt * 64;
    __shared__ float tile[64][65];
    int c = threadIdx.x & 63, r0 = threadIdx.x >> 6;  // r0 in 0..3
#pragma unroll
    for (int i = 0; i < 16; i++)
        tile[r0 + i * 4][c] = src[(long)(r0 + i * 4) * 256 + c];
    __syncthreads();
    uint2* dst = wt + (long)ld * 65536;
#pragma unroll
    for (int i = 0; i < 4; i++) {
        int kql = r0 + i * 4;          // 0..15
        H2U ua, ub;
        ua.h[0] = (_Float16)tile[c][4 * kql + 0];
        ua.h[1] = (_Float16)tile[c][4 * kql + 1];
        ub.h[0] = (_Float16)tile[c][4 * kql + 2];
        ub.h[1] = (_Float16)tile[c][4 * kql + 3];
        dst[(long)(kt * 16 + kql) * 1024 + rt * 64 + c] = make_uint2(ua.u, ub.u);
    }
}

// ---------------- generic fp32 GEMM: C = alpha*A@op(B) + bias0 + bias1 ----------------
#define GT 128
#define GK 16
__global__ __launch_bounds__(256) void gemm_k(
    const float* __restrict__ A, int lda, long sA, int amode,
    const float* __restrict__ Bm, int ldb, long sB, int transB,
    float* __restrict__ C, int ldc, long sC,
    int N, int K,
    const float* __restrict__ bias0, const float* __restrict__ bias1, float alpha)
{
    A  += (long)blockIdx.z * sA;
    Bm += (long)blockIdx.z * sB;
    C  += (long)blockIdx.z * sC;
    const int m0 = blockIdx.x * GT, n0 = blockIdx.y * GT;
    __shared__ float As[GK][GT + 4];
    __shared__ float Bs[GK][GT + 4];
    const int tid = threadIdx.x;
    const int tm = (tid & 15) * 4;
    const int tn = (tid >> 4) * 4;
    float acc[8][8];
#pragma unroll
    for (int i = 0; i < 8; i++)
#pragma unroll
        for (int j = 0; j < 8; j++) acc[i][j] = 0.f;
    const int lr = tid >> 2;
    const int lk = (tid & 3) * 4;

    for (int k0 = 0; k0 < K; k0 += GK) {
#pragma unroll
        for (int p = 0; p < 2; p++) {
            int m = m0 + p * 64 + lr;
            long rowoff = (amode == 0) ? ((long)m * lda)
                                       : ((long)m * 128 + (long)(m >> 8) * 256);
            float4 v = *(const float4*)(A + rowoff + k0 + lk);
            As[lk + 0][p * 64 + lr] = v.x;
            As[lk + 1][p * 64 + lr] = v.y;
            As[lk + 2][p * 64 + lr] = v.z;
            As[lk + 3][p * 64 + lr] = v.w;
        }
        if (transB) {
#pragma unroll
            for (int p = 0; p < 2; p++) {
                int n = n0 + p * 64 + lr;
                float4 v = make_float4(0.f, 0.f, 0.f, 0.f);
                if (n < N) v = *(const float4*)(Bm + (long)n * ldb + k0 + lk);
                Bs[lk + 0][p * 64 + lr] = v.x;
                Bs[lk + 1][p * 64 + lr] = v.y;
                Bs[lk + 2][p * 64 + lr] = v.z;
                Bs[lk + 3][p * 64 + lr] = v.w;
            }
        } else {
            int kk = tid >> 4;
            int nn = (tid & 15) * 8;
            float4 v0 = *(const float4*)(Bm + (long)(k0 + kk) * ldb + n0 + nn);
            float4 v1 = *(const float4*)(Bm + (long)(k0 + kk) * ldb + n0 + nn + 4);
            *(float4*)&Bs[kk][nn] = v0;
            *(float4*)&Bs[kk][nn + 4] = v1;
        }
        __syncthreads();
#pragma unroll
        for (int kk = 0; kk < GK; kk++) {
            float4 a0 = *(const float4*)&As[kk][tm];
            float4 a1 = *(const float4*)&As[kk][tm + 64];
            float4 b0 = *(const float4*)&Bs[kk][tn];
            float4 b1 = *(const float4*)&Bs[kk][tn + 64];
            float av[8] = {a0.x, a0.y, a0.z, a0.w, a1.x, a1.y, a1.z, a1.w};
            float bv[8] = {b0.x, b0.y, b0.z, b0.w, b1.x, b1.y, b1.z, b1.w};
#pragma unroll
            for (int i = 0; i < 8; i++)
#pragma unroll
                for (int j = 0; j < 8; j++)
                    acc[i][j] = fmaf(av[i], bv[j], acc[i][j]);
        }
        __syncthreads();
    }
#pragma unroll
    for (int i = 0; i < 8; i++) {
        int m = m0 + ((i < 4) ? (tm + i) : (tm + 64 + i - 4));
#pragma unroll
        for (int j = 0; j < 8; j++) {
            int n = n0 + ((j < 4) ? (tn + j) : (tn + 64 + j - 4));
            if (n < N) {
                float v = alpha * acc[i][j];
                if (bias0) v += bias0[n];
                if (bias1) v += bias1[n];
                C[(long)m * ldc + n] = v;
            }
        }
    }
}

// ---------------- row softmax over 256 cols ----------------
__global__ __launch_bounds__(256) void softmax_k(float* __restrict__ scores)
{
    int row = blockIdx.x * 4 + (threadIdx.x >> 6);
    int lane = threadIdx.x & 63;
    float4* p = (float4*)(scores + (long)row * 256);
    float4 v = p[lane];
    float m = fmaxf(fmaxf(v.x, v.y), fmaxf(v.z, v.w));
#pragma unroll
    for (int off = 32; off; off >>= 1) m = fmaxf(m, __shfl_xor(m, off));
    v.x = __expf(v.x - m); v.y = __expf(v.y - m);
    v.z = __expf(v.z - m); v.w = __expf(v.w - m);
    float s = v.x + v.y + v.z + v.w;
#pragma unroll
    for (int off = 32; off; off >>= 1) s += __shfl_xor(s, off);
    float inv = 1.f / s;
    v.x *= inv; v.y *= inv; v.z *= inv; v.w *= inv;
    p[lane] = v;
}

// ---------------- BiLSTM recurrence v3: cached fp16 weights + fdot2 ----------------
// 64 blocks = 2 dirs x 32 batch-pairs; 512 threads (8 waves); 1 block/CU.
// Thread owns 2 gate-rows x 2 batches. W split per step:
//   kq  0..25 : register-cached (26 uint4 = 104 VGPRs, loop-invariant)
//   kq 26..31 : LDS-cached (48 KB)
//   kq 32..63 : streamed from L2 (256 KB/step) in 4 double-buffered chunks of 8
// h packed once/step into hq[64] (uint4 = 4 k x 2 batches fp16), b128 broadcast reads.
__global__ __launch_bounds__(512) void lstm_k(
    const float* __restrict__ preF, const float* __restrict__ preB,
    const uint4* __restrict__ wtL,  // layer base: [2 dir][64 kq][512 rp] uint4
    float* __restrict__ out)        // [BT][512], cols dir*256+j
{
    const int dir = blockIdx.x & 1;
    const int b0  = (blockIdx.x >> 1) * 2;
    const int tid = threadIdx.x;
    const int r0  = tid * 2;            // 2 consecutive gate-rows per thread
    __shared__ uint4 wlds[6][512];      // kq 26..31 (48 KB)
    __shared__ uint4 hq[64];            // packed h: {b0 kp0, b0 kp1, b1 kp0, b1 kp1}
    __shared__ float gl[2][1024];
    __shared__ float hraw[2][256];
    const float* pre = dir ? preB : preF;
    const uint4* W = wtL + (long)dir * 32768;   // 64 kq * 512 rp

    uint4 wreg[26];
#pragma unroll
    for (int i = 0; i < 26; i++) wreg[i] = W[i * 512 + tid];
#pragma unroll
    for (int i = 0; i < 6; i++) wlds[i][tid] = W[(26 + i) * 512 + tid];
    float c0 = 0.f, c1 = 0.f;
    __syncthreads();

#define DOT(WV, HV) do {                                                         \
    H2U wx, wy, wz, ww, hx, hy, hz, hw;                                          \
    wx.u = (WV).x; wy.u = (WV).y; wz.u = (WV).z; ww.u = (WV).w;                  \
    hx.u = (HV).x; hy.u = (HV).y; hz.u = (HV).z; hw.u = (HV).w;                  \
    a00 = __builtin_amdgcn_fdot2(wx.h, hx.h, a00, false);                        \
    a00 = __builtin_amdgcn_fdot2(wy.h, hy.h, a00, false);                        \
    a01 = __builtin_amdgcn_fdot2(wx.h, hz.h, a01, false);                        \
    a01 = __builtin_amdgcn_fdot2(wy.h, hw.h, a01, false);                        \
    a10 = __builtin_amdgcn_fdot2(wz.h, hx.h, a10, false);                        \
    a10 = __builtin_amdgcn_fdot2(ww.h, hy.h, a10, false);                        \
    a11 = __builtin_amdgcn_fdot2(wz.h, hz.h, a11, false);                        \
    a11 = __builtin_amdgcn_fdot2(ww.h, hw.h, a11, false);                        \
} while (0)

    for (int t = 0; t < 256; t++) {
        const int tpre = dir ? (255 - t) : t;
        float2 p0 = *(const float2*)(pre + ((long)b0 * 256 + tpre) * 1024 + r0);
        float2 p1 = *(const float2*)(pre + ((long)(b0 + 1) * 256 + tpre) * 1024 + r0);
        float a00 = p0.x, a10 = p0.y, a01 = p1.x, a11 = p1.y;
        if (t > 0) {
            uint4 sA[8], sB[8];
            // issue stream chunk A (kq 32..39) before cached compute (covers L2 latency)
#pragma unroll
            for (int i = 0; i < 8; i++) sA[i] = W[(32 + i) * 512 + tid];
            // register-cached part (kq 0..25)
#pragma unroll
            for (int i = 0; i < 26; i++) { uint4 hv = hq[i]; DOT(wreg[i], hv); }
            // issue chunk B (kq 40..47)
#pragma unroll
            for (int i = 0; i < 8; i++) sB[i] = W[(40 + i) * 512 + tid];
            // LDS-cached part (kq 26..31)
#pragma unroll
            for (int i = 0; i < 6; i++) { uint4 wv = wlds[i][tid]; uint4 hv = hq[26 + i]; DOT(wv, hv); }
            // consume A, refill A (kq 48..55)
#pragma unroll
            for (int i = 0; i < 8; i++) { uint4 hv = hq[32 + i]; DOT(sA[i], hv); }
#pragma unroll
            for (int i = 0; i < 8; i++) sA[i] = W[(48 + i) * 512 + tid];
            // consume B, refill B (kq 56..63)
#pragma unroll
            for (int i = 0; i < 8; i++) { uint4 hv = hq[40 + i]; DOT(sB[i], hv); }
#pragma unroll
            for (int i = 0; i < 8; i++) sB[i] = W[(56 + i) * 512 + tid];
#pragma unroll
            for (int i = 0; i < 8; i++) { uint4 hv = hq[48 + i]; DOT(sA[i], hv); }
#pragma unroll
            for (int i = 0; i < 8; i++) { uint4 hv = hq[56 + i]; DOT(sB[i], hv); }
        }
        *(float2*)&gl[0][r0] = make_float2(a00, a10);
        *(float2*)&gl[1][r0] = make_float2(a01, a11);
        __syncthreads();
        // ---- update phase: tid<256, thread owns h-dim j for both batches ----
        if (tid < 256) {
            const int j = tid;
            float i0 = gl[0][j], f0 = gl[0][256 + j], g0 = gl[0][512 + j], o0 = gl[0][768 + j];
            float i1 = gl[1][j], f1 = gl[1][256 + j], g1 = gl[1][512 + j], o1 = gl[1][768 + j];
            float si0 = 1.f / (1.f + __expf(-i0)), sf0 = 1.f / (1.f + __expf(-f0));
            float so0 = 1.f / (1.f + __expf(-o0));
            float si1 = 1.f / (1.f + __expf(-i1)), sf1 = 1.f / (1.f + __expf(-f1));
            float so1 = 1.f / (1.f + __expf(-o1));
            c0 = sf0 * c0 + si0 * tanhf(g0);
            c1 = sf1 * c1 + si1 * tanhf(g1);
            float h0v = so0 * tanhf(c0);
            float h1v = so1 * tanhf(c1);
            hraw[0][j] = h0v;
            hraw[1][j] = h1v;
            out[((long)b0 * 256 + tpre) * 512 + dir * 256 + j] = h0v;
            out[((long)(b0 + 1) * 256 + tpre) * 512 + dir * 256 + j] = h1v;
        }
        __syncthreads();
        // ---- pack phase: tid<64 packs hq[kq] ----
        if (tid < 64) {
            int k4 = tid * 4;
            H2U u0, u1, u2, u3;
            u0.h[0] = (_Float16)hraw[0][k4 + 0]; u0.h[1] = (_Float16)hraw[0][k4 + 1];
            u1.h[0] = (_Float16)hraw[0][k4 + 2]; u1.h[1] = (_Float16)hraw[0][k4 + 3];
            u2.h[0] = (_Float16)hraw[1][k4 + 0]; u2.h[1] = (_Float16)hraw[1][k4 + 1];
            u3.h[0] = (_Float16)hraw[1][k4 + 2]; u3.h[1] = (_Float16)hraw[1][k4 + 3];
            hq[tid] = make_uint4(u0.u, u1.u, u2.u, u3.u);
        }
        __syncthreads();
    }
#undef DOT
}

// ---------------- CRF NLL + Viterbi (register-cached T columns, vectorized) ----------------
// blocks 0..63: NLL for batch b ; blocks 64..127: Viterbi for batch b.
// tcol[i]=T[i][tid] hoisted to 68 VGPRs (loop-invariant); prev read as 17 x ds_read_b128;
// pad entries 66,67 = -1e30 (exp->0, never argmax under strict >).
__global__ __launch_bounds__(128) void crf_k(
    const float* __restrict__ emit, const float* __restrict__ trans,
    const int* __restrict__ labels, float* __restrict__ outv)
{
    const int b = blockIdx.x & 63;
    const bool vit = blockIdx.x >= 64;
    const int tid = threadIdx.x;
    __shared__ float Tl[NG * NG];
    __shared__ __align__(16) float bufA[68];
    __shared__ __align__(16) float bufB[68];
    __shared__ unsigned char bp[256][NG];
    __shared__ float redv[128];
    for (int i = tid; i < NG * NG; i += 128) Tl[i] = trans[i];
    __syncthreads();
    const float* eb = emit + (long)b * 256 * NG;

    // hoist T column into registers (loop-invariant across t)
    float tcol[68];
    if (tid < NG) {
#pragma unroll
        for (int i = 0; i < NG; i++) tcol[i] = Tl[i * NG + tid];
    }
    tcol[66] = 0.f; tcol[67] = 0.f;
    // init alpha0 / delta0 + sentinel tails
    if (tid < NG) bufA[tid] = Tl[START_ * NG + tid] + eb[tid];
    if (tid == 66 || tid == 67) { bufA[tid] = -1e30f; bufB[tid] = -1e30f; }
    __syncthreads();

    if (!vit) {
        for (int t = 1; t < 256; t++) {
            const float* prev = (t & 1) ? bufA : bufB;
            float* cur  = (t & 1) ? bufB : bufA;
            float e_t = (tid < NG) ? eb[t * NG + tid] : 0.f;
            if (tid < NG) {
                float pv[68];
#pragma unroll
                for (int c = 0; c < 17; c++) {
                    float4 p4 = *(const float4*)&prev[c * 4];
                    pv[c * 4 + 0] = p4.x + tcol[c * 4 + 0];
                    pv[c * 4 + 1] = p4.y + tcol[c * 4 + 1];
                    pv[c * 4 + 2] = p4.z + tcol[c * 4 + 2];
                    pv[c * 4 + 3] = p4.w + tcol[c * 4 + 3];
                }
                float m0 = -1e30f, m1 = -1e30f, m2 = -1e30f, m3 = -1e30f;
#pragma unroll
                for (int c = 0; c < 17; c++) {
                    m0 = fmaxf(m0, pv[c * 4 + 0]);
                    m1 = fmaxf(m1, pv[c * 4 + 1]);
                    m2 = fmaxf(m2, pv[c * 4 + 2]);
                    m3 = fmaxf(m3, pv[c * 4 + 3]);
                }
                float m = fmaxf(fmaxf(m0, m1), fmaxf(m2, m3));
                float s0 = 0.f, s1 = 0.f, s2 = 0.f, s3 = 0.f;
#pragma unroll
                for (int c = 0; c < 17; c++) {
                    s0 += __expf(pv[c * 4 + 0] - m);
                    s1 += __expf(pv[c * 4 + 1] - m);
                    s2 += __expf(pv[c * 4 + 2] - m);
                    s3 += __expf(pv[c * 4 + 3] - m);
                }
                cur[tid] = m + __logf((s0 + s1) + (s2 + s3)) + e_t;
            }
            __syncthreads();
        }
        const int* lab = labels + b * 256;
        float g = 0.f;
        for (int t = tid; t < 256; t += 128) g += eb[t * NG + lab[t]];
        for (int t = tid; t < 255; t += 128) g += Tl[lab[t] * NG + lab[t + 1]];
        redv[tid] = g;
        __syncthreads();
        if (tid == 0) {
            float* fin = bufB;   // t=255 wrote bufB
            float m = -1e30f;
            for (int j = 0; j < NG; j++) m = fmaxf(m, fin[j] + Tl[j * NG + STOP_]);
            float s = 0.f;
            for (int j = 0; j < NG; j++) s += __expf(fin[j] + Tl[j * NG + STOP_] - m);
            float logZ = m + __logf(s);
            float gold = Tl[START_ * NG + lab[0]] + Tl[lab[255] * NG + STOP_];
            for (int i = 0; i < 128; i++) gold += redv[i];
            atomicAdd(outv, logZ - gold);
        }
    } else {
        for (int t = 1; t < 256; t++) {
            const float* prev = (t & 1) ? bufA : bufB;
            float* cur  = (t & 1) ? bufB : bufA;
            float e_t = (tid < NG) ? eb[t * NG + tid] : 0.f;
            if (tid < NG) {
                float m = -1e30f; int arg = 0;
#pragma unroll
                for (int c = 0; c < 17; c++) {
                    float4 p4 = *(const float4*)&prev[c * 4];
                    float v0 = p4.x + tcol[c * 4 + 0];
                    float v1 = p4.y + tcol[c * 4 + 1];
                    float v2 = p4.z + tcol[c * 4 + 2];
                    float v3 = p4.w + tcol[c * 4 + 3];
                    // sequential strict > keeps FIRST argmax; sentinels never win
                    if (v0 > m) { m = v0; arg = c * 4 + 0; }
                    if (v1 > m) { m = v1; arg = c * 4 + 1; }
                    if (v2 > m) { m = v2; arg = c * 4 + 2; }
                    if (v3 > m) { m = v3; arg = c * 4 + 3; }
                }
                bp[t][tid] = (unsigned char)arg;
                cur[tid] = m + e_t;
            }
            __syncthreads();
        }
        if (tid == 0) {
            float* fin = bufB;
            float m = -1e30f; int tag = 0;
            for (int j = 0; j < NG; j++) {
                float v = fin[j] + Tl[j * NG + STOP_];
                if (v > m) { m = v; tag = j; }
            }
            float* od = outv + 1 + (long)b * 256;
            od[255] = (float)tag;
            for (int t = 255; t >= 1; t--) { tag = bp[t][tag]; od[t - 1] = (float)tag; }
        }
    }
}

// ---------------- host ----------------
extern "C" void kernel_launch(void* const* d_in, const int* in_sizes, int n_in,
                              void* d_out, int out_size, void* d_ws, size_t ws_size,
                              hipStream_t stream)
{
    const int*   batch_word    = (const int*)d_in[0];
    const int*   batch_intents = (const int*)d_in[1];
    const int*   batch_char    = (const int*)d_in[3];
    const int*   batch_lexi    = (const int*)d_in[6];
    const int*   batch_label   = (const int*)d_in[7];
    const float* char_emb      = (const float*)d_in[8];
    const float* word_emb      = (const float*)d_in[9];
    const float* lexi_emb      = (const float*)d_in[10];
    const float* intent_emb    = (const float*)d_in[11];
    const float* conv_w        = (const float*)d_in[12];
    const float* conv_b        = (const float*)d_in[13];
    const float* w_ih          = (const float*)d_in[14];
    const float* w_hh          = (const float*)d_in[15];
    const float* b_ih          = (const float*)d_in[16];
    const float* b_hh          = (const float*)d_in[17];
    const float* proj_w        = (const float*)d_in[18];
    const float* proj_b        = (const float*)d_in[19];
    const float* trans         = (const float*)d_in[20];
    float* out = (float*)d_out;
    float* ws  = (float*)d_ws;

    float* ce_pad   = ws + OFF_CEPAD;
    float* q        = ws + OFF_Q;
    float* kv       = ws + OFF_KV;
    float* preF     = ws + OFF_PREF;
    float* scores   = ws + OFF_SC;
    float* x        = ws + OFF_X;
    float* y        = ws + OFF_Y;
    float* preB     = ws + OFF_PREB;
    float* emit     = ws + OFF_EMIT;
    uint2* wt_u2    = (uint2*)(ws + OFF_WT);
    float* w2       = ws + OFF_W2;

    embed_k<<<BT, 128, 0, stream>>>(batch_word, batch_intents, batch_char, batch_lexi,
                                    word_emb, lexi_emb, intent_emb, char_emb, kv, q, ce_pad);
    prep_k<<<(384 * 384 + 255) / 256, 256, 0, stream>>>(conv_w, w2, out);
    wt_k<<<256, 256, 0, stream>>>(w_hh, wt_u2);

    // char CNN as GEMM (A gathered from ce_pad), C into q cols 0..383
    gemm_k<<<dim3(128, 3, 1), 256, 0, stream>>>(ce_pad, 0, 0L, 1,
                                                w2, 384, 0L, 1,
                                                q, 512, 0L, 384, 384,
                                                conv_b, nullptr, 1.f);
    // attention scores = q @ kv^T / TEMP  (batched)
    gemm_k<<<dim3(2, 2, NB), 256, 0, stream>>>(q, 512, 131072L, 0,
                                               kv, 512, 131072L, 1,
                                               scores, 256, 65536L, 256, 512,
                                               nullptr, nullptr, INV_TEMP);
    softmax_k<<<4096, 256, 0, stream>>>(scores);
    // x = softmax(scores) @ kv
    gemm_k<<<dim3(2, 4, NB), 256, 0, stream>>>(scores, 256, 65536L, 0,
                                               kv, 512, 131072L, 0,
                                               x, 512, 131072L, 512, 256,
                                               nullptr, nullptr, 1.f);

    for (int l = 0; l < 2; l++) {
        const float* xin = l ? y : x;
        float* xout = l ? x : y;
        for (int d = 0; d < 2; d++) {
            gemm_k<<<dim3(128, 8, 1), 256, 0, stream>>>(
                xin, 512, 0L, 0,
                w_ih + (long)(l * 2 + d) * 1024 * 512, 512, 0L, 1,
                d ? preB : preF, 1024, 0L, 1024, 512,
                b_ih + (l * 2 + d) * 1024, b_hh + (l * 2 + d) * 1024, 1.f);
        }
        lstm_k<<<64, 512, 0, stream>>>(preF, preB,
                                       (const uint4*)(wt_u2 + (long)l * 2 * 65536), xout);
    }

    // emissions (overwrites wt region — wt is dead after last lstm)
    gemm_k<<<dim3(128, 1, 1), 256, 0, stream>>>(x, 512, 0L, 0,
                                                proj_w, 512, 0L, 1,
                                                emit, NG, 0L, NG, 512,
                                                proj_b, nullptr, 1.f);
    // CRF NLL (blocks 0..63) + Viterbi (blocks 64..127)
    crf_k<<<128, 128, 0, stream>>>(emit, trans, batch_label, out);
}

// Round 6
// 2753.248 us; speedup vs baseline: 4.4522x; 1.2459x over previous
//
#include <hip/hip_runtime.h>

// ---------------- problem constants ----------------
#define NB 64
#define NT 256
#define BT 16384          // NB*NT
#define NG 66
#define START_ 64
#define STOP_ 65
#define INV_TEMP 0.08838834764831845f  // 1/sqrt(128)

typedef _Float16 half2_t __attribute__((ext_vector_type(2)));
typedef _Float16 h8 __attribute__((ext_vector_type(8)));
typedef float f4x __attribute__((ext_vector_type(4)));
union H2U { unsigned u; half2_t h; };

// ---------------- workspace layout (float offsets) ----------------
// ce_pad [64][258][128]      @ 0          (2,113,536)   dead after conv
// q      [BT][512]           @ 2,113,536  (8,388,608)   dead after scores
// kv     [BT][512]           @ 10,502,144 (8,388,608)   dead after x-GEMM
// preF   [BT][1024]          @ 0          (16,777,216)  aliases ce_pad+q+kv-head (all dead)
// wih_h  fp16 [4][1024][512] @ 16,777,216 (1,048,576 f) kv-tail gap, dead until x-GEMM done
// xh     fp16 [BT][512]      @ 18,890,752 (4,194,304 f) reuses scores (dead after x-GEMM)
// scores [64][256][256]      @ 18,890,752 (4,194,304)
// x      [BT][512]           @ 23,085,056 (8,388,608)
// y      [BT][512]           @ 31,473,664 (8,388,608)
// preB   [BT][1024]          @ 39,862,272 (16,777,216)
// emit   [BT][66]            @ 56,639,488 (1,081,344)   ALIASES wt (wt dead before proj)
// wt fp16 [4 ld][64 kq][1024 r] uint2 @ 56,639,488 (524,288 f = 2 MB)
// w2     [384][384]          @ 57,720,832 (147,456)
#define OFF_CEPAD 0L
#define OFF_Q     2113536L
#define OFF_KV    10502144L
#define OFF_PREF  0L
#define OFF_WIH   16777216L
#define OFF_XH    18890752L
#define OFF_SC    18890752L
#define OFF_X     23085056L
#define OFF_Y     31473664L
#define OFF_PREB  39862272L
#define OFF_EMIT  56639488L
#define OFF_WT    56639488L
#define OFF_W2    57720832L

// ---------------- embedding / gather ----------------
__global__ __launch_bounds__(128) void embed_k(
    const int* __restrict__ word, const int* __restrict__ intents,
    const int* __restrict__ chars, const int* __restrict__ lexi,
    const float* __restrict__ word_emb, const float* __restrict__ lexi_emb,
    const float* __restrict__ intent_emb, const float* __restrict__ char_emb,
    float* __restrict__ kv, float* __restrict__ q, float* __restrict__ ce_pad)
{
    int bt = blockIdx.x;
    int b = bt >> 8, t = bt & 255;
    int tid = threadIdx.x;
    const float4* wrow = (const float4*)(word_emb + (long)word[bt] * 256);
    const float4* lrow = (const float4*)(lexi_emb + (long)lexi[bt] * 128);
    const float4* irow = (const float4*)(intent_emb + (long)intents[b] * 128);
    const float4* crow = (const float4*)(char_emb + (long)chars[bt] * 128);
    float4* kvrow = (float4*)(kv + (long)bt * 512);
    float4* qrow  = (float4*)(q  + (long)bt * 512);
    float4* cerow = (float4*)(ce_pad + ((long)b * 258 + t + 1) * 128);
    if (tid < 64)       kvrow[tid] = wrow[tid];
    else if (tid < 96)  kvrow[tid] = lrow[tid - 64];
    else { float4 v = irow[tid - 96]; kvrow[tid] = v; qrow[tid] = v; }
    if (tid < 32) cerow[tid] = crow[tid];
    if (t == 0) {
        float4 z = make_float4(0.f, 0.f, 0.f, 0.f);
        if (tid < 32)      ((float4*)(ce_pad + (long)b * 258 * 128))[tid] = z;
        else if (tid < 64) ((float4*)(ce_pad + ((long)b * 258 + 257) * 128))[tid - 32] = z;
    }
}

// repack conv_w (O,C,K) -> w2[o][k*128+c]; zero loss slot
__global__ __launch_bounds__(256) void prep_k(const float* __restrict__ conv_w,
                                              float* __restrict__ w2,
                                              float* __restrict__ out0)
{
    int idx = blockIdx.x * 256 + threadIdx.x;
    if (idx == 0) out0[0] = 0.f;
    if (idx < 384 * 384) {
        int o = idx / 384, r = idx % 384;
        int k = r >> 7, c = r & 127;
        w2[o * 384 + r] = conv_w[o * 384 + c * 3 + k];
    }
}

// fp32 -> fp16 elementwise (n multiple of 1024; 4 elems/thread)
__global__ __launch_bounds__(256) void cvt_k(const float* __restrict__ src,
                                             unsigned* __restrict__ dst)  // dst = half pairs
{
    long i = ((long)blockIdx.x * 256 + threadIdx.x);
    float4 v = ((const float4*)src)[i];
    H2U a, b;
    a.h[0] = (_Float16)v.x; a.h[1] = (_Float16)v.y;
    b.h[0] = (_Float16)v.z; b.h[1] = (_Float16)v.w;
    ((uint2*)dst)[i] = make_uint2(a.u, b.u);
}

// transpose+pack w_hh fp32 [4 ld][1024 row][256 k]
//   -> wt fp16 uint2 [4 ld][64 kq][1024 row], uint2 = {h2(k4q,k4q+1), h2(k4q+2,k4q+3)}
__global__ __launch_bounds__(256) void wt_k(const float* __restrict__ whh,
                                            uint2* __restrict__ wt)
{
    int bid = blockIdx.x;
    int ld = bid >> 6;
    int rt = (bid >> 2) & 15;
    int kt = bid & 3;
    const float* src = whh + ((long)ld * 1024 + rt * 64) * 256 + kt * 64;
    __shared__ float tile[64][65];
    int c = threadIdx.x & 63, r0 = threadIdx.x >> 6;  // r0 in 0..3
#pragma unroll
    for (int i = 0; i < 16; i++)
        tile[r0 + i * 4][c] = src[(long)(r0 + i * 4) * 256 + c];
    __syncthreads();
    uint2* dst = wt + (long)ld * 65536;
#pragma unroll
    for (int i = 0; i < 4; i++) {
        int kql = r0 + i * 4;          // 0..15
        H2U ua, ub;
        ua.h[0] = (_Float16)tile[c][4 * kql + 0];
        ua.h[1] = (_Float16)tile[c][4 * kql + 1];
        ub.h[0] = (_Float16)tile[c][4 * kql + 2];
        ub.h[1] = (_Float16)tile[c][4 * kql + 3];
        dst[(long)(kt * 16 + kql) * 1024 + rt * 64 + c] = make_uint2(ua.u, ub.u);
    }
}

// ---------------- generic fp32 GEMM: C = alpha*A@op(B) + bias0 + bias1 ----------------
#define GT 128
#define GK 16
__global__ __launch_bounds__(256) void gemm_k(
    const float* __restrict__ A, int lda, long sA, int amode,
    const float* __restrict__ Bm, int ldb, long sB, int transB,
    float* __restrict__ C, int ldc, long sC,
    int N, int K,
    const float* __restrict__ bias0, const float* __restrict__ bias1, float alpha)
{
    A  += (long)blockIdx.z * sA;
    Bm += (long)blockIdx.z * sB;
    C  += (long)blockIdx.z * sC;
    const int m0 = blockIdx.x * GT, n0 = blockIdx.y * GT;
    __shared__ float As[GK][GT + 4];
    __shared__ float Bs[GK][GT + 4];
    const int tid = threadIdx.x;
    const int tm = (tid & 15) * 4;
    const int tn = (tid >> 4) * 4;
    float acc[8][8];
#pragma unroll
    for (int i = 0; i < 8; i++)
#pragma unroll
        for (int j = 0; j < 8; j++) acc[i][j] = 0.f;
    const int lr = tid >> 2;
    const int lk = (tid & 3) * 4;

    for (int k0 = 0; k0 < K; k0 += GK) {
#pragma unroll
        for (int p = 0; p < 2; p++) {
            int m = m0 + p * 64 + lr;
            long rowoff = (amode == 0) ? ((long)m * lda)
                                       : ((long)m * 128 + (long)(m >> 8) * 256);
            float4 v = *(const float4*)(A + rowoff + k0 + lk);
            As[lk + 0][p * 64 + lr] = v.x;
            As[lk + 1][p * 64 + lr] = v.y;
            As[lk + 2][p * 64 + lr] = v.z;
            As[lk + 3][p * 64 + lr] = v.w;
        }
        if (transB) {
#pragma unroll
            for (int p = 0; p < 2; p++) {
                int n = n0 + p * 64 + lr;
                float4 v = make_float4(0.f, 0.f, 0.f, 0.f);
                if (n < N) v = *(const float4*)(Bm + (long)n * ldb + k0 + lk);
                Bs[lk + 0][p * 64 + lr] = v.x;
                Bs[lk + 1][p * 64 + lr] = v.y;
                Bs[lk + 2][p * 64 + lr] = v.z;
                Bs[lk + 3][p * 64 + lr] = v.w;
            }
        } else {
            int kk = tid >> 4;
            int nn = (tid & 15) * 8;
            float4 v0 = *(const float4*)(Bm + (long)(k0 + kk) * ldb + n0 + nn);
            float4 v1 = *(const float4*)(Bm + (long)(k0 + kk) * ldb + n0 + nn + 4);
            *(float4*)&Bs[kk][nn] = v0;
            *(float4*)&Bs[kk][nn + 4] = v1;
        }
        __syncthreads();
#pragma unroll
        for (int kk = 0; kk < GK; kk++) {
            float4 a0 = *(const float4*)&As[kk][tm];
            float4 a1 = *(const float4*)&As[kk][tm + 64];
            float4 b0 = *(const float4*)&Bs[kk][tn];
            float4 b1 = *(const float4*)&Bs[kk][tn + 64];
            float av[8] = {a0.x, a0.y, a0.z, a0.w, a1.x, a1.y, a1.z, a1.w};
            float bv[8] = {b0.x, b0.y, b0.z, b0.w, b1.x, b1.y, b1.z, b1.w};
#pragma unroll
            for (int i = 0; i < 8; i++)
#pragma unroll
                for (int j = 0; j < 8; j++)
                    acc[i][j] = fmaf(av[i], bv[j], acc[i][j]);
        }
        __syncthreads();
    }
#pragma unroll
    for (int i = 0; i < 8; i++) {
        int m = m0 + ((i < 4) ? (tm + i) : (tm + 64 + i - 4));
#pragma unroll
        for (int j = 0; j < 8; j++) {
            int n = n0 + ((j < 4) ? (tn + j) : (tn + 64 + j - 4));
            if (n < N) {
                float v = alpha * acc[i][j];
                if (bias0) v += bias0[n];
                if (bias1) v += bias1[n];
                C[(long)m * ldc + n] = v;
            }
        }
    }
}

// ---------------- fp16 MFMA GEMM: C = A(MxK) @ B(NxK)^T + bias0 + bias1 ----------------
// 128x128 tile, 2x2 waves of 64x64, BK=32, v_mfma_f32_16x16x32_f16.
// LDS rows padded to 40 halves (80B = 20-bank stride -> 2-way aliasing, free).
__global__ __launch_bounds__(256) void hgemm_k(
    const _Float16* __restrict__ A,   // [M][K] row-major
    const _Float16* __restrict__ Bm,  // [N][K] row-major
    float* __restrict__ C, int K, int ldc,
    const float* __restrict__ bias0, const float* __restrict__ bias1)
{
    const int m0 = blockIdx.x * 128, n0 = blockIdx.y * 128;
    const int tid = threadIdx.x;
    const int lane = tid & 63, wave = tid >> 6;
    const int wm = (wave & 1) * 64, wn = (wave >> 1) * 64;
    __shared__ _Float16 As[128][40];
    __shared__ _Float16 Bs[128][40];
    f4x acc[4][4];
#pragma unroll
    for (int i = 0; i < 4; i++)
#pragma unroll
        for (int j = 0; j < 4; j++) acc[i][j] = (f4x){0.f, 0.f, 0.f, 0.f};

    const int sr = tid & 127;            // staging row
    const int sk = (tid >> 7) * 16;      // staging k-offset (0 or 16)
    const int fm = lane & 15, fq = lane >> 4;

    for (int k0 = 0; k0 < K; k0 += 32) {
        const uint4* ga = (const uint4*)(A + (long)(m0 + sr) * K + k0 + sk);
        const uint4* gb = (const uint4*)(Bm + (long)(n0 + sr) * K + k0 + sk);
        uint4 va0 = ga[0], va1 = ga[1];
        uint4 vb0 = gb[0], vb1 = gb[1];
        *(uint4*)&As[sr][sk] = va0; *(uint4*)&As[sr][sk + 8] = va1;
        *(uint4*)&Bs[sr][sk] = vb0; *(uint4*)&Bs[sr][sk + 8] = vb1;
        __syncthreads();
        h8 af[4], bf[4];
#pragma unroll
        for (int i = 0; i < 4; i++) af[i] = *(const h8*)&As[wm + i * 16 + fm][fq * 8];
#pragma unroll
        for (int i = 0; i < 4; i++) bf[i] = *(const h8*)&Bs[wn + i * 16 + fm][fq * 8];
#pragma unroll
        for (int i = 0; i < 4; i++)
#pragma unroll
            for (int j = 0; j < 4; j++)
                acc[i][j] = __builtin_amdgcn_mfma_f32_16x16x32_f16(af[i], bf[j], acc[i][j], 0, 0, 0);
        __syncthreads();
    }
    const int col = lane & 15, rowb = (lane >> 4) * 4;
#pragma unroll
    for (int i = 0; i < 4; i++) {
#pragma unroll
        for (int j = 0; j < 4; j++) {
            int n = n0 + wn + j * 16 + col;
            float bsum = bias0[n] + bias1[n];
#pragma unroll
            for (int r = 0; r < 4; r++) {
                int m = m0 + wm + i * 16 + rowb + r;
                C[(long)m * ldc + n] = acc[i][j][r] + bsum;
            }
        }
    }
}

// ---------------- row softmax over 256 cols ----------------
__global__ __launch_bounds__(256) void softmax_k(float* __restrict__ scores)
{
    int row = blockIdx.x * 4 + (threadIdx.x >> 6);
    int lane = threadIdx.x & 63;
    float4* p = (float4*)(scores + (long)row * 256);
    float4 v = p[lane];
    float m = fmaxf(fmaxf(v.x, v.y), fmaxf(v.z, v.w));
#pragma unroll
    for (int off = 32; off; off >>= 1) m = fmaxf(m, __shfl_xor(m, off));
    v.x = __expf(v.x - m); v.y = __expf(v.y - m);
    v.z = __expf(v.z - m); v.w = __expf(v.w - m);
    float s = v.x + v.y + v.z + v.w;
#pragma unroll
    for (int off = 32; off; off >>= 1) s += __shfl_xor(s, off);
    float inv = 1.f / s;
    v.x *= inv; v.y *= inv; v.z *= inv; v.w *= inv;
    p[lane] = v;
}

// ---------------- BiLSTM recurrence v3: cached fp16 weights + fdot2 ----------------
__global__ __launch_bounds__(512) void lstm_k(
    const float* __restrict__ preF, const float* __restrict__ preB,
    const uint4* __restrict__ wtL,  // layer base: [2 dir][64 kq][512 rp] uint4
    float* __restrict__ out)        // [BT][512], cols dir*256+j
{
    const int dir = blockIdx.x & 1;
    const int b0  = (blockIdx.x >> 1) * 2;
    const int tid = threadIdx.x;
    const int r0  = tid * 2;
    __shared__ uint4 wlds[6][512];
    __shared__ uint4 hq[64];
    __shared__ float gl[2][1024];
    __shared__ float hraw[2][256];
    const float* pre = dir ? preB : preF;
    const uint4* W = wtL + (long)dir * 32768;

    uint4 wreg[26];
#pragma unroll
    for (int i = 0; i < 26; i++) wreg[i] = W[i * 512 + tid];
#pragma unroll
    for (int i = 0; i < 6; i++) wlds[i][tid] = W[(26 + i) * 512 + tid];
    float c0 = 0.f, c1 = 0.f;
    __syncthreads();

#define DOT(WV, HV) do {                                                         \
    H2U wx, wy, wz, ww, hx, hy, hz, hw;                                          \
    wx.u = (WV).x; wy.u = (WV).y; wz.u = (WV).z; ww.u = (WV).w;                  \
    hx.u = (HV).x; hy.u = (HV).y; hz.u = (HV).z; hw.u = (HV).w;                  \
    a00 = __builtin_amdgcn_fdot2(wx.h, hx.h, a00, false);                        \
    a00 = __builtin_amdgcn_fdot2(wy.h, hy.h, a00, false);                        \
    a01 = __builtin_amdgcn_fdot2(wx.h, hz.h, a01, false);                        \
    a01 = __builtin_amdgcn_fdot2(wy.h, hw.h, a01, false);                        \
    a10 = __builtin_amdgcn_fdot2(wz.h, hx.h, a10, false);                        \
    a10 = __builtin_amdgcn_fdot2(ww.h, hy.h, a10, false);                        \
    a11 = __builtin_amdgcn_fdot2(wz.h, hz.h, a11, false);                        \
    a11 = __builtin_amdgcn_fdot2(ww.h, hw.h, a11, false);                        \
} while (0)

    for (int t = 0; t < 256; t++) {
        const int tpre = dir ? (255 - t) : t;
        float2 p0 = *(const float2*)(pre + ((long)b0 * 256 + tpre) * 1024 + r0);
        float2 p1 = *(const float2*)(pre + ((long)(b0 + 1) * 256 + tpre) * 1024 + r0);
        float a00 = p0.x, a10 = p0.y, a01 = p1.x, a11 = p1.y;
        if (t > 0) {
            uint4 sA[8], sB[8];
#pragma unroll
            for (int i = 0; i < 8; i++) sA[i] = W[(32 + i) * 512 + tid];
#pragma unroll
            for (int i = 0; i < 26; i++) { uint4 hv = hq[i]; DOT(wreg[i], hv); }
#pragma unroll
            for (int i = 0; i < 8; i++) sB[i] = W[(40 + i) * 512 + tid];
#pragma unroll
            for (int i = 0; i < 6; i++) { uint4 wv = wlds[i][tid]; uint4 hv = hq[26 + i]; DOT(wv, hv); }
#pragma unroll
            for (int i = 0; i < 8; i++) { uint4 hv = hq[32 + i]; DOT(sA[i], hv); }
#pragma unroll
            for (int i = 0; i < 8; i++) sA[i] = W[(48 + i) * 512 + tid];
#pragma unroll
            for (int i = 0; i < 8; i++) { uint4 hv = hq[40 + i]; DOT(sB[i], hv); }
#pragma unroll
            for (int i = 0; i < 8; i++) sB[i] = W[(56 + i) * 512 + tid];
#pragma unroll
            for (int i = 0; i < 8; i++) { uint4 hv = hq[48 + i]; DOT(sA[i], hv); }
#pragma unroll
            for (int i = 0; i < 8; i++) { uint4 hv = hq[56 + i]; DOT(sB[i], hv); }
        }
        *(float2*)&gl[0][r0] = make_float2(a00, a10);
        *(float2*)&gl[1][r0] = make_float2(a01, a11);
        __syncthreads();
        if (tid < 256) {
            const int j = tid;
            float i0 = gl[0][j], f0 = gl[0][256 + j], g0 = gl[0][512 + j], o0 = gl[0][768 + j];
            float i1 = gl[1][j], f1 = gl[1][256 + j], g1 = gl[1][512 + j], o1 = gl[1][768 + j];
            float si0 = 1.f / (1.f + __expf(-i0)), sf0 = 1.f / (1.f + __expf(-f0));
            float so0 = 1.f / (1.f + __expf(-o0));
            float si1 = 1.f / (1.f + __expf(-i1)), sf1 = 1.f / (1.f + __expf(-f1));
            float so1 = 1.f / (1.f + __expf(-o1));
            c0 = sf0 * c0 + si0 * tanhf(g0);
            c1 = sf1 * c1 + si1 * tanhf(g1);
            float h0v = so0 * tanhf(c0);
            float h1v = so1 * tanhf(c1);
            hraw[0][j] = h0v;
            hraw[1][j] = h1v;
            out[((long)b0 * 256 + tpre) * 512 + dir * 256 + j] = h0v;
            out[((long)(b0 + 1) * 256 + tpre) * 512 + dir * 256 + j] = h1v;
        }
        __syncthreads();
        if (tid < 64) {
            int k4 = tid * 4;
            H2U u0, u1, u2, u3;
            u0.h[0] = (_Float16)hraw[0][k4 + 0]; u0.h[1] = (_Float16)hraw[0][k4 + 1];
            u1.h[0] = (_Float16)hraw[0][k4 + 2]; u1.h[1] = (_Float16)hraw[0][k4 + 3];
            u2.h[0] = (_Float16)hraw[1][k4 + 0]; u2.h[1] = (_Float16)hraw[1][k4 + 1];
            u3.h[0] = (_Float16)hraw[1][k4 + 2]; u3.h[1] = (_Float16)hraw[1][k4 + 3];
            hq[tid] = make_uint4(u0.u, u1.u, u2.u, u3.u);
        }
        __syncthreads();
    }
#undef DOT
}

// ---------------- CRF NLL + Viterbi (register-cached T columns, vectorized) ----------------
__global__ __launch_bounds__(128) void crf_k(
    const float* __restrict__ emit, const float* __restrict__ trans,
    const int* __restrict__ labels, float* __restrict__ outv)
{
    const int b = blockIdx.x & 63;
    const bool vit = blockIdx.x >= 64;
    const int tid = threadIdx.x;
    __shared__ float Tl[NG * NG];
    __shared__ __align__(16) float bufA[68];
    __shared__ __align__(16) float bufB[68];
    __shared__ unsigned char bp[256][NG];
    __shared__ float redv[128];
    for (int i = tid; i < NG * NG; i += 128) Tl[i] = trans[i];
    __syncthreads();
    const float* eb = emit + (long)b * 256 * NG;

    float tcol[68];
    if (tid < NG) {
#pragma unroll
        for (int i = 0; i < NG; i++) tcol[i] = Tl[i * NG + tid];
    }
    tcol[66] = 0.f; tcol[67] = 0.f;
    if (tid < NG) bufA[tid] = Tl[START_ * NG + tid] + eb[tid];
    if (tid == 66 || tid == 67) { bufA[tid] = -1e30f; bufB[tid] = -1e30f; }
    __syncthreads();

    if (!vit) {
        for (int t = 1; t < 256; t++) {
            const float* prev = (t & 1) ? bufA : bufB;
            float* cur  = (t & 1) ? bufB : bufA;
            float e_t = (tid < NG) ? eb[t * NG + tid] : 0.f;
            if (tid < NG) {
                float pv[68];
#pragma unroll
                for (int c = 0; c < 17; c++) {
                    float4 p4 = *(const float4*)&prev[c * 4];
                    pv[c * 4 + 0] = p4.x + tcol[c * 4 + 0];
                    pv[c * 4 + 1] = p4.y + tcol[c * 4 + 1];
                    pv[c * 4 + 2] = p4.z + tcol[c * 4 + 2];
                    pv[c * 4 + 3] = p4.w + tcol[c * 4 + 3];
                }
                float m0 = -1e30f, m1 = -1e30f, m2 = -1e30f, m3 = -1e30f;
#pragma unroll
                for (int c = 0; c < 17; c++) {
                    m0 = fmaxf(m0, pv[c * 4 + 0]);
                    m1 = fmaxf(m1, pv[c * 4 + 1]);
                    m2 = fmaxf(m2, pv[c * 4 + 2]);
                    m3 = fmaxf(m3, pv[c * 4 + 3]);
                }
                float m = fmaxf(fmaxf(m0, m1), fmaxf(m2, m3));
                float s0 = 0.f, s1 = 0.f, s2 = 0.f, s3 = 0.f;
#pragma unroll
                for (int c = 0; c < 17; c++) {
                    s0 += __expf(pv[c * 4 + 0] - m);
                    s1 += __expf(pv[c * 4 + 1] - m);
                    s2 += __expf(pv[c * 4 + 2] - m);
                    s3 += __expf(pv[c * 4 + 3] - m);
                }
                cur[tid] = m + __logf((s0 + s1) + (s2 + s3)) + e_t;
            }
            __syncthreads();
        }
        const int* lab = labels + b * 256;
        float g = 0.f;
        for (int t = tid; t < 256; t += 128) g += eb[t * NG + lab[t]];
        for (int t = tid; t < 255; t += 128) g += Tl[lab[t] * NG + lab[t + 1]];
        redv[tid] = g;
        __syncthreads();
        if (tid == 0) {
            float* fin = bufB;
            float m = -1e30f;
            for (int j = 0; j < NG; j++) m = fmaxf(m, fin[j] + Tl[j * NG + STOP_]);
            float s = 0.f;
            for (int j = 0; j < NG; j++) s += __expf(fin[j] + Tl[j * NG + STOP_] - m);
            float logZ = m + __logf(s);
            float gold = Tl[START_ * NG + lab[0]] + Tl[lab[255] * NG + STOP_];
            for (int i = 0; i < 128; i++) gold += redv[i];
            atomicAdd(outv, logZ - gold);
        }
    } else {
        for (int t = 1; t < 256; t++) {
            const float* prev = (t & 1) ? bufA : bufB;
            float* cur  = (t & 1) ? bufB : bufA;
            float e_t = (tid < NG) ? eb[t * NG + tid] : 0.f;
            if (tid < NG) {
                float m = -1e30f; int arg = 0;
#pragma unroll
                for (int c = 0; c < 17; c++) {
                    float4 p4 = *(const float4*)&prev[c * 4];
                    float v0 = p4.x + tcol[c * 4 + 0];
                    float v1 = p4.y + tcol[c * 4 + 1];
                    float v2 = p4.z + tcol[c * 4 + 2];
                    float v3 = p4.w + tcol[c * 4 + 3];
                    if (v0 > m) { m = v0; arg = c * 4 + 0; }
                    if (v1 > m) { m = v1; arg = c * 4 + 1; }
                    if (v2 > m) { m = v2; arg = c * 4 + 2; }
                    if (v3 > m) { m = v3; arg = c * 4 + 3; }
                }
                bp[t][tid] = (unsigned char)arg;
                cur[tid] = m + e_t;
            }
            __syncthreads();
        }
        if (tid == 0) {
            float* fin = bufB;
            float m = -1e30f; int tag = 0;
            for (int j = 0; j < NG; j++) {
                float v = fin[j] + Tl[j * NG + STOP_];
                if (v > m) { m = v; tag = j; }
            }
            float* od = outv + 1 + (long)b * 256;
            od[255] = (float)tag;
            for (int t = 255; t >= 1; t--) { tag = bp[t][tag]; od[t - 1] = (float)tag; }
        }
    }
}

// ---------------- host ----------------
extern "C" void kernel_launch(void* const* d_in, const int* in_sizes, int n_in,
                              void* d_out, int out_size, void* d_ws, size_t ws_size,
                              hipStream_t stream)
{
    const int*   batch_word    = (const int*)d_in[0];
    const int*   batch_intents = (const int*)d_in[1];
    const int*   batch_char    = (const int*)d_in[3];
    const int*   batch_lexi    = (const int*)d_in[6];
    const int*   batch_label   = (const int*)d_in[7];
    const float* char_emb      = (const float*)d_in[8];
    const float* word_emb      = (const float*)d_in[9];
    const float* lexi_emb      = (const float*)d_in[10];
    const float* intent_emb    = (const float*)d_in[11];
    const float* conv_w        = (const float*)d_in[12];
    const float* conv_b        = (const float*)d_in[13];
    const float* w_ih          = (const float*)d_in[14];
    const float* w_hh          = (const float*)d_in[15];
    const float* b_ih          = (const float*)d_in[16];
    const float* b_hh          = (const float*)d_in[17];
    const float* proj_w        = (const float*)d_in[18];
    const float* proj_b        = (const float*)d_in[19];
    const float* trans         = (const float*)d_in[20];
    float* out = (float*)d_out;
    float* ws  = (float*)d_ws;

    float* ce_pad   = ws + OFF_CEPAD;
    float* q        = ws + OFF_Q;
    float* kv       = ws + OFF_KV;
    float* preF     = ws + OFF_PREF;
    float* scores   = ws + OFF_SC;
    float* x        = ws + OFF_X;
    float* y        = ws + OFF_Y;
    float* preB     = ws + OFF_PREB;
    float* emit     = ws + OFF_EMIT;
    uint2* wt_u2    = (uint2*)(ws + OFF_WT);
    float* w2       = ws + OFF_W2;
    _Float16* wih_h = (_Float16*)(ws + OFF_WIH);
    _Float16* xh    = (_Float16*)(ws + OFF_XH);

    embed_k<<<BT, 128, 0, stream>>>(batch_word, batch_intents, batch_char, batch_lexi,
                                    word_emb, lexi_emb, intent_emb, char_emb, kv, q, ce_pad);
    prep_k<<<(384 * 384 + 255) / 256, 256, 0, stream>>>(conv_w, w2, out);
    wt_k<<<256, 256, 0, stream>>>(w_hh, wt_u2);

    // char CNN as GEMM (A gathered from ce_pad), C into q cols 0..383
    gemm_k<<<dim3(128, 3, 1), 256, 0, stream>>>(ce_pad, 0, 0L, 1,
                                                w2, 384, 0L, 1,
                                                q, 512, 0L, 384, 384,
                                                conv_b, nullptr, 1.f);
    // attention scores = q @ kv^T / TEMP  (batched)
    gemm_k<<<dim3(2, 2, NB), 256, 0, stream>>>(q, 512, 131072L, 0,
                                               kv, 512, 131072L, 1,
                                               scores, 256, 65536L, 256, 512,
                                               nullptr, nullptr, INV_TEMP);
    softmax_k<<<4096, 256, 0, stream>>>(scores);
    // x = softmax(scores) @ kv
    gemm_k<<<dim3(2, 4, NB), 256, 0, stream>>>(scores, 256, 65536L, 0,
                                               kv, 512, 131072L, 0,
                                               x, 512, 131072L, 512, 256,
                                               nullptr, nullptr, 1.f);

    // w_ih -> fp16 (kv-tail gap now dead): 4*1024*512 = 2,097,152 elems / 4 per thread
    cvt_k<<<2048, 256, 0, stream>>>(w_ih, (unsigned*)wih_h);

    for (int l = 0; l < 2; l++) {
        const float* xin = l ? y : x;
        float* xout = l ? x : y;
        // xin -> fp16 (scores region dead after x-GEMM): 16384*512 = 8,388,608 elems
        cvt_k<<<8192, 256, 0, stream>>>(xin, (unsigned*)xh);
        for (int d = 0; d < 2; d++) {
            hgemm_k<<<dim3(128, 8, 1), 256, 0, stream>>>(
                xh, wih_h + (long)(l * 2 + d) * 1024 * 512,
                d ? preB : preF, 512, 1024,
                b_ih + (l * 2 + d) * 1024, b_hh + (l * 2 + d) * 1024);
        }
        lstm_k<<<64, 512, 0, stream>>>(preF, preB,
                                       (const uint4*)(wt_u2 + (long)l * 2 * 65536), xout);
    }

    // emissions (overwrites wt region — wt is dead after last lstm)
    gemm_k<<<dim3(128, 1, 1), 256, 0, stream>>>(x, 512, 0L, 0,
                                                proj_w, 512, 0L, 1,
                                                emit, NG, 0L, NG, 512,
                                                proj_b, nullptr, 1.f);
    // CRF NLL (blocks 0..63) + Viterbi (blocks 64..127)
    crf_k<<<128, 128, 0, stream>>>(emit, trans, batch_label, out);
}

// Round 7
// 2122.954 us; speedup vs baseline: 5.7741x; 1.2969x over previous
//
#include <hip/hip_runtime.h>

// ---------------- problem constants ----------------
#define NB 64
#define NT 256
#define BT 16384          // NB*NT
#define NG 66
#define START_ 64
#define STOP_ 65
#define INV_TEMP 0.08838834764831845f  // 1/sqrt(128)

typedef _Float16 half2_t __attribute__((ext_vector_type(2)));
typedef _Float16 h8 __attribute__((ext_vector_type(8)));
typedef float f4x __attribute__((ext_vector_type(4)));
union H2U { unsigned u; half2_t h; };

// ---------------- workspace layout (float offsets) ----------------
#define OFF_CEPAD 0L
#define OFF_Q     2113536L
#define OFF_KV    10502144L
#define OFF_PREF  0L
#define OFF_WIH   16777216L
#define OFF_XH    18890752L
#define OFF_SC    18890752L
#define OFF_X     23085056L
#define OFF_Y     31473664L
#define OFF_PREB  39862272L
#define OFF_EMIT  56639488L
#define OFF_WT    56639488L
#define OFF_W2    57720832L

// ---------------- embedding / gather ----------------
__global__ __launch_bounds__(128) void embed_k(
    const int* __restrict__ word, const int* __restrict__ intents,
    const int* __restrict__ chars, const int* __restrict__ lexi,
    const float* __restrict__ word_emb, const float* __restrict__ lexi_emb,
    const float* __restrict__ intent_emb, const float* __restrict__ char_emb,
    float* __restrict__ kv, float* __restrict__ q, float* __restrict__ ce_pad)
{
    int bt = blockIdx.x;
    int b = bt >> 8, t = bt & 255;
    int tid = threadIdx.x;
    const float4* wrow = (const float4*)(word_emb + (long)word[bt] * 256);
    const float4* lrow = (const float4*)(lexi_emb + (long)lexi[bt] * 128);
    const float4* irow = (const float4*)(intent_emb + (long)intents[b] * 128);
    const float4* crow = (const float4*)(char_emb + (long)chars[bt] * 128);
    float4* kvrow = (float4*)(kv + (long)bt * 512);
    float4* qrow  = (float4*)(q  + (long)bt * 512);
    float4* cerow = (float4*)(ce_pad + ((long)b * 258 + t + 1) * 128);
    if (tid < 64)       kvrow[tid] = wrow[tid];
    else if (tid < 96)  kvrow[tid] = lrow[tid - 64];
    else { float4 v = irow[tid - 96]; kvrow[tid] = v; qrow[tid] = v; }
    if (tid < 32) cerow[tid] = crow[tid];
    if (t == 0) {
        float4 z = make_float4(0.f, 0.f, 0.f, 0.f);
        if (tid < 32)      ((float4*)(ce_pad + (long)b * 258 * 128))[tid] = z;
        else if (tid < 64) ((float4*)(ce_pad + ((long)b * 258 + 257) * 128))[tid - 32] = z;
    }
}

// repack conv_w (O,C,K) -> w2[o][k*128+c]; zero loss slot
__global__ __launch_bounds__(256) void prep_k(const float* __restrict__ conv_w,
                                              float* __restrict__ w2,
                                              float* __restrict__ out0)
{
    int idx = blockIdx.x * 256 + threadIdx.x;
    if (idx == 0) out0[0] = 0.f;
    if (idx < 384 * 384) {
        int o = idx / 384, r = idx % 384;
        int k = r >> 7, c = r & 127;
        w2[o * 384 + r] = conv_w[o * 384 + c * 3 + k];
    }
}

// fp32 -> fp16 elementwise (n multiple of 1024; 4 elems/thread)
__global__ __launch_bounds__(256) void cvt_k(const float* __restrict__ src,
                                             unsigned* __restrict__ dst)
{
    long i = ((long)blockIdx.x * 256 + threadIdx.x);
    float4 v = ((const float4*)src)[i];
    H2U a, b;
    a.h[0] = (_Float16)v.x; a.h[1] = (_Float16)v.y;
    b.h[0] = (_Float16)v.z; b.h[1] = (_Float16)v.w;
    ((uint2*)dst)[i] = make_uint2(a.u, b.u);
}

// transpose+pack w_hh fp32 [4 ld][1024 row][256 k]
//   -> wt fp16 uint2 [4 ld][64 kq][1024 row], uint2 = {h2(k4q,k4q+1), h2(k4q+2,k4q+3)}
__global__ __launch_bounds__(256) void wt_k(const float* __restrict__ whh,
                                            uint2* __restrict__ wt)
{
    int bid = blockIdx.x;
    int ld = bid >> 6;
    int rt = (bid >> 2) & 15;
    int kt = bid & 3;
    const float* src = whh + ((long)ld * 1024 + rt * 64) * 256 + kt * 64;
    __shared__ float tile[64][65];
    int c = threadIdx.x & 63, r0 = threadIdx.x >> 6;  // r0 in 0..3
#pragma unroll
    for (int i = 0; i < 16; i++)
        tile[r0 + i * 4][c] = src[(long)(r0 + i * 4) * 256 + c];
    __syncthreads();
    uint2* dst = wt + (long)ld * 65536;
#pragma unroll
    for (int i = 0; i < 4; i++) {
        int kql = r0 + i * 4;          // 0..15
        H2U ua, ub;
        ua.h[0] = (_Float16)tile[c][4 * kql + 0];
        ua.h[1] = (_Float16)tile[c][4 * kql + 1];
        ub.h[0] = (_Float16)tile[c][4 * kql + 2];
        ub.h[1] = (_Float16)tile[c][4 * kql + 3];
        dst[(long)(kt * 16 + kql) * 1024 + rt * 64 + c] = make_uint2(ua.u, ub.u);
    }
}

// ---------------- generic fp32 GEMM: C = alpha*A@op(B) + bias0 + bias1 ----------------
#define GT 128
#define GK 16
__global__ __launch_bounds__(256) void gemm_k(
    const float* __restrict__ A, int lda, long sA, int amode,
    const float* __restrict__ Bm, int ldb, long sB, int transB,
    float* __restrict__ C, int ldc, long sC,
    int N, int K,
    const float* __restrict__ bias0, const float* __restrict__ bias1, float alpha)
{
    A  += (long)blockIdx.z * sA;
    Bm += (long)blockIdx.z * sB;
    C  += (long)blockIdx.z * sC;
    const int m0 = blockIdx.x * GT, n0 = blockIdx.y * GT;
    __shared__ float As[GK][GT + 4];
    __shared__ float Bs[GK][GT + 4];
    const int tid = threadIdx.x;
    const int tm = (tid & 15) * 4;
    const int tn = (tid >> 4) * 4;
    float acc[8][8];
#pragma unroll
    for (int i = 0; i < 8; i++)
#pragma unroll
        for (int j = 0; j < 8; j++) acc[i][j] = 0.f;
    const int lr = tid >> 2;
    const int lk = (tid & 3) * 4;

    for (int k0 = 0; k0 < K; k0 += GK) {
#pragma unroll
        for (int p = 0; p < 2; p++) {
            int m = m0 + p * 64 + lr;
            long rowoff = (amode == 0) ? ((long)m * lda)
                                       : ((long)m * 128 + (long)(m >> 8) * 256);
            float4 v = *(const float4*)(A + rowoff + k0 + lk);
            As[lk + 0][p * 64 + lr] = v.x;
            As[lk + 1][p * 64 + lr] = v.y;
            As[lk + 2][p * 64 + lr] = v.z;
            As[lk + 3][p * 64 + lr] = v.w;
        }
        if (transB) {
#pragma unroll
            for (int p = 0; p < 2; p++) {
                int n = n0 + p * 64 + lr;
                float4 v = make_float4(0.f, 0.f, 0.f, 0.f);
                if (n < N) v = *(const float4*)(Bm + (long)n * ldb + k0 + lk);
                Bs[lk + 0][p * 64 + lr] = v.x;
                Bs[lk + 1][p * 64 + lr] = v.y;
                Bs[lk + 2][p * 64 + lr] = v.z;
                Bs[lk + 3][p * 64 + lr] = v.w;
            }
        } else {
            int kk = tid >> 4;
            int nn = (tid & 15) * 8;
            float4 v0 = *(const float4*)(Bm + (long)(k0 + kk) * ldb + n0 + nn);
            float4 v1 = *(const float4*)(Bm + (long)(k0 + kk) * ldb + n0 + nn + 4);
            *(float4*)&Bs[kk][nn] = v0;
            *(float4*)&Bs[kk][nn + 4] = v1;
        }
        __syncthreads();
#pragma unroll
        for (int kk = 0; kk < GK; kk++) {
            float4 a0 = *(const float4*)&As[kk][tm];
            float4 a1 = *(const float4*)&As[kk][tm + 64];
            float4 b0 = *(const float4*)&Bs[kk][tn];
            float4 b1 = *(const float4*)&Bs[kk][tn + 64];
            float av[8] = {a0.x, a0.y, a0.z, a0.w, a1.x, a1.y, a1.z, a1.w};
            float bv[8] = {b0.x, b0.y, b0.z, b0.w, b1.x, b1.y, b1.z, b1.w};
#pragma unroll
            for (int i = 0; i < 8; i++)
#pragma unroll
                for (int j = 0; j < 8; j++)
                    acc[i][j] = fmaf(av[i], bv[j], acc[i][j]);
        }
        __syncthreads();
    }
#pragma unroll
    for (int i = 0; i < 8; i++) {
        int m = m0 + ((i < 4) ? (tm + i) : (tm + 64 + i - 4));
#pragma unroll
        for (int j = 0; j < 8; j++) {
            int n = n0 + ((j < 4) ? (tn + j) : (tn + 64 + j - 4));
            if (n < N) {
                float v = alpha * acc[i][j];
                if (bias0) v += bias0[n];
                if (bias1) v += bias1[n];
                C[(long)m * ldc + n] = v;
            }
        }
    }
}

// ---------------- fp16 MFMA GEMM: C = A(MxK) @ B(NxK)^T + bias0 + bias1 ----------------
__global__ __launch_bounds__(256) void hgemm_k(
    const _Float16* __restrict__ A,   // [M][K] row-major
    const _Float16* __restrict__ Bm,  // [N][K] row-major
    float* __restrict__ C, int K, int ldc,
    const float* __restrict__ bias0, const float* __restrict__ bias1)
{
    const int m0 = blockIdx.x * 128, n0 = blockIdx.y * 128;
    const int tid = threadIdx.x;
    const int lane = tid & 63, wave = tid >> 6;
    const int wm = (wave & 1) * 64, wn = (wave >> 1) * 64;
    __shared__ _Float16 As[128][40];
    __shared__ _Float16 Bs[128][40];
    f4x acc[4][4];
#pragma unroll
    for (int i = 0; i < 4; i++)
#pragma unroll
        for (int j = 0; j < 4; j++) acc[i][j] = (f4x){0.f, 0.f, 0.f, 0.f};

    const int sr = tid & 127;            // staging row
    const int sk = (tid >> 7) * 16;      // staging k-offset (0 or 16)
    const int fm = lane & 15, fq = lane >> 4;

    for (int k0 = 0; k0 < K; k0 += 32) {
        const uint4* ga = (const uint4*)(A + (long)(m0 + sr) * K + k0 + sk);
        const uint4* gb = (const uint4*)(Bm + (long)(n0 + sr) * K + k0 + sk);
        uint4 va0 = ga[0], va1 = ga[1];
        uint4 vb0 = gb[0], vb1 = gb[1];
        *(uint4*)&As[sr][sk] = va0; *(uint4*)&As[sr][sk + 8] = va1;
        *(uint4*)&Bs[sr][sk] = vb0; *(uint4*)&Bs[sr][sk + 8] = vb1;
        __syncthreads();
        h8 af[4], bf[4];
#pragma unroll
        for (int i = 0; i < 4; i++) af[i] = *(const h8*)&As[wm + i * 16 + fm][fq * 8];
#pragma unroll
        for (int i = 0; i < 4; i++) bf[i] = *(const h8*)&Bs[wn + i * 16 + fm][fq * 8];
#pragma unroll
        for (int i = 0; i < 4; i++)
#pragma unroll
            for (int j = 0; j < 4; j++)
                acc[i][j] = __builtin_amdgcn_mfma_f32_16x16x32_f16(af[i], bf[j], acc[i][j], 0, 0, 0);
        __syncthreads();
    }
    const int col = lane & 15, rowb = (lane >> 4) * 4;
#pragma unroll
    for (int i = 0; i < 4; i++) {
#pragma unroll
        for (int j = 0; j < 4; j++) {
            int n = n0 + wn + j * 16 + col;
            float bsum = bias0[n] + bias1[n];
#pragma unroll
            for (int r = 0; r < 4; r++) {
                int m = m0 + wm + i * 16 + rowb + r;
                C[(long)m * ldc + n] = acc[i][j][r] + bsum;
            }
        }
    }
}

// ---------------- row softmax over 256 cols ----------------
__global__ __launch_bounds__(256) void softmax_k(float* __restrict__ scores)
{
    int row = blockIdx.x * 4 + (threadIdx.x >> 6);
    int lane = threadIdx.x & 63;
    float4* p = (float4*)(scores + (long)row * 256);
    float4 v = p[lane];
    float m = fmaxf(fmaxf(v.x, v.y), fmaxf(v.z, v.w));
#pragma unroll
    for (int off = 32; off; off >>= 1) m = fmaxf(m, __shfl_xor(m, off));
    v.x = __expf(v.x - m); v.y = __expf(v.y - m);
    v.z = __expf(v.z - m); v.w = __expf(v.w - m);
    float s = v.x + v.y + v.z + v.w;
#pragma unroll
    for (int off = 32; off; off >>= 1) s += __shfl_xor(s, off);
    float inv = 1.f / s;
    v.x *= inv; v.y *= inv; v.z *= inv; v.w *= inv;
    p[lane] = v;
}

// ---------------- BiLSTM recurrence v4: 1 batch/block, 128 blocks ----------------
// 128 blocks = 2 dirs x 64 batches; 512 threads (2 waves/SIMD); thread owns 2 gate-rows.
// W split per step: kq 0..39 register-cached (160 VGPR), kq 40..45 LDS (48 KB),
// kq 46..63 streamed (144 KB/step) in 3 chunks of 6 (issue covered by cached compute).
// h stored directly as fp16 in LDS by update threads (no pack phase, 2 barriers/step).
__global__ __launch_bounds__(512, 2) void lstm_k(
    const float* __restrict__ preF, const float* __restrict__ preB,
    const uint4* __restrict__ wtL,  // layer base: [2 dir][64 kq][512 rp] uint4
    float* __restrict__ out)        // [BT][512], cols dir*256+j
{
    const int dir = blockIdx.x & 1;
    const int b   = blockIdx.x >> 1;
    const int tid = threadIdx.x;
    const int r0  = tid * 2;            // 2 consecutive gate-rows per thread
    __shared__ uint4 wlds[6][512];      // kq 40..45 (48 KB)
    __shared__ __align__(8) _Float16 hq16[256];
    __shared__ float gl[1024];
    const float* pre = (dir ? preB : preF) + (long)b * 256 * 1024;
    const uint4* W = wtL + (long)dir * 32768;   // 64 kq * 512 rp

    uint4 wreg[40];
#pragma unroll
    for (int i = 0; i < 40; i++) wreg[i] = W[i * 512 + tid];
#pragma unroll
    for (int i = 0; i < 6; i++) wlds[i][tid] = W[(40 + i) * 512 + tid];
    float cst = 0.f;
    __syncthreads();

#define DOT(WV, HV) do {                                                         \
    H2U wx, wy, wz, ww, hx, hy;                                                  \
    wx.u = (WV).x; wy.u = (WV).y; wz.u = (WV).z; ww.u = (WV).w;                  \
    hx.u = (HV).x; hy.u = (HV).y;                                                \
    a0 = __builtin_amdgcn_fdot2(wx.h, hx.h, a0, false);                          \
    a0 = __builtin_amdgcn_fdot2(wy.h, hy.h, a0, false);                          \
    a1 = __builtin_amdgcn_fdot2(wz.h, hx.h, a1, false);                          \
    a1 = __builtin_amdgcn_fdot2(ww.h, hy.h, a1, false);                          \
} while (0)

    for (int t = 0; t < 256; t++) {
        const int tpre = dir ? (255 - t) : t;
        float2 p = *(const float2*)(pre + (long)tpre * 1024 + r0);
        float a0 = 0.f, a1 = 0.f;
        if (t > 0) {
            uint4 s0[6], s1[6];
            // issue chunk A (kq 46..51) — covered by reg compute
#pragma unroll
            for (int i = 0; i < 6; i++) s0[i] = W[(46 + i) * 512 + tid];
            // register-cached kq 0..39
#pragma unroll
            for (int i = 0; i < 40; i++) {
                uint2 hv = *(const uint2*)&hq16[i * 4];
                DOT(wreg[i], hv);
            }
            // issue chunk B (kq 52..57)
#pragma unroll
            for (int i = 0; i < 6; i++) s1[i] = W[(52 + i) * 512 + tid];
            // LDS-cached kq 40..45
#pragma unroll
            for (int i = 0; i < 6; i++) {
                uint4 wv = wlds[i][tid];
                uint2 hv = *(const uint2*)&hq16[(40 + i) * 4];
                DOT(wv, hv);
            }
            // consume A, refill with chunk C (kq 58..63)
#pragma unroll
            for (int i = 0; i < 6; i++) {
                uint2 hv = *(const uint2*)&hq16[(46 + i) * 4];
                DOT(s0[i], hv);
            }
#pragma unroll
            for (int i = 0; i < 6; i++) s0[i] = W[(58 + i) * 512 + tid];
            // consume B
#pragma unroll
            for (int i = 0; i < 6; i++) {
                uint2 hv = *(const uint2*)&hq16[(52 + i) * 4];
                DOT(s1[i], hv);
            }
            // consume C
#pragma unroll
            for (int i = 0; i < 6; i++) {
                uint2 hv = *(const uint2*)&hq16[(58 + i) * 4];
                DOT(s0[i], hv);
            }
        }
        *(float2*)&gl[r0] = make_float2(a0 + p.x, a1 + p.y);
        __syncthreads();
        // ---- update phase: tid<256, thread owns h-dim j ----
        if (tid < 256) {
            const int j = tid;
            float gi = gl[j], gf = gl[256 + j], gg = gl[512 + j], go = gl[768 + j];
            float si = 1.f / (1.f + __expf(-gi));
            float sf = 1.f / (1.f + __expf(-gf));
            float so = 1.f / (1.f + __expf(-go));
            cst = sf * cst + si * tanhf(gg);
            float h = so * tanhf(cst);
            hq16[j] = (_Float16)h;
            out[((long)b * 256 + tpre) * 512 + dir * 256 + j] = h;
        }
        __syncthreads();
    }
#undef DOT
}

// ---------------- CRF NLL + Viterbi (register-cached T columns, vectorized) ----------------
__global__ __launch_bounds__(128) void crf_k(
    const float* __restrict__ emit, const float* __restrict__ trans,
    const int* __restrict__ labels, float* __restrict__ outv)
{
    const int b = blockIdx.x & 63;
    const bool vit = blockIdx.x >= 64;
    const int tid = threadIdx.x;
    __shared__ float Tl[NG * NG];
    __shared__ __align__(16) float bufA[68];
    __shared__ __align__(16) float bufB[68];
    __shared__ unsigned char bp[256][NG];
    __shared__ float redv[128];
    for (int i = tid; i < NG * NG; i += 128) Tl[i] = trans[i];
    __syncthreads();
    const float* eb = emit + (long)b * 256 * NG;

    float tcol[68];
    if (tid < NG) {
#pragma unroll
        for (int i = 0; i < NG; i++) tcol[i] = Tl[i * NG + tid];
    }
    tcol[66] = 0.f; tcol[67] = 0.f;
    if (tid < NG) bufA[tid] = Tl[START_ * NG + tid] + eb[tid];
    if (tid == 66 || tid == 67) { bufA[tid] = -1e30f; bufB[tid] = -1e30f; }
    __syncthreads();

    if (!vit) {
        for (int t = 1; t < 256; t++) {
            const float* prev = (t & 1) ? bufA : bufB;
            float* cur  = (t & 1) ? bufB : bufA;
            float e_t = (tid < NG) ? eb[t * NG + tid] : 0.f;
            if (tid < NG) {
                float pv[68];
#pragma unroll
                for (int c = 0; c < 17; c++) {
                    float4 p4 = *(const float4*)&prev[c * 4];
                    pv[c * 4 + 0] = p4.x + tcol[c * 4 + 0];
                    pv[c * 4 + 1] = p4.y + tcol[c * 4 + 1];
                    pv[c * 4 + 2] = p4.z + tcol[c * 4 + 2];
                    pv[c * 4 + 3] = p4.w + tcol[c * 4 + 3];
                }
                float m0 = -1e30f, m1 = -1e30f, m2 = -1e30f, m3 = -1e30f;
#pragma unroll
                for (int c = 0; c < 17; c++) {
                    m0 = fmaxf(m0, pv[c * 4 + 0]);
                    m1 = fmaxf(m1, pv[c * 4 + 1]);
                    m2 = fmaxf(m2, pv[c * 4 + 2]);
                    m3 = fmaxf(m3, pv[c * 4 + 3]);
                }
                float m = fmaxf(fmaxf(m0, m1), fmaxf(m2, m3));
                float s0 = 0.f, s1 = 0.f, s2 = 0.f, s3 = 0.f;
#pragma unroll
                for (int c = 0; c < 17; c++) {
                    s0 += __expf(pv[c * 4 + 0] - m);
                    s1 += __expf(pv[c * 4 + 1] - m);
                    s2 += __expf(pv[c * 4 + 2] - m);
                    s3 += __expf(pv[c * 4 + 3] - m);
                }
                cur[tid] = m + __logf((s0 + s1) + (s2 + s3)) + e_t;
            }
            __syncthreads();
        }
        const int* lab = labels + b * 256;
        float g = 0.f;
        for (int t = tid; t < 256; t += 128) g += eb[t * NG + lab[t]];
        for (int t = tid; t < 255; t += 128) g += Tl[lab[t] * NG + lab[t + 1]];
        redv[tid] = g;
        __syncthreads();
        if (tid == 0) {
            float* fin = bufB;
            float m = -1e30f;
            for (int j = 0; j < NG; j++) m = fmaxf(m, fin[j] + Tl[j * NG + STOP_]);
            float s = 0.f;
            for (int j = 0; j < NG; j++) s += __expf(fin[j] + Tl[j * NG + STOP_] - m);
            float logZ = m + __logf(s);
            float gold = Tl[START_ * NG + lab[0]] + Tl[lab[255] * NG + STOP_];
            for (int i = 0; i < 128; i++) gold += redv[i];
            atomicAdd(outv, logZ - gold);
        }
    } else {
        for (int t = 1; t < 256; t++) {
            const float* prev = (t & 1) ? bufA : bufB;
            float* cur  = (t & 1) ? bufB : bufA;
            float e_t = (tid < NG) ? eb[t * NG + tid] : 0.f;
            if (tid < NG) {
                float m = -1e30f; int arg = 0;
#pragma unroll
                for (int c = 0; c < 17; c++) {
                    float4 p4 = *(const float4*)&prev[c * 4];
                    float v0 = p4.x + tcol[c * 4 + 0];
                    float v1 = p4.y + tcol[c * 4 + 1];
                    float v2 = p4.z + tcol[c * 4 + 2];
                    float v3 = p4.w + tcol[c * 4 + 3];
                    if (v0 > m) { m = v0; arg = c * 4 + 0; }
                    if (v1 > m) { m = v1; arg = c * 4 + 1; }
                    if (v2 > m) { m = v2; arg = c * 4 + 2; }
                    if (v3 > m) { m = v3; arg = c * 4 + 3; }
                }
                bp[t][tid] = (unsigned char)arg;
                cur[tid] = m + e_t;
            }
            __syncthreads();
        }
        if (tid == 0) {
            float* fin = bufB;
            float m = -1e30f; int tag = 0;
            for (int j = 0; j < NG; j++) {
                float v = fin[j] + Tl[j * NG + STOP_];
                if (v > m) { m = v; tag = j; }
            }
            float* od = outv + 1 + (long)b * 256;
            od[255] = (float)tag;
            for (int t = 255; t >= 1; t--) { tag = bp[t][tag]; od[t - 1] = (float)tag; }
        }
    }
}

// ---------------- host ----------------
extern "C" void kernel_launch(void* const* d_in, const int* in_sizes, int n_in,
                              void* d_out, int out_size, void* d_ws, size_t ws_size,
                              hipStream_t stream)
{
    const int*   batch_word    = (const int*)d_in[0];
    const int*   batch_intents = (const int*)d_in[1];
    const int*   batch_char    = (const int*)d_in[3];
    const int*   batch_lexi    = (const int*)d_in[6];
    const int*   batch_label   = (const int*)d_in[7];
    const float* char_emb      = (const float*)d_in[8];
    const float* word_emb      = (const float*)d_in[9];
    const float* lexi_emb      = (const float*)d_in[10];
    const float* intent_emb    = (const float*)d_in[11];
    const float* conv_w        = (const float*)d_in[12];
    const float* conv_b        = (const float*)d_in[13];
    const float* w_ih          = (const float*)d_in[14];
    const float* w_hh          = (const float*)d_in[15];
    const float* b_ih          = (const float*)d_in[16];
    const float* b_hh          = (const float*)d_in[17];
    const float* proj_w        = (const float*)d_in[18];
    const float* proj_b        = (const float*)d_in[19];
    const float* trans         = (const float*)d_in[20];
    float* out = (float*)d_out;
    float* ws  = (float*)d_ws;

    float* ce_pad   = ws + OFF_CEPAD;
    float* q        = ws + OFF_Q;
    float* kv       = ws + OFF_KV;
    float* preF     = ws + OFF_PREF;
    float* scores   = ws + OFF_SC;
    float* x        = ws + OFF_X;
    float* y        = ws + OFF_Y;
    float* preB     = ws + OFF_PREB;
    float* emit     = ws + OFF_EMIT;
    uint2* wt_u2    = (uint2*)(ws + OFF_WT);
    float* w2       = ws + OFF_W2;
    _Float16* wih_h = (_Float16*)(ws + OFF_WIH);
    _Float16* xh    = (_Float16*)(ws + OFF_XH);

    embed_k<<<BT, 128, 0, stream>>>(batch_word, batch_intents, batch_char, batch_lexi,
                                    word_emb, lexi_emb, intent_emb, char_emb, kv, q, ce_pad);
    prep_k<<<(384 * 384 + 255) / 256, 256, 0, stream>>>(conv_w, w2, out);
    wt_k<<<256, 256, 0, stream>>>(w_hh, wt_u2);

    // char CNN as GEMM (A gathered from ce_pad), C into q cols 0..383
    gemm_k<<<dim3(128, 3, 1), 256, 0, stream>>>(ce_pad, 0, 0L, 1,
                                                w2, 384, 0L, 1,
                                                q, 512, 0L, 384, 384,
                                                conv_b, nullptr, 1.f);
    // attention scores = q @ kv^T / TEMP  (batched)
    gemm_k<<<dim3(2, 2, NB), 256, 0, stream>>>(q, 512, 131072L, 0,
                                               kv, 512, 131072L, 1,
                                               scores, 256, 65536L, 256, 512,
                                               nullptr, nullptr, INV_TEMP);
    softmax_k<<<4096, 256, 0, stream>>>(scores);
    // x = softmax(scores) @ kv
    gemm_k<<<dim3(2, 4, NB), 256, 0, stream>>>(scores, 256, 65536L, 0,
                                               kv, 512, 131072L, 0,
                                               x, 512, 131072L, 512, 256,
                                               nullptr, nullptr, 1.f);

    // w_ih -> fp16 (kv-tail gap now dead)
    cvt_k<<<2048, 256, 0, stream>>>(w_ih, (unsigned*)wih_h);

    for (int l = 0; l < 2; l++) {
        const float* xin = l ? y : x;
        float* xout = l ? x : y;
        cvt_k<<<8192, 256, 0, stream>>>(xin, (unsigned*)xh);
        for (int d = 0; d < 2; d++) {
            hgemm_k<<<dim3(128, 8, 1), 256, 0, stream>>>(
                xh, wih_h + (long)(l * 2 + d) * 1024 * 512,
                d ? preB : preF, 512, 1024,
                b_ih + (l * 2 + d) * 1024, b_hh + (l * 2 + d) * 1024);
        }
        lstm_k<<<128, 512, 0, stream>>>(preF, preB,
                                        (const uint4*)(wt_u2 + (long)l * 2 * 65536), xout);
    }

    // emissions (overwrites wt region — wt is dead after last lstm)
    gemm_k<<<dim3(128, 1, 1), 256, 0, stream>>>(x, 512, 0L, 0,
                                                proj_w, 512, 0L, 1,
                                                emit, NG, 0L, NG, 512,
                                                proj_b, nullptr, 1.f);
    // CRF NLL (blocks 0..63) + Viterbi (blocks 64..127)
    crf_k<<<128, 128, 0, stream>>>(emit, trans, batch_label, out);
}

// Round 8
// 1901.904 us; speedup vs baseline: 6.4452x; 1.1162x over previous
//
#include <hip/hip_runtime.h>

// ---------------- problem constants ----------------
#define NB 64
#define NT 256
#define BT 16384          // NB*NT
#define NG 66
#define START_ 64
#define STOP_ 65
#define INV_TEMP 0.08838834764831845f  // 1/sqrt(128)

typedef _Float16 half2_t __attribute__((ext_vector_type(2)));
typedef _Float16 h8 __attribute__((ext_vector_type(8)));
typedef float f4x __attribute__((ext_vector_type(4)));
union H2U { unsigned u; half2_t h; };

// ---------------- workspace layout (float offsets) ----------------
#define OFF_CEPAD 0L
#define OFF_Q     2113536L
#define OFF_KV    10502144L
#define OFF_PREF  0L
#define OFF_WIH   16777216L
#define OFF_XH    18890752L
#define OFF_SC    18890752L
#define OFF_X     23085056L
#define OFF_Y     31473664L
#define OFF_PREB  39862272L
#define OFF_EMIT  56639488L
#define OFF_WT    56639488L
#define OFF_W2    57720832L

__device__ __forceinline__ float fsig(float x) {
    return 1.f / (1.f + __expf(-x));
}
__device__ __forceinline__ float ftanh(float x) {
    float xc = fminf(fmaxf(x, -15.f), 15.f);
    float e = __expf(2.f * xc);
    return (e - 1.f) / (e + 1.f);
}

// ---------------- embedding / gather ----------------
__global__ __launch_bounds__(128) void embed_k(
    const int* __restrict__ word, const int* __restrict__ intents,
    const int* __restrict__ chars, const int* __restrict__ lexi,
    const float* __restrict__ word_emb, const float* __restrict__ lexi_emb,
    const float* __restrict__ intent_emb, const float* __restrict__ char_emb,
    float* __restrict__ kv, float* __restrict__ q, float* __restrict__ ce_pad)
{
    int bt = blockIdx.x;
    int b = bt >> 8, t = bt & 255;
    int tid = threadIdx.x;
    const float4* wrow = (const float4*)(word_emb + (long)word[bt] * 256);
    const float4* lrow = (const float4*)(lexi_emb + (long)lexi[bt] * 128);
    const float4* irow = (const float4*)(intent_emb + (long)intents[b] * 128);
    const float4* crow = (const float4*)(char_emb + (long)chars[bt] * 128);
    float4* kvrow = (float4*)(kv + (long)bt * 512);
    float4* qrow  = (float4*)(q  + (long)bt * 512);
    float4* cerow = (float4*)(ce_pad + ((long)b * 258 + t + 1) * 128);
    if (tid < 64)       kvrow[tid] = wrow[tid];
    else if (tid < 96)  kvrow[tid] = lrow[tid - 64];
    else { float4 v = irow[tid - 96]; kvrow[tid] = v; qrow[tid] = v; }
    if (tid < 32) cerow[tid] = crow[tid];
    if (t == 0) {
        float4 z = make_float4(0.f, 0.f, 0.f, 0.f);
        if (tid < 32)      ((float4*)(ce_pad + (long)b * 258 * 128))[tid] = z;
        else if (tid < 64) ((float4*)(ce_pad + ((long)b * 258 + 257) * 128))[tid - 32] = z;
    }
}

// repack conv_w (O,C,K) -> w2[o][k*128+c]; zero loss slot
__global__ __launch_bounds__(256) void prep_k(const float* __restrict__ conv_w,
                                              float* __restrict__ w2,
                                              float* __restrict__ out0)
{
    int idx = blockIdx.x * 256 + threadIdx.x;
    if (idx == 0) out0[0] = 0.f;
    if (idx < 384 * 384) {
        int o = idx / 384, r = idx % 384;
        int k = r >> 7, c = r & 127;
        w2[o * 384 + r] = conv_w[o * 384 + c * 3 + k];
    }
}

// fp32 -> fp16 elementwise (n multiple of 1024; 4 elems/thread)
__global__ __launch_bounds__(256) void cvt_k(const float* __restrict__ src,
                                             unsigned* __restrict__ dst)
{
    long i = ((long)blockIdx.x * 256 + threadIdx.x);
    float4 v = ((const float4*)src)[i];
    H2U a, b;
    a.h[0] = (_Float16)v.x; a.h[1] = (_Float16)v.y;
    b.h[0] = (_Float16)v.z; b.h[1] = (_Float16)v.w;
    ((uint2*)dst)[i] = make_uint2(a.u, b.u);
}

// transpose+pack w_hh fp32 [4 ld][1024 row][256 k]
//   -> wt fp16 uint2 [4 ld][64 kq][1024 row], uint2 = {h2(k4q,k4q+1), h2(k4q+2,k4q+3)}
__global__ __launch_bounds__(256) void wt_k(const float* __restrict__ whh,
                                            uint2* __restrict__ wt)
{
    int bid = blockIdx.x;
    int ld = bid >> 6;
    int rt = (bid >> 2) & 15;
    int kt = bid & 3;
    const float* src = whh + ((long)ld * 1024 + rt * 64) * 256 + kt * 64;
    __shared__ float tile[64][65];
    int c = threadIdx.x & 63, r0 = threadIdx.x >> 6;  // r0 in 0..3
#pragma unroll
    for (int i = 0; i < 16; i++)
        tile[r0 + i * 4][c] = src[(long)(r0 + i * 4) * 256 + c];
    __syncthreads();
    uint2* dst = wt + (long)ld * 65536;
#pragma unroll
    for (int i = 0; i < 4; i++) {
        int kql = r0 + i * 4;          // 0..15
        H2U ua, ub;
        ua.h[0] = (_Float16)tile[c][4 * kql + 0];
        ua.h[1] = (_Float16)tile[c][4 * kql + 1];
        ub.h[0] = (_Float16)tile[c][4 * kql + 2];
        ub.h[1] = (_Float16)tile[c][4 * kql + 3];
        dst[(long)(kt * 16 + kql) * 1024 + rt * 64 + c] = make_uint2(ua.u, ub.u);
    }
}

// ---------------- generic fp32 GEMM: C = alpha*A@op(B) + bias0 + bias1 ----------------
#define GT 128
#define GK 16
__global__ __launch_bounds__(256) void gemm_k(
    const float* __restrict__ A, int lda, long sA, int amode,
    const float* __restrict__ Bm, int ldb, long sB, int transB,
    float* __restrict__ C, int ldc, long sC,
    int N, int K,
    const float* __restrict__ bias0, const float* __restrict__ bias1, float alpha)
{
    A  += (long)blockIdx.z * sA;
    Bm += (long)blockIdx.z * sB;
    C  += (long)blockIdx.z * sC;
    const int m0 = blockIdx.x * GT, n0 = blockIdx.y * GT;
    __shared__ float As[GK][GT + 4];
    __shared__ float Bs[GK][GT + 4];
    const int tid = threadIdx.x;
    const int tm = (tid & 15) * 4;
    const int tn = (tid >> 4) * 4;
    float acc[8][8];
#pragma unroll
    for (int i = 0; i < 8; i++)
#pragma unroll
        for (int j = 0; j < 8; j++) acc[i][j] = 0.f;
    const int lr = tid >> 2;
    const int lk = (tid & 3) * 4;

    for (int k0 = 0; k0 < K; k0 += GK) {
#pragma unroll
        for (int p = 0; p < 2; p++) {
            int m = m0 + p * 64 + lr;
            long rowoff = (amode == 0) ? ((long)m * lda)
                                       : ((long)m * 128 + (long)(m >> 8) * 256);
            float4 v = *(const float4*)(A + rowoff + k0 + lk);
            As[lk + 0][p * 64 + lr] = v.x;
            As[lk + 1][p * 64 + lr] = v.y;
            As[lk + 2][p * 64 + lr] = v.z;
            As[lk + 3][p * 64 + lr] = v.w;
        }
        if (transB) {
#pragma unroll
            for (int p = 0; p < 2; p++) {
                int n = n0 + p * 64 + lr;
                float4 v = make_float4(0.f, 0.f, 0.f, 0.f);
                if (n < N) v = *(const float4*)(Bm + (long)n * ldb + k0 + lk);
                Bs[lk + 0][p * 64 + lr] = v.x;
                Bs[lk + 1][p * 64 + lr] = v.y;
                Bs[lk + 2][p * 64 + lr] = v.z;
                Bs[lk + 3][p * 64 + lr] = v.w;
            }
        } else {
            int kk = tid >> 4;
            int nn = (tid & 15) * 8;
            float4 v0 = *(const float4*)(Bm + (long)(k0 + kk) * ldb + n0 + nn);
            float4 v1 = *(const float4*)(Bm + (long)(k0 + kk) * ldb + n0 + nn + 4);
            *(float4*)&Bs[kk][nn] = v0;
            *(float4*)&Bs[kk][nn + 4] = v1;
        }
        __syncthreads();
#pragma unroll
        for (int kk = 0; kk < GK; kk++) {
            float4 a0 = *(const float4*)&As[kk][tm];
            float4 a1 = *(const float4*)&As[kk][tm + 64];
            float4 b0 = *(const float4*)&Bs[kk][tn];
            float4 b1 = *(const float4*)&Bs[kk][tn + 64];
            float av[8] = {a0.x, a0.y, a0.z, a0.w, a1.x, a1.y, a1.z, a1.w};
            float bv[8] = {b0.x, b0.y, b0.z, b0.w, b1.x, b1.y, b1.z, b1.w};
#pragma unroll
            for (int i = 0; i < 8; i++)
#pragma unroll
                for (int j = 0; j < 8; j++)
                    acc[i][j] = fmaf(av[i], bv[j], acc[i][j]);
        }
        __syncthreads();
    }
#pragma unroll
    for (int i = 0; i < 8; i++) {
        int m = m0 + ((i < 4) ? (tm + i) : (tm + 64 + i - 4));
#pragma unroll
        for (int j = 0; j < 8; j++) {
            int n = n0 + ((j < 4) ? (tn + j) : (tn + 64 + j - 4));
            if (n < N) {
                float v = alpha * acc[i][j];
                if (bias0) v += bias0[n];
                if (bias1) v += bias1[n];
                C[(long)m * ldc + n] = v;
            }
        }
    }
}

// ---------------- fp16 MFMA GEMM: C = A(MxK) @ B(NxK)^T + bias0 + bias1 ----------------
__global__ __launch_bounds__(256) void hgemm_k(
    const _Float16* __restrict__ A,   // [M][K] row-major
    const _Float16* __restrict__ Bm,  // [N][K] row-major
    float* __restrict__ C, int K, int ldc,
    const float* __restrict__ bias0, const float* __restrict__ bias1)
{
    const int m0 = blockIdx.x * 128, n0 = blockIdx.y * 128;
    const int tid = threadIdx.x;
    const int lane = tid & 63, wave = tid >> 6;
    const int wm = (wave & 1) * 64, wn = (wave >> 1) * 64;
    __shared__ _Float16 As[128][40];
    __shared__ _Float16 Bs[128][40];
    f4x acc[4][4];
#pragma unroll
    for (int i = 0; i < 4; i++)
#pragma unroll
        for (int j = 0; j < 4; j++) acc[i][j] = (f4x){0.f, 0.f, 0.f, 0.f};

    const int sr = tid & 127;            // staging row
    const int sk = (tid >> 7) * 16;      // staging k-offset (0 or 16)
    const int fm = lane & 15, fq = lane >> 4;

    for (int k0 = 0; k0 < K; k0 += 32) {
        const uint4* ga = (const uint4*)(A + (long)(m0 + sr) * K + k0 + sk);
        const uint4* gb = (const uint4*)(Bm + (long)(n0 + sr) * K + k0 + sk);
        uint4 va0 = ga[0], va1 = ga[1];
        uint4 vb0 = gb[0], vb1 = gb[1];
        *(uint4*)&As[sr][sk] = va0; *(uint4*)&As[sr][sk + 8] = va1;
        *(uint4*)&Bs[sr][sk] = vb0; *(uint4*)&Bs[sr][sk + 8] = vb1;
        __syncthreads();
        h8 af[4], bf[4];
#pragma unroll
        for (int i = 0; i < 4; i++) af[i] = *(const h8*)&As[wm + i * 16 + fm][fq * 8];
#pragma unroll
        for (int i = 0; i < 4; i++) bf[i] = *(const h8*)&Bs[wn + i * 16 + fm][fq * 8];
#pragma unroll
        for (int i = 0; i < 4; i++)
#pragma unroll
            for (int j = 0; j < 4; j++)
                acc[i][j] = __builtin_amdgcn_mfma_f32_16x16x32_f16(af[i], bf[j], acc[i][j], 0, 0, 0);
        __syncthreads();
    }
    const int col = lane & 15, rowb = (lane >> 4) * 4;
#pragma unroll
    for (int i = 0; i < 4; i++) {
#pragma unroll
        for (int j = 0; j < 4; j++) {
            int n = n0 + wn + j * 16 + col;
            float bsum = bias0[n] + bias1[n];
#pragma unroll
            for (int r = 0; r < 4; r++) {
                int m = m0 + wm + i * 16 + rowb + r;
                C[(long)m * ldc + n] = acc[i][j][r] + bsum;
            }
        }
    }
}

// ---------------- row softmax over 256 cols ----------------
__global__ __launch_bounds__(256) void softmax_k(float* __restrict__ scores)
{
    int row = blockIdx.x * 4 + (threadIdx.x >> 6);
    int lane = threadIdx.x & 63;
    float4* p = (float4*)(scores + (long)row * 256);
    float4 v = p[lane];
    float m = fmaxf(fmaxf(v.x, v.y), fmaxf(v.z, v.w));
#pragma unroll
    for (int off = 32; off; off >>= 1) m = fmaxf(m, __shfl_xor(m, off));
    v.x = __expf(v.x - m); v.y = __expf(v.y - m);
    v.z = __expf(v.z - m); v.w = __expf(v.w - m);
    float s = v.x + v.y + v.z + v.w;
#pragma unroll
    for (int off = 32; off; off >>= 1) s += __shfl_xor(s, off);
    float inv = 1.f / s;
    v.x *= inv; v.y *= inv; v.z *= inv; v.w *= inv;
    p[lane] = v;
}

// ---------------- BiLSTM recurrence v5: balanced weight pipes ----------------
// 128 blocks = 2 dirs x 64 batches; 512 threads; 1 block/CU; thread owns 2 gate-rows.
// W split per step, balanced to the ~1024-cyc VALU floor:
//   kq  0..39 : register-cached (160 VGPR incl. AGPR half of unified file)
//   kq 40..55 : LDS-cached (128 KB; LDS pipe ~1000 cyc/step)
//   kq 56..63 : streamed from L2 (64 KB/step ~1000 cyc, issued before cached compute)
__global__ __launch_bounds__(512, 2) void lstm_k(
    const float* __restrict__ preF, const float* __restrict__ preB,
    const uint4* __restrict__ wtL,  // layer base: [2 dir][64 kq][512 rp] uint4
    float* __restrict__ out)        // [BT][512], cols dir*256+j
{
    const int dir = blockIdx.x & 1;
    const int b   = blockIdx.x >> 1;
    const int tid = threadIdx.x;
    const int r0  = tid * 2;            // 2 consecutive gate-rows per thread
    __shared__ uint4 wlds[16][512];     // kq 40..55 (128 KB)
    __shared__ __align__(8) _Float16 hq16[256];
    __shared__ float gl[1024];
    const float* pre = (dir ? preB : preF) + (long)b * 256 * 1024;
    const uint4* W = wtL + (long)dir * 32768;   // 64 kq * 512 rp

    uint4 wreg[40];
#pragma unroll
    for (int i = 0; i < 40; i++) wreg[i] = W[i * 512 + tid];
#pragma unroll
    for (int i = 0; i < 16; i++) wlds[i][tid] = W[(40 + i) * 512 + tid];
    float cst = 0.f;
    __syncthreads();

#define DOT(WV, HV) do {                                                         \
    H2U wx, wy, wz, ww, hx, hy;                                                  \
    wx.u = (WV).x; wy.u = (WV).y; wz.u = (WV).z; ww.u = (WV).w;                  \
    hx.u = (HV).x; hy.u = (HV).y;                                                \
    a0 = __builtin_amdgcn_fdot2(wx.h, hx.h, a0, false);                          \
    a0 = __builtin_amdgcn_fdot2(wy.h, hy.h, a0, false);                          \
    a1 = __builtin_amdgcn_fdot2(wz.h, hx.h, a1, false);                          \
    a1 = __builtin_amdgcn_fdot2(ww.h, hy.h, a1, false);                          \
} while (0)

    for (int t = 0; t < 256; t++) {
        const int tpre = dir ? (255 - t) : t;
        float2 p = *(const float2*)(pre + (long)tpre * 1024 + r0);
        float a0 = 0.f, a1 = 0.f;
        if (t > 0) {
            uint4 s0[8];
            // issue streamed chunk (kq 56..63) — latency covered by cached compute
#pragma unroll
            for (int i = 0; i < 8; i++) s0[i] = W[(56 + i) * 512 + tid];
            // register-cached kq 0..39
#pragma unroll
            for (int i = 0; i < 40; i++) {
                uint2 hv = *(const uint2*)&hq16[i * 4];
                DOT(wreg[i], hv);
            }
            // LDS-cached kq 40..55
#pragma unroll
            for (int i = 0; i < 16; i++) {
                uint4 wv = wlds[i][tid];
                uint2 hv = *(const uint2*)&hq16[(40 + i) * 4];
                DOT(wv, hv);
            }
            // consume streamed chunk
#pragma unroll
            for (int i = 0; i < 8; i++) {
                uint2 hv = *(const uint2*)&hq16[(56 + i) * 4];
                DOT(s0[i], hv);
            }
        }
        *(float2*)&gl[r0] = make_float2(a0 + p.x, a1 + p.y);
        __syncthreads();
        // ---- update phase: tid<256, thread owns h-dim j ----
        if (tid < 256) {
            const int j = tid;
            float gi = gl[j], gf = gl[256 + j], gg = gl[512 + j], go = gl[768 + j];
            float si = fsig(gi), sf = fsig(gf), so = fsig(go);
            cst = sf * cst + si * ftanh(gg);
            float h = so * ftanh(cst);
            hq16[j] = (_Float16)h;
            out[((long)b * 256 + tpre) * 512 + dir * 256 + j] = h;
        }
        __syncthreads();
    }
#undef DOT
}

// ---------------- CRF NLL + Viterbi (register-cached T columns, vectorized) ----------------
__global__ __launch_bounds__(128) void crf_k(
    const float* __restrict__ emit, const float* __restrict__ trans,
    const int* __restrict__ labels, float* __restrict__ outv)
{
    const int b = blockIdx.x & 63;
    const bool vit = blockIdx.x >= 64;
    const int tid = threadIdx.x;
    __shared__ float Tl[NG * NG];
    __shared__ __align__(16) float bufA[68];
    __shared__ __align__(16) float bufB[68];
    __shared__ unsigned char bp[256][NG];
    __shared__ float redv[128];
    for (int i = tid; i < NG * NG; i += 128) Tl[i] = trans[i];
    __syncthreads();
    const float* eb = emit + (long)b * 256 * NG;

    float tcol[68];
    if (tid < NG) {
#pragma unroll
        for (int i = 0; i < NG; i++) tcol[i] = Tl[i * NG + tid];
    }
    tcol[66] = 0.f; tcol[67] = 0.f;
    if (tid < NG) bufA[tid] = Tl[START_ * NG + tid] + eb[tid];
    if (tid == 66 || tid == 67) { bufA[tid] = -1e30f; bufB[tid] = -1e30f; }
    __syncthreads();

    if (!vit) {
        for (int t = 1; t < 256; t++) {
            const float* prev = (t & 1) ? bufA : bufB;
            float* cur  = (t & 1) ? bufB : bufA;
            float e_t = (tid < NG) ? eb[t * NG + tid] : 0.f;
            if (tid < NG) {
                float pv[68];
#pragma unroll
                for (int c = 0; c < 17; c++) {
                    float4 p4 = *(const float4*)&prev[c * 4];
                    pv[c * 4 + 0] = p4.x + tcol[c * 4 + 0];
                    pv[c * 4 + 1] = p4.y + tcol[c * 4 + 1];
                    pv[c * 4 + 2] = p4.z + tcol[c * 4 + 2];
                    pv[c * 4 + 3] = p4.w + tcol[c * 4 + 3];
                }
                float m0 = -1e30f, m1 = -1e30f, m2 = -1e30f, m3 = -1e30f;
#pragma unroll
                for (int c = 0; c < 17; c++) {
                    m0 = fmaxf(m0, pv[c * 4 + 0]);
                    m1 = fmaxf(m1, pv[c * 4 + 1]);
                    m2 = fmaxf(m2, pv[c * 4 + 2]);
                    m3 = fmaxf(m3, pv[c * 4 + 3]);
                }
                float m = fmaxf(fmaxf(m0, m1), fmaxf(m2, m3));
                float s0 = 0.f, s1 = 0.f, s2 = 0.f, s3 = 0.f;
#pragma unroll
                for (int c = 0; c < 17; c++) {
                    s0 += __expf(pv[c * 4 + 0] - m);
                    s1 += __expf(pv[c * 4 + 1] - m);
                    s2 += __expf(pv[c * 4 + 2] - m);
                    s3 += __expf(pv[c * 4 + 3] - m);
                }
                cur[tid] = m + __logf((s0 + s1) + (s2 + s3)) + e_t;
            }
            __syncthreads();
        }
        const int* lab = labels + b * 256;
        float g = 0.f;
        for (int t = tid; t < 256; t += 128) g += eb[t * NG + lab[t]];
        for (int t = tid; t < 255; t += 128) g += Tl[lab[t] * NG + lab[t + 1]];
        redv[tid] = g;
        __syncthreads();
        if (tid == 0) {
            float* fin = bufB;
            float m = -1e30f;
            for (int j = 0; j < NG; j++) m = fmaxf(m, fin[j] + Tl[j * NG + STOP_]);
            float s = 0.f;
            for (int j = 0; j < NG; j++) s += __expf(fin[j] + Tl[j * NG + STOP_] - m);
            float logZ = m + __logf(s);
            float gold = Tl[START_ * NG + lab[0]] + Tl[lab[255] * NG + STOP_];
            for (int i = 0; i < 128; i++) gold += redv[i];
            atomicAdd(outv, logZ - gold);
        }
    } else {
        for (int t = 1; t < 256; t++) {
            const float* prev = (t & 1) ? bufA : bufB;
            float* cur  = (t & 1) ? bufB : bufA;
            float e_t = (tid < NG) ? eb[t * NG + tid] : 0.f;
            if (tid < NG) {
                float m = -1e30f; int arg = 0;
#pragma unroll
                for (int c = 0; c < 17; c++) {
                    float4 p4 = *(const float4*)&prev[c * 4];
                    float v0 = p4.x + tcol[c * 4 + 0];
                    float v1 = p4.y + tcol[c * 4 + 1];
                    float v2 = p4.z + tcol[c * 4 + 2];
                    float v3 = p4.w + tcol[c * 4 + 3];
                    if (v0 > m) { m = v0; arg = c * 4 + 0; }
                    if (v1 > m) { m = v1; arg = c * 4 + 1; }
                    if (v2 > m) { m = v2; arg = c * 4 + 2; }
                    if (v3 > m) { m = v3; arg = c * 4 + 3; }
                }
                bp[t][tid] = (unsigned char)arg;
                cur[tid] = m + e_t;
            }
            __syncthreads();
        }
        if (tid == 0) {
            float* fin = bufB;
            float m = -1e30f; int tag = 0;
            for (int j = 0; j < NG; j++) {
                float v = fin[j] + Tl[j * NG + STOP_];
                if (v > m) { m = v; tag = j; }
            }
            float* od = outv + 1 + (long)b * 256;
            od[255] = (float)tag;
            for (int t = 255; t >= 1; t--) { tag = bp[t][tag]; od[t - 1] = (float)tag; }
        }
    }
}

// ---------------- host ----------------
extern "C" void kernel_launch(void* const* d_in, const int* in_sizes, int n_in,
                              void* d_out, int out_size, void* d_ws, size_t ws_size,
                              hipStream_t stream)
{
    const int*   batch_word    = (const int*)d_in[0];
    const int*   batch_intents = (const int*)d_in[1];
    const int*   batch_char    = (const int*)d_in[3];
    const int*   batch_lexi    = (const int*)d_in[6];
    const int*   batch_label   = (const int*)d_in[7];
    const float* char_emb      = (const float*)d_in[8];
    const float* word_emb      = (const float*)d_in[9];
    const float* lexi_emb      = (const float*)d_in[10];
    const float* intent_emb    = (const float*)d_in[11];
    const float* conv_w        = (const float*)d_in[12];
    const float* conv_b        = (const float*)d_in[13];
    const float* w_ih          = (const float*)d_in[14];
    const float* w_hh          = (const float*)d_in[15];
    const float* b_ih          = (const float*)d_in[16];
    const float* b_hh          = (const float*)d_in[17];
    const float* proj_w        = (const float*)d_in[18];
    const float* proj_b        = (const float*)d_in[19];
    const float* trans         = (const float*)d_in[20];
    float* out = (float*)d_out;
    float* ws  = (float*)d_ws;

    float* ce_pad   = ws + OFF_CEPAD;
    float* q        = ws + OFF_Q;
    float* kv       = ws + OFF_KV;
    float* preF     = ws + OFF_PREF;
    float* scores   = ws + OFF_SC;
    float* x        = ws + OFF_X;
    float* y        = ws + OFF_Y;
    float* preB     = ws + OFF_PREB;
    float* emit     = ws + OFF_EMIT;
    uint2* wt_u2    = (uint2*)(ws + OFF_WT);
    float* w2       = ws + OFF_W2;
    _Float16* wih_h = (_Float16*)(ws + OFF_WIH);
    _Float16* xh    = (_Float16*)(ws + OFF_XH);

    embed_k<<<BT, 128, 0, stream>>>(batch_word, batch_intents, batch_char, batch_lexi,
                                    word_emb, lexi_emb, intent_emb, char_emb, kv, q, ce_pad);
    prep_k<<<(384 * 384 + 255) / 256, 256, 0, stream>>>(conv_w, w2, out);
    wt_k<<<256, 256, 0, stream>>>(w_hh, wt_u2);

    // char CNN as GEMM (A gathered from ce_pad), C into q cols 0..383
    gemm_k<<<dim3(128, 3, 1), 256, 0, stream>>>(ce_pad, 0, 0L, 1,
                                                w2, 384, 0L, 1,
                                                q, 512, 0L, 384, 384,
                                                conv_b, nullptr, 1.f);
    // attention scores = q @ kv^T / TEMP  (batched)
    gemm_k<<<dim3(2, 2, NB), 256, 0, stream>>>(q, 512, 131072L, 0,
                                               kv, 512, 131072L, 1,
                                               scores, 256, 65536L, 256, 512,
                                               nullptr, nullptr, INV_TEMP);
    softmax_k<<<4096, 256, 0, stream>>>(scores);
    // x = softmax(scores) @ kv
    gemm_k<<<dim3(2, 4, NB), 256, 0, stream>>>(scores, 256, 65536L, 0,
                                               kv, 512, 131072L, 0,
                                               x, 512, 131072L, 512, 256,
                                               nullptr, nullptr, 1.f);

    // w_ih -> fp16 (kv-tail gap now dead)
    cvt_k<<<2048, 256, 0, stream>>>(w_ih, (unsigned*)wih_h);

    for (int l = 0; l < 2; l++) {
        const float* xin = l ? y : x;
        float* xout = l ? x : y;
        cvt_k<<<8192, 256, 0, stream>>>(xin, (unsigned*)xh);
        for (int d = 0; d < 2; d++) {
            hgemm_k<<<dim3(128, 8, 1), 256, 0, stream>>>(
                xh, wih_h + (long)(l * 2 + d) * 1024 * 512,
                d ? preB : preF, 512, 1024,
                b_ih + (l * 2 + d) * 1024, b_hh + (l * 2 + d) * 1024);
        }
        lstm_k<<<128, 512, 0, stream>>>(preF, preB,
                                        (const uint4*)(wt_u2 + (long)l * 2 * 65536), xout);
    }

    // emissions (overwrites wt region — wt is dead after last lstm)
    gemm_k<<<dim3(128, 1, 1), 256, 0, stream>>>(x, 512, 0L, 0,
                                                proj_w, 512, 0L, 1,
                                                emit, NG, 0L, NG, 512,
                                                proj_b, nullptr, 1.f);
    // CRF NLL (blocks 0..63) + Viterbi (blocks 64..127)
    crf_k<<<128, 128, 0, stream>>>(emit, trans, batch_label, out);
}

// Round 10
// 1660.696 us; speedup vs baseline: 7.3813x; 1.1452x over previous
//
#include <hip/hip_runtime.h>

// ---------------- problem constants ----------------
#define NB 64
#define NT 256
#define BT 16384          // NB*NT
#define NG 66
#define START_ 64
#define STOP_ 65
#define INV_TEMP 0.08838834764831845f  // 1/sqrt(128)

typedef _Float16 half2_t __attribute__((ext_vector_type(2)));
typedef _Float16 h8 __attribute__((ext_vector_type(8)));
typedef float f4x __attribute__((ext_vector_type(4)));
union H2U { unsigned u; half2_t h; };

// ---------------- workspace layout (float offsets) ----------------
// preF fp32 [BT][1024] @ 0          (16,777,216)
//   (attention temporaries alias preF region — all dead before pre-GEMMs:)
//   ce_pad_h fp16 [64][258][128] @ 0          (1,056,768 f)
//   q_h      fp16 [BT][512]      @ 1,056,768  (4,194,304 f)
//   scores   fp32 [64][256][256] @ 5,251,072  (4,194,304 f)
//   P_h      fp16 [64][256][256] @ 9,445,376  (2,097,152 f)
//   kvT_h    fp16 [64][512][256] @ 11,542,528 (4,194,304 f)
// preB fp32 [BT][1024] @ 16,777,216 (16,777,216)
//   kv_h fp16 [BT][512] @ 16,777,216 (4,194,304 f) — dead before preB written
// x1_h fp16 [BT][512] @ 33,554,432 (4,194,304 f)   attn out; later layer-2 out
// y_h  fp16 [BT][512] @ 37,748,736 (4,194,304 f)   layer-1 out
// wt   fp16 [4][64kq][1024] @ 41,943,040 (524,288 f)
// wih_h fp16 [4][1024][512] @ 42,467,328 (1,048,576 f)
// projw_h fp16 [66][512]    @ 43,515,904 (16,896 f)
// w2_h fp16 [384][384]      @ 43,532,800 (73,728 f)
// emit fp32 [BT][66]        @ 43,606,528 (1,081,344 f)
#define OFF_PREF   0L
#define OFF_CEPADH 0L
#define OFF_QH     1056768L
#define OFF_SC     5251072L
#define OFF_PH     9445376L
#define OFF_KVT    11542528L
#define OFF_PREB   16777216L
#define OFF_KVH    16777216L
#define OFF_X1H    33554432L
#define OFF_YH     37748736L
#define OFF_WT     41943040L
#define OFF_WIH    42467328L
#define OFF_PROJW  43515904L
#define OFF_W2H    43532800L
#define OFF_EMIT   43606528L

__device__ __forceinline__ float fsig(float x) {
    return 1.f / (1.f + __expf(-x));
}
__device__ __forceinline__ float ftanh(float x) {
    float xc = fminf(fmaxf(x, -15.f), 15.f);
    float e = __expf(2.f * xc);
    return (e - 1.f) / (e + 1.f);
}
__device__ __forceinline__ uint2 f4h(float4 v) {
    H2U a, b;
    a.h[0] = (_Float16)v.x; a.h[1] = (_Float16)v.y;
    b.h[0] = (_Float16)v.z; b.h[1] = (_Float16)v.w;
    return make_uint2(a.u, b.u);
}

// ---------------- embedding / gather (fp16 outputs) ----------------
__global__ __launch_bounds__(128) void embed_k(
    const int* __restrict__ word, const int* __restrict__ intents,
    const int* __restrict__ chars, const int* __restrict__ lexi,
    const float* __restrict__ word_emb, const float* __restrict__ lexi_emb,
    const float* __restrict__ intent_emb, const float* __restrict__ char_emb,
    _Float16* __restrict__ kvh, _Float16* __restrict__ qh, _Float16* __restrict__ cepad)
{
    int bt = blockIdx.x;
    int b = bt >> 8, t = bt & 255;
    int tid = threadIdx.x;
    const float4* wrow = (const float4*)(word_emb + (long)word[bt] * 256);
    const float4* lrow = (const float4*)(lexi_emb + (long)lexi[bt] * 128);
    const float4* irow = (const float4*)(intent_emb + (long)intents[b] * 128);
    const float4* crow = (const float4*)(char_emb + (long)chars[bt] * 128);
    uint2* kvrow = (uint2*)(kvh + (long)bt * 512);
    uint2* qrow  = (uint2*)(qh + (long)bt * 512);
    uint2* cerow = (uint2*)(cepad + ((long)b * 258 + t + 1) * 128);
    if (tid < 64)       kvrow[tid] = f4h(wrow[tid]);
    else if (tid < 96)  kvrow[tid] = f4h(lrow[tid - 64]);
    else { uint2 v = f4h(irow[tid - 96]); kvrow[tid] = v; qrow[tid] = v; }
    if (tid < 32) cerow[tid] = f4h(crow[tid]);
    if (t == 0) {
        uint2 z = make_uint2(0u, 0u);
        if (tid < 32)      ((uint2*)(cepad + (long)b * 258 * 128))[tid] = z;
        else if (tid < 64) ((uint2*)(cepad + ((long)b * 258 + 257) * 128))[tid - 32] = z;
    }
}

// repack conv_w (O,C,K) -> w2_h fp16 [o][k*128+c]; zero loss slot
__global__ __launch_bounds__(256) void prep_k(const float* __restrict__ conv_w,
                                              _Float16* __restrict__ w2,
                                              float* __restrict__ out0)
{
    int idx = blockIdx.x * 256 + threadIdx.x;
    if (idx == 0) out0[0] = 0.f;
    if (idx < 384 * 384) {
        int o = idx / 384, r = idx % 384;
        int k = r >> 7, c = r & 127;
        w2[o * 384 + r] = (_Float16)conv_w[o * 384 + c * 3 + k];
    }
}

// fp32 -> fp16 elementwise (n multiple of 1024; 4 elems/thread)
__global__ __launch_bounds__(256) void cvt_k(const float* __restrict__ src,
                                             uint2* __restrict__ dst)
{
    long i = ((long)blockIdx.x * 256 + threadIdx.x);
    dst[i] = f4h(((const float4*)src)[i]);
}

// transpose+pack w_hh fp32 [4 ld][1024 row][256 k]
//   -> wt fp16 uint2 [4 ld][64 kq][1024 row]
__global__ __launch_bounds__(256) void wt_k(const float* __restrict__ whh,
                                            uint2* __restrict__ wt)
{
    int bid = blockIdx.x;
    int ld = bid >> 6;
    int rt = (bid >> 2) & 15;
    int kt = bid & 3;
    const float* src = whh + ((long)ld * 1024 + rt * 64) * 256 + kt * 64;
    __shared__ float tile[64][65];
    int c = threadIdx.x & 63, r0 = threadIdx.x >> 6;  // r0 in 0..3
#pragma unroll
    for (int i = 0; i < 16; i++)
        tile[r0 + i * 4][c] = src[(long)(r0 + i * 4) * 256 + c];
    __syncthreads();
    uint2* dst = wt + (long)ld * 65536;
#pragma unroll
    for (int i = 0; i < 4; i++) {
        int kql = r0 + i * 4;          // 0..15
        H2U ua, ub;
        ua.h[0] = (_Float16)tile[c][4 * kql + 0];
        ua.h[1] = (_Float16)tile[c][4 * kql + 1];
        ub.h[0] = (_Float16)tile[c][4 * kql + 2];
        ub.h[1] = (_Float16)tile[c][4 * kql + 3];
        dst[(long)(kt * 16 + kql) * 1024 + rt * 64 + c] = make_uint2(ua.u, ub.u);
    }
}

// fp16 transpose kv [b][256 t][512 d] -> kvT [b][512 d][256 t]
__global__ __launch_bounds__(256) void tr_k(const _Float16* __restrict__ kv,
                                            _Float16* __restrict__ kvT)
{
    int bid = blockIdx.x;                 // 64 b * 8 dt * 4 tt = 2048
    int b = bid >> 5, rem = bid & 31;
    int dt = rem >> 2, tt = rem & 3;
    __shared__ _Float16 tile[64][66];
    int c = threadIdx.x & 63, r0 = threadIdx.x >> 6;
    const _Float16* src = kv + ((long)b * 256 + tt * 64) * 512 + dt * 64;
#pragma unroll
    for (int i = 0; i < 16; i++)
        tile[r0 + i * 4][c] = src[(long)(r0 + i * 4) * 512 + c];
    __syncthreads();
    _Float16* dst = kvT + ((long)b * 512 + dt * 64) * 256 + tt * 64;
#pragma unroll
    for (int i = 0; i < 16; i++)
        dst[(long)(r0 + i * 4) * 256 + c] = tile[c][r0 + i * 4];
}

// ---------------- generalized fp16 MFMA GEMM ----------------
// C = alpha * A(MxK) @ B(NxK)^T + bias0 + bias1.  128x128 tile, 2x2 waves, BK=32.
// amode=1: A rows gathered from ce_pad layout (row m -> m*128 + (m>>8)*256, 384 contiguous halves).
// c_half: store fp16 else fp32. N-guard in staging (clamp) and epilogue (mask).
__global__ __launch_bounds__(256) void hgemm_k(
    const _Float16* __restrict__ A, int K, long sA, int amode,
    const _Float16* __restrict__ Bm, long sB, int N,
    void* __restrict__ Cv, long sC, int ldc, int c_half,
    const float* __restrict__ bias0, const float* __restrict__ bias1, float alpha)
{
    A  += (long)blockIdx.z * sA;
    Bm += (long)blockIdx.z * sB;
    const long cbase = (long)blockIdx.z * sC;
    const int m0 = blockIdx.x * 128, n0 = blockIdx.y * 128;
    const int tid = threadIdx.x;
    const int lane = tid & 63, wave = tid >> 6;
    const int wm = (wave & 1) * 64, wn = (wave >> 1) * 64;
    __shared__ _Float16 As[128][40];
    __shared__ _Float16 Bs[128][40];
    f4x acc[4][4];
#pragma unroll
    for (int i = 0; i < 4; i++)
#pragma unroll
        for (int j = 0; j < 4; j++) acc[i][j] = (f4x){0.f, 0.f, 0.f, 0.f};

    const int sr = tid & 127;
    const int sk = (tid >> 7) * 16;
    const int fm = lane & 15, fq = lane >> 4;
    const int mr = m0 + sr;
    const long aoff = amode ? ((long)mr * 128 + (long)(mr >> 8) * 256) : ((long)mr * K);
    int nr = n0 + sr; if (nr >= N) nr = N - 1;

    for (int k0 = 0; k0 < K; k0 += 32) {
        const uint4* ga = (const uint4*)(A + aoff + k0 + sk);
        const uint4* gb = (const uint4*)(Bm + (long)nr * K + k0 + sk);
        uint4 va0 = ga[0], va1 = ga[1];
        uint4 vb0 = gb[0], vb1 = gb[1];
        *(uint4*)&As[sr][sk] = va0; *(uint4*)&As[sr][sk + 8] = va1;
        *(uint4*)&Bs[sr][sk] = vb0; *(uint4*)&Bs[sr][sk + 8] = vb1;
        __syncthreads();
        h8 af[4], bf[4];
#pragma unroll
        for (int i = 0; i < 4; i++) af[i] = *(const h8*)&As[wm + i * 16 + fm][fq * 8];
#pragma unroll
        for (int i = 0; i < 4; i++) bf[i] = *(const h8*)&Bs[wn + i * 16 + fm][fq * 8];
#pragma unroll
        for (int i = 0; i < 4; i++)
#pragma unroll
            for (int j = 0; j < 4; j++)
                acc[i][j] = __builtin_amdgcn_mfma_f32_16x16x32_f16(af[i], bf[j], acc[i][j], 0, 0, 0);
        __syncthreads();
    }
    const int col = lane & 15, rowb = (lane >> 4) * 4;
#pragma unroll
    for (int i = 0; i < 4; i++) {
#pragma unroll
        for (int j = 0; j < 4; j++) {
            int n = n0 + wn + j * 16 + col;
            if (n < N) {
                float bsum = (bias0 ? bias0[n] : 0.f) + (bias1 ? bias1[n] : 0.f);
#pragma unroll
                for (int r = 0; r < 4; r++) {
                    int m = m0 + wm + i * 16 + rowb + r;
                    float v = acc[i][j][r] * alpha + bsum;
                    if (c_half) ((_Float16*)Cv)[cbase + (long)m * ldc + n] = (_Float16)v;
                    else        ((float*)Cv)[cbase + (long)m * ldc + n] = v;
                }
            }
        }
    }
}

// ---------------- row softmax over 256 cols: fp32 in, fp16 out ----------------
__global__ __launch_bounds__(256) void softmax_k(const float* __restrict__ scores,
                                                 _Float16* __restrict__ P)
{
    int row = blockIdx.x * 4 + (threadIdx.x >> 6);
    int lane = threadIdx.x & 63;
    const float4* p = (const float4*)(scores + (long)row * 256);
    float4 v = p[lane];
    float m = fmaxf(fmaxf(v.x, v.y), fmaxf(v.z, v.w));
#pragma unroll
    for (int off = 32; off; off >>= 1) m = fmaxf(m, __shfl_xor(m, off));
    v.x = __expf(v.x - m); v.y = __expf(v.y - m);
    v.z = __expf(v.z - m); v.w = __expf(v.w - m);
    float s = v.x + v.y + v.z + v.w;
#pragma unroll
    for (int off = 32; off; off >>= 1) s += __shfl_xor(s, off);
    float inv = 1.f / s;
    v.x *= inv; v.y *= inv; v.z *= inv; v.w *= inv;
    ((uint2*)(P + (long)row * 256))[lane] = f4h(v);
}

// ---------------- BiLSTM recurrence v6: balanced pipes, fp16 out, paired h reads ----------------
__global__ __launch_bounds__(512, 2) void lstm_k(
    const float* __restrict__ preF, const float* __restrict__ preB,
    const uint4* __restrict__ wtL,   // layer base: [2 dir][64 kq][512 rp] uint4
    _Float16* __restrict__ out)      // [BT][512] fp16, cols dir*256+j
{
    const int dir = blockIdx.x & 1;
    const int b   = blockIdx.x >> 1;
    const int tid = threadIdx.x;
    const int r0  = tid * 2;
    __shared__ uint4 wlds[16][512];     // kq 40..55 (128 KB)
    __shared__ __align__(16) _Float16 hq16[256];
    __shared__ float gl[1024];
    const float* pre = (dir ? preB : preF) + (long)b * 256 * 1024;
    const uint4* W = wtL + (long)dir * 32768;

    uint4 wreg[40];
#pragma unroll
    for (int i = 0; i < 40; i++) wreg[i] = W[i * 512 + tid];
#pragma unroll
    for (int i = 0; i < 16; i++) wlds[i][tid] = W[(40 + i) * 512 + tid];
    float cst = 0.f;
    __syncthreads();

#define DOT(WV, HV) do {                                                         \
    H2U wx, wy, wz, ww, hx, hy;                                                  \
    wx.u = (WV).x; wy.u = (WV).y; wz.u = (WV).z; ww.u = (WV).w;                  \
    hx.u = (HV).x; hy.u = (HV).y;                                                \
    a0 = __builtin_amdgcn_fdot2(wx.h, hx.h, a0, false);                          \
    a0 = __builtin_amdgcn_fdot2(wy.h, hy.h, a0, false);                          \
    a1 = __builtin_amdgcn_fdot2(wz.h, hx.h, a1, false);                          \
    a1 = __builtin_amdgcn_fdot2(ww.h, hy.h, a1, false);                          \
} while (0)

    for (int t = 0; t < 256; t++) {
        const int tpre = dir ? (255 - t) : t;
        float2 p = *(const float2*)(pre + (long)tpre * 1024 + r0);
        float a0 = 0.f, a1 = 0.f;
        if (t > 0) {
            uint4 s0[8];
            // issue streamed chunk (kq 56..63) — latency covered by cached compute
#pragma unroll
            for (int i = 0; i < 8; i++) s0[i] = W[(56 + i) * 512 + tid];
            // register-cached kq 0..39 (paired h reads: one b128 per 2 kq)
#pragma unroll
            for (int i = 0; i < 20; i++) {
                uint4 h4 = *(const uint4*)&hq16[i * 8];
                uint2 ha = make_uint2(h4.x, h4.y), hb = make_uint2(h4.z, h4.w);
                DOT(wreg[2 * i], ha);
                DOT(wreg[2 * i + 1], hb);
            }
            // LDS-cached kq 40..55
#pragma unroll
            for (int i = 0; i < 8; i++) {
                uint4 h4 = *(const uint4*)&hq16[(40 + 2 * i) * 4];
                uint2 ha = make_uint2(h4.x, h4.y), hb = make_uint2(h4.z, h4.w);
                uint4 w0 = wlds[2 * i][tid];
                uint4 w1 = wlds[2 * i + 1][tid];
                DOT(w0, ha);
                DOT(w1, hb);
            }
            // consume streamed chunk
#pragma unroll
            for (int i = 0; i < 4; i++) {
                uint4 h4 = *(const uint4*)&hq16[(56 + 2 * i) * 4];
                uint2 ha = make_uint2(h4.x, h4.y), hb = make_uint2(h4.z, h4.w);
                DOT(s0[2 * i], ha);
                DOT(s0[2 * i + 1], hb);
            }
        }
        *(float2*)&gl[r0] = make_float2(a0 + p.x, a1 + p.y);
        __syncthreads();
        // ---- update phase: tid<256, thread owns h-dim j ----
        if (tid < 256) {
            const int j = tid;
            float gi = gl[j], gf = gl[256 + j], gg = gl[512 + j], go = gl[768 + j];
            float si = fsig(gi), sf = fsig(gf), so = fsig(go);
            cst = sf * cst + si * ftanh(gg);
            float h = so * ftanh(cst);
            _Float16 hh = (_Float16)h;
            hq16[j] = hh;
            out[((long)b * 256 + tpre) * 512 + dir * 256 + j] = hh;
        }
        __syncthreads();
    }
#undef DOT
}

// ---------------- CRF NLL + Viterbi (register-cached T columns, vectorized) ----------------
__global__ __launch_bounds__(128) void crf_k(
    const float* __restrict__ emit, const float* __restrict__ trans,
    const int* __restrict__ labels, float* __restrict__ outv)
{
    const int b = blockIdx.x & 63;
    const bool vit = blockIdx.x >= 64;
    const int tid = threadIdx.x;
    __shared__ float Tl[NG * NG];
    __shared__ __align__(16) float bufA[68];
    __shared__ __align__(16) float bufB[68];
    __shared__ unsigned char bp[256][NG];
    __shared__ float redv[128];
    for (int i = tid; i < NG * NG; i += 128) Tl[i] = trans[i];
    __syncthreads();
    const float* eb = emit + (long)b * 256 * NG;

    float tcol[68];
    if (tid < NG) {
#pragma unroll
        for (int i = 0; i < NG; i++) tcol[i] = Tl[i * NG + tid];
    }
    tcol[66] = 0.f; tcol[67] = 0.f;
    if (tid < NG) bufA[tid] = Tl[START_ * NG + tid] + eb[tid];
    if (tid == 66 || tid == 67) { bufA[tid] = -1e30f; bufB[tid] = -1e30f; }
    __syncthreads();

    if (!vit) {
        for (int t = 1; t < 256; t++) {
            const float* prev = (t & 1) ? bufA : bufB;
            float* cur  = (t & 1) ? bufB : bufA;
            float e_t = (tid < NG) ? eb[t * NG + tid] : 0.f;
            if (tid < NG) {
                float pv[68];
#pragma unroll
                for (int c = 0; c < 17; c++) {
                    float4 p4 = *(const float4*)&prev[c * 4];
                    pv[c * 4 + 0] = p4.x + tcol[c * 4 + 0];
                    pv[c * 4 + 1] = p4.y + tcol[c * 4 + 1];
                    pv[c * 4 + 2] = p4.z + tcol[c * 4 + 2];
                    pv[c * 4 + 3] = p4.w + tcol[c * 4 + 3];
                }
                float m0 = -1e30f, m1 = -1e30f, m2 = -1e30f, m3 = -1e30f;
#pragma unroll
                for (int c = 0; c < 17; c++) {
                    m0 = fmaxf(m0, pv[c * 4 + 0]);
                    m1 = fmaxf(m1, pv[c * 4 + 1]);
                    m2 = fmaxf(m2, pv[c * 4 + 2]);
                    m3 = fmaxf(m3, pv[c * 4 + 3]);
                }
                float m = fmaxf(fmaxf(m0, m1), fmaxf(m2, m3));
                float s0 = 0.f, s1 = 0.f, s2 = 0.f, s3 = 0.f;
#pragma unroll
                for (int c = 0; c < 17; c++) {
                    s0 += __expf(pv[c * 4 + 0] - m);
                    s1 += __expf(pv[c * 4 + 1] - m);
                    s2 += __expf(pv[c * 4 + 2] - m);
                    s3 += __expf(pv[c * 4 + 3] - m);
                }
                cur[tid] = m + __logf((s0 + s1) + (s2 + s3)) + e_t;
            }
            __syncthreads();
        }
        const int* lab = labels + b * 256;
        float g = 0.f;
        for (int t = tid; t < 256; t += 128) g += eb[t * NG + lab[t]];
        for (int t = tid; t < 255; t += 128) g += Tl[lab[t] * NG + lab[t + 1]];
        redv[tid] = g;
        __syncthreads();
        if (tid == 0) {
            float* fin = bufB;
            float m = -1e30f;
            for (int j = 0; j < NG; j++) m = fmaxf(m, fin[j] + Tl[j * NG + STOP_]);
            float s = 0.f;
            for (int j = 0; j < NG; j++) s += __expf(fin[j] + Tl[j * NG + STOP_] - m);
            float logZ = m + __logf(s);
            float gold = Tl[START_ * NG + lab[0]] + Tl[lab[255] * NG + STOP_];
            for (int i = 0; i < 128; i++) gold += redv[i];
            atomicAdd(outv, logZ - gold);
        }
    } else {
        for (int t = 1; t < 256; t++) {
            const float* prev = (t & 1) ? bufA : bufB;
            float* cur  = (t & 1) ? bufB : bufA;
            float e_t = (tid < NG) ? eb[t * NG + tid] : 0.f;
            if (tid < NG) {
                float m = -1e30f; int arg = 0;
#pragma unroll
                for (int c = 0; c < 17; c++) {
                    float4 p4 = *(const float4*)&prev[c * 4];
                    float v0 = p4.x + tcol[c * 4 + 0];
                    float v1 = p4.y + tcol[c * 4 + 1];
                    float v2 = p4.z + tcol[c * 4 + 2];
                    float v3 = p4.w + tcol[c * 4 + 3];
                    if (v0 > m) { m = v0; arg = c * 4 + 0; }
                    if (v1 > m) { m = v1; arg = c * 4 + 1; }
                    if (v2 > m) { m = v2; arg = c * 4 + 2; }
                    if (v3 > m) { m = v3; arg = c * 4 + 3; }
                }
                bp[t][tid] = (unsigned char)arg;
                cur[tid] = m + e_t;
            }
            __syncthreads();
        }
        if (tid == 0) {
            float* fin = bufB;
            float m = -1e30f; int tag = 0;
            for (int j = 0; j < NG; j++) {
                float v = fin[j] + Tl[j * NG + STOP_];
                if (v > m) { m = v; tag = j; }
            }
            float* od = outv + 1 + (long)b * 256;
            od[255] = (float)tag;
            for (int t = 255; t >= 1; t--) { tag = bp[t][tag]; od[t - 1] = (float)tag; }
        }
    }
}

// ---------------- host ----------------
extern "C" void kernel_launch(void* const* d_in, const int* in_sizes, int n_in,
                              void* d_out, int out_size, void* d_ws, size_t ws_size,
                              hipStream_t stream)
{
    const int*   batch_word    = (const int*)d_in[0];
    const int*   batch_intents = (const int*)d_in[1];
    const int*   batch_char    = (const int*)d_in[3];
    const int*   batch_lexi    = (const int*)d_in[6];
    const int*   batch_label   = (const int*)d_in[7];
    const float* char_emb      = (const float*)d_in[8];
    const float* word_emb      = (const float*)d_in[9];
    const float* lexi_emb      = (const float*)d_in[10];
    const float* intent_emb    = (const float*)d_in[11];
    const float* conv_w        = (const float*)d_in[12];
    const float* conv_b        = (const float*)d_in[13];
    const float* w_ih          = (const float*)d_in[14];
    const float* w_hh          = (const float*)d_in[15];
    const float* b_ih          = (const float*)d_in[16];
    const float* b_hh          = (const float*)d_in[17];
    const float* proj_w        = (const float*)d_in[18];
    const float* proj_b        = (const float*)d_in[19];
    const float* trans         = (const float*)d_in[20];
    float* out = (float*)d_out;
    float* ws  = (float*)d_ws;

    float*    preF   = ws + OFF_PREF;
    float*    preB   = ws + OFF_PREB;
    float*    scores = ws + OFF_SC;
    float*    emit   = ws + OFF_EMIT;
    _Float16* cepadh = (_Float16*)(ws + OFF_CEPADH);
    _Float16* qh     = (_Float16*)(ws + OFF_QH);
    _Float16* Ph     = (_Float16*)(ws + OFF_PH);
    _Float16* kvTh   = (_Float16*)(ws + OFF_KVT);
    _Float16* kvh    = (_Float16*)(ws + OFF_KVH);
    _Float16* x1h    = (_Float16*)(ws + OFF_X1H);
    _Float16* yh     = (_Float16*)(ws + OFF_YH);
    uint2*    wt_u2  = (uint2*)(ws + OFF_WT);
    _Float16* wihh   = (_Float16*)(ws + OFF_WIH);
    _Float16* projwh = (_Float16*)(ws + OFF_PROJW);
    _Float16* w2h    = (_Float16*)(ws + OFF_W2H);

    embed_k<<<BT, 128, 0, stream>>>(batch_word, batch_intents, batch_char, batch_lexi,
                                    word_emb, lexi_emb, intent_emb, char_emb,
                                    kvh, qh, cepadh);
    prep_k<<<(384 * 384 + 255) / 256, 256, 0, stream>>>(conv_w, w2h, out);
    wt_k<<<256, 256, 0, stream>>>(w_hh, wt_u2);
    cvt_k<<<2048, 256, 0, stream>>>(w_ih, (uint2*)wihh);
    cvt_k<<<33, 256, 0, stream>>>(proj_w, (uint2*)projwh);
    tr_k<<<2048, 256, 0, stream>>>(kvh, kvTh);

    // char CNN: q_h[:, 0:384] = ce_pad_h @ w2_h^T + conv_b   (amode A-gather)
    hgemm_k<<<dim3(128, 3, 1), 256, 0, stream>>>(
        cepadh, 384, 0L, 1, w2h, 0L, 384,
        qh, 0L, 512, 1, conv_b, nullptr, 1.f);
    // scores = q_h @ kv_h^T * INV_TEMP  (batched, fp32 out)
    hgemm_k<<<dim3(2, 2, NB), 256, 0, stream>>>(
        qh, 512, 131072L, 0, kvh, 131072L, 256,
        scores, 65536L, 256, 0, nullptr, nullptr, INV_TEMP);
    softmax_k<<<4096, 256, 0, stream>>>(scores, Ph);
    // x1 = P_h @ kvT_h^T  (batched, fp16 out)
    hgemm_k<<<dim3(2, 4, NB), 256, 0, stream>>>(
        Ph, 256, 65536L, 0, kvTh, 131072L, 512,
        x1h, 131072L, 512, 1, nullptr, nullptr, 1.f);

    for (int l = 0; l < 2; l++) {
        const _Float16* xin = l ? yh : x1h;
        _Float16* xout = l ? x1h : yh;
        for (int d = 0; d < 2; d++) {
            hgemm_k<<<dim3(128, 8, 1), 256, 0, stream>>>(
                xin, 512, 0L, 0, wihh + (long)(l * 2 + d) * 1024 * 512, 0L, 1024,
                d ? preB : preF, 0L, 1024, 0,
                b_ih + (l * 2 + d) * 1024, b_hh + (l * 2 + d) * 1024, 1.f);
        }
        lstm_k<<<128, 512, 0, stream>>>(preF, preB,
                                        (const uint4*)(wt_u2 + (long)l * 2 * 65536), xout);
    }

    // emissions = x2_h @ proj_w_h^T + proj_b  (N=66 guarded, fp32 out)
    hgemm_k<<<dim3(128, 1, 1), 256, 0, stream>>>(
        x1h, 512, 0L, 0, projwh, 0L, NG,
        emit, 0L, NG, 0, proj_b, nullptr, 1.f);
    // CRF NLL (blocks 0..63) + Viterbi (blocks 64..127)
    crf_k<<<128, 128, 0, stream>>>(emit, trans, batch_label, out);
}